// Round 1
// baseline (6642.200 us; speedup 1.0000x reference)
//
#include <hip/hip_runtime.h>

#define H 128

// ---------------------------------------------------------------- utilities

static inline int gridFor(long long work, int block, int cap = 4096){
  long long g = (work + block - 1) / block;
  if (g > cap) g = cap;
  if (g < 1) g = 1;
  return (int)g;
}

__device__ __forceinline__ float waveReduceSum(float v){
  #pragma unroll
  for(int off = 32; off > 0; off >>= 1) v += __shfl_down(v, off);
  return v;
}

__device__ __forceinline__ void atomicMaxF(float* addr, float val){
  int* ia = (int*)addr;
  int old = *ia;
  while(__int_as_float(old) < val){
    int assumed = old;
    old = atomicCAS(ia, assumed, __float_as_int(val));
    if(old == assumed) break;
  }
}

// ---------------------------------------------------------------- kernels

__global__ void fill_f32(float* __restrict__ p, float v, int n){
  for(int i = blockIdx.x*blockDim.x + threadIdx.x; i < n; i += gridDim.x*blockDim.x)
    p[i] = v;
}

__global__ void count_dst(const int* __restrict__ dst, float* __restrict__ cnt, int E){
  for(int e = blockIdx.x*blockDim.x + threadIdx.x; e < E; e += gridDim.x*blockDim.x)
    atomicAdd(&cnt[dst[e]], 1.0f);
}

__global__ void make_dinv(const float* __restrict__ cnt, float* __restrict__ dinv, int n){
  for(int i = blockIdx.x*blockDim.x + threadIdx.x; i < n; i += gridDim.x*blockDim.x){
    float d = cnt[i];
    dinv[i] = d > 0.f ? rsqrtf(fmaxf(d, 1.f)) : 0.f;
  }
}

// out[i,j] (+)= sum_k h[i,k] * W[k,j]   (C = 5 or 6 small hop dim)
template<int C, bool ACC>
__global__ void tag_gemm(const float* __restrict__ h, const float* __restrict__ W,
                         float* __restrict__ out, int N){
  int total = N * H;
  for(int t = blockIdx.x*blockDim.x + threadIdx.x; t < total; t += gridDim.x*blockDim.x){
    int i = t >> 7, j = t & 127;
    float acc = ACC ? out[t] : 0.f;
    #pragma unroll
    for(int k = 0; k < C; k++) acc += h[i*C + k] * W[k*H + j];
    out[t] = acc;
  }
}

// hout[dst] += hin[src] * dinv[src]*dinv[dst]  (C channels, atomics)
template<int C>
__global__ void tag_hop(const int* __restrict__ src, const int* __restrict__ dst,
                        const float* __restrict__ dinv, const float* __restrict__ hin,
                        float* __restrict__ hout, int E){
  for(int e = blockIdx.x*blockDim.x + threadIdx.x; e < E; e += gridDim.x*blockDim.x){
    int s = src[e], d = dst[e];
    float nrm = dinv[s] * dinv[d];
    if(nrm != 0.f){
      #pragma unroll
      for(int k = 0; k < C; k++)
        atomicAdd(&hout[d*C + k], hin[s*C + k] * nrm);
    }
  }
}

__global__ void bias_relu(float* __restrict__ x, const float* __restrict__ b, int N){
  int total = N * H;
  for(int t = blockIdx.x*blockDim.x + threadIdx.x; t < total; t += gridDim.x*blockDim.x)
    x[t] = fmaxf(x[t] + b[t & 127], 0.f);
}

// agg[dst] += x[src]  (128-wide rows; one wave per edge, 2 floats per lane)
__global__ void gather_add(const int* __restrict__ src, const int* __restrict__ dst,
                           const float* __restrict__ x, float* __restrict__ agg, int E){
  int lane = threadIdx.x & 63;
  int w = (blockIdx.x*blockDim.x + threadIdx.x) >> 6;
  int nw = (gridDim.x*blockDim.x) >> 6;
  for(int e = w; e < E; e += nw){
    int s = src[e], d = dst[e];
    float2 v = *(const float2*)&x[(long long)s*H + lane*2];
    atomicAdd(&agg[(long long)d*H + lane*2],     v.x);
    atomicAdd(&agg[(long long)d*H + lane*2 + 1], v.y);
  }
}

// out[i] = maybe_relu( (agg[i]/max(cnt[i],1)) @ Wl + bl + x[i] @ Wr )
// In-place safe (out == x): each row is read into LDS before any store.
template<bool HAS_AGG, bool RELU, bool BIAS>
__global__ __launch_bounds__(256) void combine128(
    const float* __restrict__ x, const float* __restrict__ agg,
    const float* __restrict__ cnt, const float* __restrict__ Wl,
    const float* __restrict__ bl, const float* __restrict__ Wr,
    float* __restrict__ out, int N){
  __shared__ float xs[32 * H];
  __shared__ float ags[32 * H];
  const int t  = threadIdx.x;
  const int cg = t & 31;   // column group: 4 cols
  const int rg = t >> 5;   // row group: 4 rows

  for(int base = blockIdx.x * 32; base < N; base += gridDim.x * 32){
    for(int u = t; u < 32 * H; u += 256){
      int r = u >> 7, c = u & 127;
      int row = base + r;
      float xv = 0.f, av = 0.f;
      if(row < N){
        xv = x[(long long)row*H + c];
        if(HAS_AGG) av = agg[(long long)row*H + c] / fmaxf(cnt[row], 1.f);
      }
      xs[u] = xv;
      if(HAS_AGG) ags[u] = av;
    }
    __syncthreads();

    float acc[4][4];
    #pragma unroll
    for(int r = 0; r < 4; r++)
      #pragma unroll
      for(int c = 0; c < 4; c++)
        acc[r][c] = BIAS ? bl[cg*4 + c] : 0.f;

    #pragma unroll 4
    for(int k = 0; k < H; k++){
      const float4 wr4 = *(const float4*)&Wr[k*H + cg*4];
      float4 wl4 = make_float4(0.f,0.f,0.f,0.f);
      if(HAS_AGG) wl4 = *(const float4*)&Wl[k*H + cg*4];
      #pragma unroll
      for(int r = 0; r < 4; r++){
        float xv = xs[(rg*4 + r)*H + k];
        acc[r][0] += xv * wr4.x; acc[r][1] += xv * wr4.y;
        acc[r][2] += xv * wr4.z; acc[r][3] += xv * wr4.w;
        if(HAS_AGG){
          float av = ags[(rg*4 + r)*H + k];
          acc[r][0] += av * wl4.x; acc[r][1] += av * wl4.y;
          acc[r][2] += av * wl4.z; acc[r][3] += av * wl4.w;
        }
      }
    }

    #pragma unroll
    for(int r = 0; r < 4; r++){
      int row = base + rg*4 + r;
      if(row < N){
        float4 o = make_float4(acc[r][0], acc[r][1], acc[r][2], acc[r][3]);
        if(RELU){
          o.x = fmaxf(o.x, 0.f); o.y = fmaxf(o.y, 0.f);
          o.z = fmaxf(o.z, 0.f); o.w = fmaxf(o.w, 0.f);
        }
        *(float4*)&out[(long long)row*H + cg*4] = o;
      }
    }
    __syncthreads();
  }
}

// out[i] = dot(x[i,:], v)  (wave per row)
__global__ void rowdot(const float* __restrict__ x, const float* __restrict__ v,
                       float* __restrict__ out, int N){
  int lane = threadIdx.x & 63;
  int w = (blockIdx.x*blockDim.x + threadIdx.x) >> 6;
  int nw = (gridDim.x*blockDim.x) >> 6;
  for(int i = w; i < N; i += nw){
    float acc = x[(long long)i*H + lane] * v[lane] + x[(long long)i*H + 64 + lane] * v[64 + lane];
    acc = waveReduceSum(acc);
    if(lane == 0) out[i] = acc;
  }
}

__global__ void dot128(const float* __restrict__ a, const float* __restrict__ b,
                       float* __restrict__ o){
  int l = threadIdx.x;
  float acc = a[l]*b[l] + a[l+64]*b[l+64];
  acc = waveReduceSum(acc);
  if(l == 0) o[0] = acc;
}

__global__ void gat_logits(const int* __restrict__ src, const int* __restrict__ dst,
                           const float* __restrict__ attr, const float* __restrict__ av,
                           const float* __restrict__ ad, const float* __restrict__ cptr,
                           float* __restrict__ ae, int E){
  float c = cptr[0];
  for(int e = blockIdx.x*blockDim.x + threadIdx.x; e < E; e += gridDim.x*blockDim.x){
    float a = av[src[e]] + ad[dst[e]] + attr[e] * c;
    ae[e] = a > 0.f ? a : 0.2f * a;   // leaky_relu 0.2
  }
}

__global__ void seg_max(const float* __restrict__ ae, const int* __restrict__ dst,
                        float* __restrict__ m, int E){
  for(int e = blockIdx.x*blockDim.x + threadIdx.x; e < E; e += gridDim.x*blockDim.x)
    atomicMaxF(&m[dst[e]], ae[e]);
}

__global__ void gat_exp(float* __restrict__ ae, const int* __restrict__ dst,
                        const float* __restrict__ m, float* __restrict__ den, int E){
  for(int e = blockIdx.x*blockDim.x + threadIdx.x; e < E; e += gridDim.x*blockDim.x){
    float ex = expf(ae[e] - m[dst[e]]);
    ae[e] = ex;
    atomicAdd(&den[dst[e]], ex);
  }
}

// out[dst] += (ae[e]/max(den[dst],1e-16)) * hs[src]
__global__ void gat_scatter(const int* __restrict__ src, const int* __restrict__ dst,
                            const float* __restrict__ ae, const float* __restrict__ den,
                            const float* __restrict__ hs, float* __restrict__ out, int E){
  int lane = threadIdx.x & 63;
  int w = (blockIdx.x*blockDim.x + threadIdx.x) >> 6;
  int nw = (gridDim.x*blockDim.x) >> 6;
  for(int e = w; e < E; e += nw){
    int s = src[e], d = dst[e];
    float alpha = ae[e] / fmaxf(den[d], 1e-16f);
    float2 v = *(const float2*)&hs[(long long)s*H + lane*2];
    atomicAdd(&out[(long long)d*H + lane*2],     v.x * alpha);
    atomicAdd(&out[(long long)d*H + lane*2 + 1], v.y * alpha);
  }
}

__global__ void mlp_out(const float* __restrict__ x, const float* __restrict__ W,
                        const float* __restrict__ b, float* __restrict__ out, int N){
  int lane = threadIdx.x & 63;
  int w = (blockIdx.x*blockDim.x + threadIdx.x) >> 6;
  int nw = (gridDim.x*blockDim.x) >> 6;
  for(int i = w; i < N; i += nw){
    float acc = x[(long long)i*H + lane] * W[lane] + x[(long long)i*H + 64 + lane] * W[64 + lane];
    acc = waveReduceSum(acc);
    if(lane == 0) out[i] = acc + b[0];
  }
}

// ---------------------------------------------------------------- launch

extern "C" void kernel_launch(void* const* d_in, const int* in_sizes, int n_in,
                              void* d_out, int out_size, void* d_ws, size_t ws_size,
                              hipStream_t stream) {
  const float* game_x  = (const float*)d_in[0];
  const float* state_x = (const float*)d_in[1];
  const int*   e_vv    = (const int*)d_in[2];
  const int*   e_hist  = (const int*)d_in[4];
  const float* attr_h  = (const float*)d_in[5];
  const int*   e_in    = (const int*)d_in[6];
  const int*   e_ss    = (const int*)d_in[7];
  const float* tag1_W  = (const float*)d_in[8];
  const float* tag1_b  = (const float*)d_in[9];
  const float* tag2_W  = (const float*)d_in[10];
  const float* tag2_b  = (const float*)d_in[11];
  const float* sage_Wl = (const float*)d_in[12];
  const float* sage_bl = (const float*)d_in[13];
  const float* sage_Wr = (const float*)d_in[14];
  const float* gat_Wsrc= (const float*)d_in[15];
  const float* gat_Wdst= (const float*)d_in[16];
  const float* gat_We  = (const float*)d_in[17];
  const float* gat_asrc= (const float*)d_in[18];
  const float* gat_adst= (const float*)d_in[19];
  const float* gat_ae  = (const float*)d_in[20];
  const float* gat_b   = (const float*)d_in[21];
  const float* mlp_W   = (const float*)d_in[22];
  const float* mlp_b   = (const float*)d_in[23];
  float* out = (float*)d_out;

  const int NV  = in_sizes[0] / 5;
  const int NS  = in_sizes[1] / 6;
  const int EVV = in_sizes[2] / 2;
  const int EH  = in_sizes[4] / 2;
  const int EIN = in_sizes[6] / 2;
  const int ESS = in_sizes[7] / 2;

  const int* vv_src = e_vv;            const int* vv_dst = e_vv + EVV;
  const int* eh_src = e_hist;          const int* eh_dst = e_hist + EH;
  const int* in_src = e_in;            const int* in_dst = e_in + EIN;
  const int* ss_src = e_ss;            const int* ss_dst = e_ss + ESS;

  // workspace bump allocator (512B aligned)
  char* wp = (char*)d_ws;
  auto alloc = [&](size_t elems) -> float* {
    float* p = (float*)wp;
    size_t bytes = (elems * 4 + 511) & ~size_t(511);
    wp += bytes;
    return p;
  };
  float* V0    = alloc((size_t)NV * H);   // gx
  float* V1    = alloc((size_t)NV * H);   // agg / hs
  float* S0    = alloc((size_t)NS * H);   // sx / agg
  float* S1    = alloc((size_t)NS * H);   // agg / hist / sx2
  float* cnt_v = alloc(NV);
  float* dinv_v= alloc(NV);
  float* cnt_s = alloc(NS);
  float* dinv_s= alloc(NS);
  float* cnt_in= alloc(NS);
  float* av    = alloc(NV);
  float* ad    = alloc(NS);
  float* m_s   = alloc(NS);
  float* den_s = alloc(NS);
  float* aeb   = alloc(EH);
  float* h5a   = alloc((size_t)NV * 5);
  float* h5b   = alloc((size_t)NV * 5);
  float* h6a   = alloc((size_t)NS * 6);
  float* h6b   = alloc((size_t)NS * 6);
  float* cbuf  = alloc(1);
  (void)ws_size; (void)n_in; (void)out_size;

  const int B = 256;
  #define GRID1(n) gridFor((long long)(n), B), B, 0, stream
  #define GRIDW(e) gridFor((long long)(e) * 64, B, 8192), B, 0, stream

  // ---- degree counts (shared by TAG norm and SAGE mean)
  hipMemsetAsync(cnt_v, 0, (size_t)NV*4, stream);
  hipMemsetAsync(cnt_s, 0, (size_t)NS*4, stream);
  hipMemsetAsync(cnt_in,0, (size_t)NS*4, stream);
  count_dst<<<GRID1(EVV)>>>(vv_dst, cnt_v, EVV);
  count_dst<<<GRID1(ESS)>>>(ss_dst, cnt_s, ESS);
  count_dst<<<GRID1(EIN)>>>(in_dst, cnt_in, EIN);
  make_dinv<<<GRID1(NV)>>>(cnt_v, dinv_v, NV);
  make_dinv<<<GRID1(NS)>>>(cnt_s, dinv_s, NS);

  // ---- TAG1 (game tower) -> V0
  tag_gemm<5,false><<<GRID1((long long)NV*H)>>>(game_x, tag1_W, V0, NV);
  hipMemsetAsync(h5b, 0, (size_t)NV*5*4, stream);
  tag_hop<5><<<GRID1(EVV)>>>(vv_src, vv_dst, dinv_v, game_x, h5b, EVV);
  tag_gemm<5,true><<<GRID1((long long)NV*H)>>>(h5b, tag1_W + 1*5*H, V0, NV);
  hipMemsetAsync(h5a, 0, (size_t)NV*5*4, stream);
  tag_hop<5><<<GRID1(EVV)>>>(vv_src, vv_dst, dinv_v, h5b, h5a, EVV);
  tag_gemm<5,true><<<GRID1((long long)NV*H)>>>(h5a, tag1_W + 2*5*H, V0, NV);
  hipMemsetAsync(h5b, 0, (size_t)NV*5*4, stream);
  tag_hop<5><<<GRID1(EVV)>>>(vv_src, vv_dst, dinv_v, h5a, h5b, EVV);
  tag_gemm<5,true><<<GRID1((long long)NV*H)>>>(h5b, tag1_W + 3*5*H, V0, NV);
  bias_relu<<<GRID1((long long)NV*H)>>>(V0, tag1_b, NV);

  // ---- SAGE 0,1 on e_vv (in-place on V0)
  for(int layer = 0; layer < 2; layer++){
    hipMemsetAsync(V1, 0, (size_t)NV*H*4, stream);
    gather_add<<<GRIDW(EVV)>>>(vv_src, vv_dst, V0, V1, EVV);
    combine128<true,true,true><<<gridFor(((long long)NV+31)/32, 1, 8192), B, 0, stream>>>(
        V0, V1, cnt_v, sage_Wl + (size_t)layer*H*H, sage_bl + (size_t)layer*H,
        sage_Wr + (size_t)layer*H*H, V0, NV);
  }

  // ---- TAG2 (state tower) -> S0
  tag_gemm<6,false><<<GRID1((long long)NS*H)>>>(state_x, tag2_W, S0, NS);
  hipMemsetAsync(h6b, 0, (size_t)NS*6*4, stream);
  tag_hop<6><<<GRID1(ESS)>>>(ss_src, ss_dst, dinv_s, state_x, h6b, ESS);
  tag_gemm<6,true><<<GRID1((long long)NS*H)>>>(h6b, tag2_W + 1*6*H, S0, NS);
  hipMemsetAsync(h6a, 0, (size_t)NS*6*4, stream);
  tag_hop<6><<<GRID1(ESS)>>>(ss_src, ss_dst, dinv_s, h6b, h6a, ESS);
  tag_gemm<6,true><<<GRID1((long long)NS*H)>>>(h6a, tag2_W + 2*6*H, S0, NS);
  hipMemsetAsync(h6b, 0, (size_t)NS*6*4, stream);
  tag_hop<6><<<GRID1(ESS)>>>(ss_src, ss_dst, dinv_s, h6a, h6b, ESS);
  tag_gemm<6,true><<<GRID1((long long)NS*H)>>>(h6b, tag2_W + 3*6*H, S0, NS);
  bias_relu<<<GRID1((long long)NS*H)>>>(S0, tag2_b, NS);

  // ---- SAGE 2,3 on e_ss (in-place on S0)
  for(int layer = 2; layer < 4; layer++){
    hipMemsetAsync(S1, 0, (size_t)NS*H*4, stream);
    gather_add<<<GRIDW(ESS)>>>(ss_src, ss_dst, S0, S1, ESS);
    combine128<true,true,true><<<gridFor(((long long)NS+31)/32, 1, 8192), B, 0, stream>>>(
        S0, S1, cnt_s, sage_Wl + (size_t)layer*H*H, sage_bl + (size_t)layer*H,
        sage_Wr + (size_t)layer*H*H, S0, NS);
  }

  // ---- GAT (gx -> sx attention) : hist -> S1
  combine128<false,false,false><<<gridFor(((long long)NV+31)/32, 1, 8192), B, 0, stream>>>(
      V0, nullptr, nullptr, nullptr, nullptr, gat_Wsrc, V1, NV);            // hs = gx@Wsrc
  combine128<false,false,false><<<gridFor(((long long)NS+31)/32, 1, 8192), B, 0, stream>>>(
      S0, nullptr, nullptr, nullptr, nullptr, gat_Wdst, S1, NS);            // hd = sx@Wdst
  rowdot<<<GRIDW(NV)>>>(V1, gat_asrc, av, NV);
  rowdot<<<GRIDW(NS)>>>(S1, gat_adst, ad, NS);
  dot128<<<1, 64, 0, stream>>>(gat_We, gat_ae, cbuf);
  gat_logits<<<GRID1(EH)>>>(eh_src, eh_dst, attr_h, av, ad, cbuf, aeb, EH);
  fill_f32<<<GRID1(NS)>>>(m_s, -3.0e38f, NS);
  hipMemsetAsync(den_s, 0, (size_t)NS*4, stream);
  seg_max<<<GRID1(EH)>>>(aeb, eh_dst, m_s, EH);
  gat_exp<<<GRID1(EH)>>>(aeb, eh_dst, m_s, den_s, EH);
  hipMemsetAsync(S1, 0, (size_t)NS*H*4, stream);
  gat_scatter<<<GRIDW(EH)>>>(eh_src, eh_dst, aeb, den_s, V1, S1, EH);
  bias_relu<<<GRID1((long long)NS*H)>>>(S1, gat_b, NS);                     // hist in S1

  // ---- SAGE4: aggregate gx over e_in, x_dst = hist (in-place on S1)
  hipMemsetAsync(S0, 0, (size_t)NS*H*4, stream);
  gather_add<<<GRIDW(EIN)>>>(in_src, in_dst, V0, S0, EIN);
  combine128<true,true,true><<<gridFor(((long long)NS+31)/32, 1, 8192), B, 0, stream>>>(
      S1, S0, cnt_in, sage_Wl + (size_t)4*H*H, sage_bl + (size_t)4*H,
      sage_Wr + (size_t)4*H*H, S1, NS);

  // ---- SAGE 5,6 on e_ss (in-place on S1)
  for(int layer = 5; layer < 7; layer++){
    hipMemsetAsync(S0, 0, (size_t)NS*H*4, stream);
    gather_add<<<GRIDW(ESS)>>>(ss_src, ss_dst, S1, S0, ESS);
    combine128<true,true,true><<<gridFor(((long long)NS+31)/32, 1, 8192), B, 0, stream>>>(
        S1, S0, cnt_s, sage_Wl + (size_t)layer*H*H, sage_bl + (size_t)layer*H,
        sage_Wr + (size_t)layer*H*H, S1, NS);
  }

  // ---- final MLP -> d_out
  mlp_out<<<GRIDW(NS)>>>(S1, mlp_W, mlp_b, out, NS);

  #undef GRID1
  #undef GRIDW
}

// Round 2
// 2325.443 us; speedup vs baseline: 2.8563x; 2.8563x over previous
//
#include <hip/hip_runtime.h>

#define H 128

// ---------------------------------------------------------------- utilities

static inline int gridFor(long long work, int block, int cap = 8192){
  long long g = (work + block - 1) / block;
  if (g > cap) g = cap;
  if (g < 1) g = 1;
  return (int)g;
}

__device__ __forceinline__ float waveAllSum(float v){
  #pragma unroll
  for(int off = 32; off > 0; off >>= 1) v += __shfl_xor(v, off);
  return v;
}
__device__ __forceinline__ float waveAllMax(float v){
  #pragma unroll
  for(int off = 32; off > 0; off >>= 1) v = fmaxf(v, __shfl_xor(v, off));
  return v;
}
__device__ __forceinline__ float waveReduceSum(float v){
  #pragma unroll
  for(int off = 32; off > 0; off >>= 1) v += __shfl_down(v, off);
  return v;
}

// ---------------------------------------------------------------- CSR build

__global__ void count_dst_i(const int* __restrict__ dst, int* __restrict__ cnt, int E){
  for(int e = blockIdx.x*blockDim.x + threadIdx.x; e < E; e += gridDim.x*blockDim.x)
    atomicAdd(&cnt[dst[e]], 1);
}

// single-block exclusive scan; writes out[0..n-1] exclusive prefix, out[n] = total
__global__ __launch_bounds__(1024) void exscan(const int* __restrict__ in,
                                               int* __restrict__ out, int n){
  __shared__ int sd[1024];
  __shared__ int runS;
  if(threadIdx.x == 0) runS = 0;
  __syncthreads();
  const int CH = 4096;
  for(int base = 0; base < n; base += CH){
    int v[4]; int local = 0;
    #pragma unroll
    for(int k = 0; k < 4; k++){
      int i = base + threadIdx.x*4 + k;
      v[k] = (i < n) ? in[i] : 0;
      local += v[k];
    }
    int myrun = runS;
    sd[threadIdx.x] = local;
    __syncthreads();
    for(int off = 1; off < 1024; off <<= 1){
      int t = (threadIdx.x >= off) ? sd[threadIdx.x - off] : 0;
      __syncthreads();
      sd[threadIdx.x] += t;
      __syncthreads();
    }
    int excl = myrun + sd[threadIdx.x] - local;   // exclusive base for this thread's 4
    #pragma unroll
    for(int k = 0; k < 4; k++){
      int i = base + threadIdx.x*4 + k;
      if(i < n) out[i] = excl;
      excl += v[k];
    }
    int total = sd[1023];
    __syncthreads();
    if(threadIdx.x == 0) runS = myrun + total;
    __syncthreads();
  }
  if(threadIdx.x == 0) out[n] = runS;
}

__global__ void csr_fill(const int* __restrict__ src, const int* __restrict__ dst,
                         int* __restrict__ cursor, int* __restrict__ col,
                         int* __restrict__ eid, int E){
  for(int e = blockIdx.x*blockDim.x + threadIdx.x; e < E; e += gridDim.x*blockDim.x){
    int d = dst[e];
    int pos = atomicAdd(&cursor[d], 1);
    col[pos] = src[e];
    if(eid) eid[pos] = e;
  }
}

__global__ void make_dinv(const int* __restrict__ rowp, float* __restrict__ dinv, int n){
  for(int i = blockIdx.x*blockDim.x + threadIdx.x; i < n; i += gridDim.x*blockDim.x){
    int d = rowp[i+1] - rowp[i];
    dinv[i] = d > 0 ? rsqrtf((float)d) : 0.f;
  }
}

// ---------------------------------------------------------------- TAG

// out[i,j] (+)= sum_k h[i,k] * W[k,j]   (C = 5 or 6)
template<int C, bool ACC>
__global__ void tag_gemm(const float* __restrict__ h, const float* __restrict__ W,
                         float* __restrict__ out, int N){
  int total = N * H;
  for(int t = blockIdx.x*blockDim.x + threadIdx.x; t < total; t += gridDim.x*blockDim.x){
    int i = t >> 7, j = t & 127;
    float acc = ACC ? out[t] : 0.f;
    #pragma unroll
    for(int k = 0; k < C; k++) acc += h[i*C + k] * W[k*H + j];
    out[t] = acc;
  }
}

// hout[i] = sum_{e: dst=i} hin[src]*dinv[src]*dinv[i]   (thread per dst row)
template<int C>
__global__ void csr_tag_hop(const int* __restrict__ rowp, const int* __restrict__ col,
                            const float* __restrict__ dinv, const float* __restrict__ hin,
                            float* __restrict__ hout, int N){
  for(int i = blockIdx.x*blockDim.x + threadIdx.x; i < N; i += gridDim.x*blockDim.x){
    int b = rowp[i], e = rowp[i+1];
    float dd = dinv[i];
    float acc[C];
    #pragma unroll
    for(int k = 0; k < C; k++) acc[k] = 0.f;
    for(int p = b; p < e; p++){
      int s = col[p];
      float nrm = dinv[s] * dd;
      #pragma unroll
      for(int k = 0; k < C; k++) acc[k] += hin[s*C + k] * nrm;
    }
    #pragma unroll
    for(int k = 0; k < C; k++) hout[i*C + k] = acc[k];
  }
}

__global__ void bias_relu(float* __restrict__ x, const float* __restrict__ b, int N){
  int total = N * H;
  for(int t = blockIdx.x*blockDim.x + threadIdx.x; t < total; t += gridDim.x*blockDim.x)
    x[t] = fmaxf(x[t] + b[t & 127], 0.f);
}

// ---------------------------------------------------------------- SAGE gather

// agg[i] = mean_{e: dst=i} x[src]   (wave per dst row, float2 per lane)
__global__ void csr_gather(const int* __restrict__ rowp, const int* __restrict__ col,
                           const float* __restrict__ x, float* __restrict__ agg, int N){
  int lane = threadIdx.x & 63;
  int w = (blockIdx.x*blockDim.x + threadIdx.x) >> 6;
  int nw = (gridDim.x*blockDim.x) >> 6;
  for(int i = w; i < N; i += nw){
    int b = rowp[i], e = rowp[i+1];
    float2 acc = make_float2(0.f, 0.f);
    for(int p = b; p < e; p++){
      int s = col[p];
      float2 v = *(const float2*)&x[(size_t)s*H + lane*2];
      acc.x += v.x; acc.y += v.y;
    }
    float inv = 1.f / fmaxf((float)(e - b), 1.f);
    acc.x *= inv; acc.y *= inv;
    *(float2*)&agg[(size_t)i*H + lane*2] = acc;
  }
}

// ---------------------------------------------------------------- dense combine

// out[i] = maybe_relu( agg[i] @ Wl + bl + x[i] @ Wr )   (agg already mean'd)
// In-place safe (out == x): rows staged in LDS before stores.
template<bool HAS_AGG, bool RELU, bool BIAS>
__global__ __launch_bounds__(256) void combine128(
    const float* __restrict__ x, const float* __restrict__ agg,
    const float* __restrict__ Wl, const float* __restrict__ bl,
    const float* __restrict__ Wr, float* __restrict__ out, int N){
  __shared__ float xs[32 * H];
  __shared__ float ags[HAS_AGG ? 32 * H : 1];
  const int t  = threadIdx.x;
  const int cg = t & 31;
  const int rg = t >> 5;

  for(int base = blockIdx.x * 32; base < N; base += gridDim.x * 32){
    for(int u = t; u < 32 * H; u += 256){
      int r = u >> 7, c = u & 127;
      int row = base + r;
      float xv = 0.f, av = 0.f;
      if(row < N){
        xv = x[(size_t)row*H + c];
        if(HAS_AGG) av = agg[(size_t)row*H + c];
      }
      xs[u] = xv;
      if(HAS_AGG) ags[u] = av;
    }
    __syncthreads();

    float acc[4][4];
    #pragma unroll
    for(int r = 0; r < 4; r++)
      #pragma unroll
      for(int c = 0; c < 4; c++)
        acc[r][c] = BIAS ? bl[cg*4 + c] : 0.f;

    #pragma unroll 4
    for(int k = 0; k < H; k++){
      const float4 wr4 = *(const float4*)&Wr[k*H + cg*4];
      float4 wl4 = make_float4(0.f,0.f,0.f,0.f);
      if(HAS_AGG) wl4 = *(const float4*)&Wl[k*H + cg*4];
      #pragma unroll
      for(int r = 0; r < 4; r++){
        float xv = xs[(rg*4 + r)*H + k];
        acc[r][0] += xv * wr4.x; acc[r][1] += xv * wr4.y;
        acc[r][2] += xv * wr4.z; acc[r][3] += xv * wr4.w;
        if(HAS_AGG){
          float av = ags[(rg*4 + r)*H + k];
          acc[r][0] += av * wl4.x; acc[r][1] += av * wl4.y;
          acc[r][2] += av * wl4.z; acc[r][3] += av * wl4.w;
        }
      }
    }

    #pragma unroll
    for(int r = 0; r < 4; r++){
      int row = base + rg*4 + r;
      if(row < N){
        float4 o = make_float4(acc[r][0], acc[r][1], acc[r][2], acc[r][3]);
        if(RELU){
          o.x = fmaxf(o.x, 0.f); o.y = fmaxf(o.y, 0.f);
          o.z = fmaxf(o.z, 0.f); o.w = fmaxf(o.w, 0.f);
        }
        *(float4*)&out[(size_t)row*H + cg*4] = o;
      }
    }
    __syncthreads();
  }
}

// ---------------------------------------------------------------- GAT

__global__ void rowdot(const float* __restrict__ x, const float* __restrict__ v,
                       float* __restrict__ out, int N){
  int lane = threadIdx.x & 63;
  int w = (blockIdx.x*blockDim.x + threadIdx.x) >> 6;
  int nw = (gridDim.x*blockDim.x) >> 6;
  for(int i = w; i < N; i += nw){
    float acc = x[(size_t)i*H + lane] * v[lane] + x[(size_t)i*H + 64 + lane] * v[64 + lane];
    acc = waveReduceSum(acc);
    if(lane == 0) out[i] = acc;
  }
}

__global__ void dot128(const float* __restrict__ a, const float* __restrict__ b,
                       float* __restrict__ o){
  int l = threadIdx.x;
  float acc = a[l]*b[l] + a[l+64]*b[l+64];
  acc = waveReduceSum(acc);
  if(l == 0) o[0] = acc;
}

// Full GAT per dst row (wave per row): logits -> segmax -> softmax -> weighted sum
// out[i] = relu( sum_e alpha_e * hs[src_e] + bias )
__global__ void gat_fused(const int* __restrict__ rowp, const int* __restrict__ col,
                          const int* __restrict__ eid, const float* __restrict__ attr,
                          const float* __restrict__ av, const float* __restrict__ ad,
                          const float* __restrict__ cptr, const float* __restrict__ hs,
                          const float* __restrict__ bias, float* __restrict__ out, int N){
  const float c = cptr[0];
  int lane = threadIdx.x & 63;
  int w = (blockIdx.x*blockDim.x + threadIdx.x) >> 6;
  int nw = (gridDim.x*blockDim.x) >> 6;
  for(int i = w; i < N; i += nw){
    int b = rowp[i], e = rowp[i+1];
    float adi = ad[i];
    // pass 1: max over edges (lane-strided)
    float amax = -3.0e38f;
    for(int p = b + lane; p < e; p += 64){
      float a = av[col[p]] + adi + attr[eid[p]] * c;
      a = a > 0.f ? a : 0.2f * a;
      amax = fmaxf(amax, a);
    }
    amax = waveAllMax(amax);
    // pass 2: sum of exp
    float sume = 0.f;
    for(int p = b + lane; p < e; p += 64){
      float a = av[col[p]] + adi + attr[eid[p]] * c;
      a = a > 0.f ? a : 0.2f * a;
      sume += __expf(a - amax);
    }
    sume = waveAllSum(sume);
    float rden = 1.f / fmaxf(sume, 1e-16f);
    // pass 3: weighted accumulate (all lanes walk edges; lane covers 2 columns)
    float2 acc = make_float2(0.f, 0.f);
    for(int p = b; p < e; p++){
      int s = col[p];
      float a = av[s] + adi + attr[eid[p]] * c;
      a = a > 0.f ? a : 0.2f * a;
      float alpha = __expf(a - amax) * rden;
      float2 v = *(const float2*)&hs[(size_t)s*H + lane*2];
      acc.x += alpha * v.x; acc.y += alpha * v.y;
    }
    float2 o = make_float2(fmaxf(acc.x + bias[lane*2], 0.f),
                           fmaxf(acc.y + bias[lane*2 + 1], 0.f));
    *(float2*)&out[(size_t)i*H + lane*2] = o;
  }
}

__global__ void mlp_out(const float* __restrict__ x, const float* __restrict__ W,
                        const float* __restrict__ b, float* __restrict__ out, int N){
  int lane = threadIdx.x & 63;
  int w = (blockIdx.x*blockDim.x + threadIdx.x) >> 6;
  int nw = (gridDim.x*blockDim.x) >> 6;
  for(int i = w; i < N; i += nw){
    float acc = x[(size_t)i*H + lane] * W[lane] + x[(size_t)i*H + 64 + lane] * W[64 + lane];
    acc = waveReduceSum(acc);
    if(lane == 0) out[i] = acc + b[0];
  }
}

// ---------------------------------------------------------------- launch

extern "C" void kernel_launch(void* const* d_in, const int* in_sizes, int n_in,
                              void* d_out, int out_size, void* d_ws, size_t ws_size,
                              hipStream_t stream) {
  const float* game_x  = (const float*)d_in[0];
  const float* state_x = (const float*)d_in[1];
  const int*   e_vv    = (const int*)d_in[2];
  const int*   e_hist  = (const int*)d_in[4];
  const float* attr_h  = (const float*)d_in[5];
  const int*   e_in    = (const int*)d_in[6];
  const int*   e_ss    = (const int*)d_in[7];
  const float* tag1_W  = (const float*)d_in[8];
  const float* tag1_b  = (const float*)d_in[9];
  const float* tag2_W  = (const float*)d_in[10];
  const float* tag2_b  = (const float*)d_in[11];
  const float* sage_Wl = (const float*)d_in[12];
  const float* sage_bl = (const float*)d_in[13];
  const float* sage_Wr = (const float*)d_in[14];
  const float* gat_Wsrc= (const float*)d_in[15];
  const float* gat_Wdst= (const float*)d_in[16];
  const float* gat_We  = (const float*)d_in[17];
  const float* gat_asrc= (const float*)d_in[18];
  const float* gat_adst= (const float*)d_in[19];
  const float* gat_ae  = (const float*)d_in[20];
  const float* gat_b   = (const float*)d_in[21];
  const float* mlp_W   = (const float*)d_in[22];
  const float* mlp_b   = (const float*)d_in[23];
  float* out = (float*)d_out;

  const int NV  = in_sizes[0] / 5;
  const int NS  = in_sizes[1] / 6;
  const int EVV = in_sizes[2] / 2;
  const int EH  = in_sizes[4] / 2;
  const int EIN = in_sizes[6] / 2;
  const int ESS = in_sizes[7] / 2;

  const int* vv_src = e_vv;   const int* vv_dst = e_vv + EVV;
  const int* eh_src = e_hist; const int* eh_dst = e_hist + EH;
  const int* in_src = e_in;   const int* in_dst = e_in + EIN;
  const int* ss_src = e_ss;   const int* ss_dst = e_ss + ESS;

  // workspace bump allocator (512B aligned)
  char* wp = (char*)d_ws;
  auto alloc = [&](size_t bytes) -> void* {
    void* p = (void*)wp;
    wp += (bytes + 511) & ~size_t(511);
    return p;
  };
  float* V0 = (float*)alloc((size_t)NV*H*4);
  float* V1 = (float*)alloc((size_t)NV*H*4);
  float* S0 = (float*)alloc((size_t)NS*H*4);
  float* S1 = (float*)alloc((size_t)NS*H*4);
  float* dinv_v = (float*)alloc((size_t)NV*4);
  float* dinv_s = (float*)alloc((size_t)NS*4);
  float* av  = (float*)alloc((size_t)NV*4);
  float* ad  = (float*)alloc((size_t)NS*4);
  float* h5a = (float*)alloc((size_t)NV*5*4);
  float* h5b = (float*)alloc((size_t)NV*5*4);
  float* h6a = (float*)alloc((size_t)NS*6*4);
  float* h6b = (float*)alloc((size_t)NS*6*4);
  float* cbuf= (float*)alloc(4);
  // CSR: vv
  int* vv_rowp = (int*)alloc((size_t)(NV+1)*4);
  int* vv_col  = (int*)alloc((size_t)EVV*4);
  int* vv_cur  = (int*)alloc((size_t)NV*4);
  // CSR: ss
  int* ss_rowp = (int*)alloc((size_t)(NS+1)*4);
  int* ss_col  = (int*)alloc((size_t)ESS*4);
  int* ss_cur  = (int*)alloc((size_t)NS*4);
  // CSR: hist (needs eid for attr)
  int* eh_rowp = (int*)alloc((size_t)(NS+1)*4);
  int* eh_col  = (int*)alloc((size_t)EH*4);
  int* eh_eid  = (int*)alloc((size_t)EH*4);
  int* eh_cur  = (int*)alloc((size_t)NS*4);
  // CSR: in
  int* in_rowp = (int*)alloc((size_t)(NS+1)*4);
  int* in_col  = (int*)alloc((size_t)EIN*4);
  int* in_cur  = (int*)alloc((size_t)NS*4);
  (void)ws_size; (void)n_in; (void)out_size;

  const int B = 256;
  #define GRID1(n) gridFor((long long)(n), B), B, 0, stream
  #define GRIDW(e) gridFor((long long)(e) * 64, B, 8192), B, 0, stream

  // ---- build 4 CSRs
  hipMemsetAsync(vv_cur, 0, (size_t)NV*4, stream);
  hipMemsetAsync(ss_cur, 0, (size_t)NS*4, stream);
  hipMemsetAsync(eh_cur, 0, (size_t)NS*4, stream);
  hipMemsetAsync(in_cur, 0, (size_t)NS*4, stream);
  count_dst_i<<<GRID1(EVV)>>>(vv_dst, vv_cur, EVV);
  count_dst_i<<<GRID1(ESS)>>>(ss_dst, ss_cur, ESS);
  count_dst_i<<<GRID1(EH)>>>(eh_dst, eh_cur, EH);
  count_dst_i<<<GRID1(EIN)>>>(in_dst, in_cur, EIN);
  exscan<<<1, 1024, 0, stream>>>(vv_cur, vv_rowp, NV);
  exscan<<<1, 1024, 0, stream>>>(ss_cur, ss_rowp, NS);
  exscan<<<1, 1024, 0, stream>>>(eh_cur, eh_rowp, NS);
  exscan<<<1, 1024, 0, stream>>>(in_cur, in_rowp, NS);
  hipMemcpyAsync(vv_cur, vv_rowp, (size_t)NV*4, hipMemcpyDeviceToDevice, stream);
  hipMemcpyAsync(ss_cur, ss_rowp, (size_t)NS*4, hipMemcpyDeviceToDevice, stream);
  hipMemcpyAsync(eh_cur, eh_rowp, (size_t)NS*4, hipMemcpyDeviceToDevice, stream);
  hipMemcpyAsync(in_cur, in_rowp, (size_t)NS*4, hipMemcpyDeviceToDevice, stream);
  csr_fill<<<GRID1(EVV)>>>(vv_src, vv_dst, vv_cur, vv_col, nullptr, EVV);
  csr_fill<<<GRID1(ESS)>>>(ss_src, ss_dst, ss_cur, ss_col, nullptr, ESS);
  csr_fill<<<GRID1(EH)>>>(eh_src, eh_dst, eh_cur, eh_col, eh_eid, EH);
  csr_fill<<<GRID1(EIN)>>>(in_src, in_dst, in_cur, in_col, nullptr, EIN);
  make_dinv<<<GRID1(NV)>>>(vv_rowp, dinv_v, NV);
  make_dinv<<<GRID1(NS)>>>(ss_rowp, dinv_s, NS);

  // ---- TAG1 (game tower) -> V0
  tag_gemm<5,false><<<GRID1((long long)NV*H)>>>(game_x, tag1_W, V0, NV);
  csr_tag_hop<5><<<GRID1(NV)>>>(vv_rowp, vv_col, dinv_v, game_x, h5b, NV);
  tag_gemm<5,true><<<GRID1((long long)NV*H)>>>(h5b, tag1_W + 1*5*H, V0, NV);
  csr_tag_hop<5><<<GRID1(NV)>>>(vv_rowp, vv_col, dinv_v, h5b, h5a, NV);
  tag_gemm<5,true><<<GRID1((long long)NV*H)>>>(h5a, tag1_W + 2*5*H, V0, NV);
  csr_tag_hop<5><<<GRID1(NV)>>>(vv_rowp, vv_col, dinv_v, h5a, h5b, NV);
  tag_gemm<5,true><<<GRID1((long long)NV*H)>>>(h5b, tag1_W + 3*5*H, V0, NV);
  bias_relu<<<GRID1((long long)NV*H)>>>(V0, tag1_b, NV);

  // ---- SAGE 0,1 on vv (in-place on V0)
  for(int layer = 0; layer < 2; layer++){
    csr_gather<<<GRIDW(NV)>>>(vv_rowp, vv_col, V0, V1, NV);
    combine128<true,true,true><<<gridFor((NV+31)/32, 1, 8192), B, 0, stream>>>(
        V0, V1, sage_Wl + (size_t)layer*H*H, sage_bl + (size_t)layer*H,
        sage_Wr + (size_t)layer*H*H, V0, NV);
  }

  // ---- TAG2 (state tower) -> S0
  tag_gemm<6,false><<<GRID1((long long)NS*H)>>>(state_x, tag2_W, S0, NS);
  csr_tag_hop<6><<<GRID1(NS)>>>(ss_rowp, ss_col, dinv_s, state_x, h6b, NS);
  tag_gemm<6,true><<<GRID1((long long)NS*H)>>>(h6b, tag2_W + 1*6*H, S0, NS);
  csr_tag_hop<6><<<GRID1(NS)>>>(ss_rowp, ss_col, dinv_s, h6b, h6a, NS);
  tag_gemm<6,true><<<GRID1((long long)NS*H)>>>(h6a, tag2_W + 2*6*H, S0, NS);
  csr_tag_hop<6><<<GRID1(NS)>>>(ss_rowp, ss_col, dinv_s, h6a, h6b, NS);
  tag_gemm<6,true><<<GRID1((long long)NS*H)>>>(h6b, tag2_W + 3*6*H, S0, NS);
  bias_relu<<<GRID1((long long)NS*H)>>>(S0, tag2_b, NS);

  // ---- SAGE 2,3 on ss (in-place on S0)
  for(int layer = 2; layer < 4; layer++){
    csr_gather<<<GRIDW(NS)>>>(ss_rowp, ss_col, S0, S1, NS);
    combine128<true,true,true><<<gridFor((NS+31)/32, 1, 8192), B, 0, stream>>>(
        S0, S1, sage_Wl + (size_t)layer*H*H, sage_bl + (size_t)layer*H,
        sage_Wr + (size_t)layer*H*H, S0, NS);
  }

  // ---- GAT (gx -> sx) : hist -> S1
  combine128<false,false,false><<<gridFor((NV+31)/32, 1, 8192), B, 0, stream>>>(
      V0, nullptr, nullptr, nullptr, gat_Wsrc, V1, NV);                 // hs = gx@Wsrc
  rowdot<<<GRIDW(NV)>>>(V1, gat_asrc, av, NV);
  combine128<false,false,false><<<gridFor((NS+31)/32, 1, 8192), B, 0, stream>>>(
      S0, nullptr, nullptr, nullptr, gat_Wdst, S1, NS);                 // hd = sx@Wdst
  rowdot<<<GRIDW(NS)>>>(S1, gat_adst, ad, NS);
  dot128<<<1, 64, 0, stream>>>(gat_We, gat_ae, cbuf);
  gat_fused<<<GRIDW(NS)>>>(eh_rowp, eh_col, eh_eid, attr_h, av, ad, cbuf,
                           V1, gat_b, S1, NS);                          // hist in S1

  // ---- SAGE4: aggregate gx over e_in, x_dst = hist (in-place on S1)
  csr_gather<<<GRIDW(NS)>>>(in_rowp, in_col, V0, S0, NS);
  combine128<true,true,true><<<gridFor((NS+31)/32, 1, 8192), B, 0, stream>>>(
      S1, S0, sage_Wl + (size_t)4*H*H, sage_bl + (size_t)4*H,
      sage_Wr + (size_t)4*H*H, S1, NS);

  // ---- SAGE 5,6 on ss (in-place on S1)
  for(int layer = 5; layer < 7; layer++){
    csr_gather<<<GRIDW(NS)>>>(ss_rowp, ss_col, S1, S0, NS);
    combine128<true,true,true><<<gridFor((NS+31)/32, 1, 8192), B, 0, stream>>>(
        S1, S0, sage_Wl + (size_t)layer*H*H, sage_bl + (size_t)layer*H,
        sage_Wr + (size_t)layer*H*H, S1, NS);
  }

  // ---- final MLP -> d_out
  mlp_out<<<GRIDW(NS)>>>(S1, mlp_W, mlp_b, out, NS);

  #undef GRID1
  #undef GRIDW
}

// Round 4
// 1685.979 us; speedup vs baseline: 3.9397x; 1.3793x over previous
//
#include <hip/hip_runtime.h>

#define H 128

// ---------------------------------------------------------------- utilities

static inline int gridFor(long long work, int block, int cap = 8192){
  long long g = (work + block - 1) / block;
  if (g > cap) g = cap;
  if (g < 1) g = 1;
  return (int)g;
}

__device__ __forceinline__ float waveAllSum(float v){
  #pragma unroll
  for(int off = 32; off > 0; off >>= 1) v += __shfl_xor(v, off);
  return v;
}
__device__ __forceinline__ float waveAllMax(float v){
  #pragma unroll
  for(int off = 32; off > 0; off >>= 1) v = fmaxf(v, __shfl_xor(v, off));
  return v;
}
__device__ __forceinline__ float waveReduceSum(float v){
  #pragma unroll
  for(int off = 32; off > 0; off >>= 1) v += __shfl_down(v, off);
  return v;
}

// ---------------------------------------------------------------- CSR build

__global__ void count_dst_i(const int* __restrict__ dst, int* __restrict__ cnt, int E){
  for(int e = blockIdx.x*blockDim.x + threadIdx.x; e < E; e += gridDim.x*blockDim.x)
    atomicAdd(&cnt[dst[e]], 1);
}

// multi-block scan: phase 1 — per-block (4096 elems) totals
__global__ __launch_bounds__(256) void scan_block_sums(const int* __restrict__ in,
                                                       int* __restrict__ bsum, int n){
  int base = blockIdx.x * 4096 + threadIdx.x * 16;
  int s = 0;
  #pragma unroll
  for(int j = 0; j < 16; j++){ int i = base + j; if(i < n) s += in[i]; }
  #pragma unroll
  for(int off = 32; off > 0; off >>= 1) s += __shfl_down(s, off);
  __shared__ int ws[4];
  if((threadIdx.x & 63) == 0) ws[threadIdx.x >> 6] = s;
  __syncthreads();
  if(threadIdx.x == 0) bsum[blockIdx.x] = ws[0] + ws[1] + ws[2] + ws[3];
}

// phase 2 — single wave exclusive-scan of block sums (nb <= 64)
__global__ void scan_top(int* __restrict__ bsum, int nb){
  int t = threadIdx.x;
  int v = (t < nb) ? bsum[t] : 0;
  int incl = v;
  #pragma unroll
  for(int off = 1; off < 64; off <<= 1){
    int u = __shfl_up(incl, off);
    if(t >= off) incl += u;
  }
  if(t < nb) bsum[t] = incl - v;
}

// phase 3 — per-block exclusive scan + block offset; last thread writes out[n]=total
__global__ __launch_bounds__(256) void scan_final(const int* __restrict__ in,
                                                  const int* __restrict__ bsum,
                                                  int* __restrict__ out, int n){
  int t = threadIdx.x;
  int base = blockIdx.x * 4096 + t * 16;
  int v[16]; int s = 0;
  #pragma unroll
  for(int j = 0; j < 16; j++){ int i = base + j; v[j] = (i < n) ? in[i] : 0; s += v[j]; }
  int lane = t & 63, wid = t >> 6;
  int incl = s;
  #pragma unroll
  for(int off = 1; off < 64; off <<= 1){
    int u = __shfl_up(incl, off);
    if(lane >= off) incl += u;
  }
  __shared__ int ws[4];
  if(lane == 63) ws[wid] = incl;
  __syncthreads();
  int wofs = 0;
  for(int wj = 0; wj < wid; wj++) wofs += ws[wj];
  int excl = bsum[blockIdx.x] + wofs + incl - s;
  #pragma unroll
  for(int j = 0; j < 16; j++){ int i = base + j; if(i < n) out[i] = excl; excl += v[j]; }
  if((int)blockIdx.x == (int)gridDim.x - 1 && t == 255) out[n] = excl;
}

__global__ void csr_fill(const int* __restrict__ src, const int* __restrict__ dst,
                         int* __restrict__ cursor, int* __restrict__ col,
                         int* __restrict__ eid, int E){
  for(int e = blockIdx.x*blockDim.x + threadIdx.x; e < E; e += gridDim.x*blockDim.x){
    int d = dst[e];
    int pos = atomicAdd(&cursor[d], 1);
    col[pos] = src[e];
    if(eid) eid[pos] = e;
  }
}

__global__ void make_dinv(const int* __restrict__ rowp, float* __restrict__ dinv, int n){
  for(int i = blockIdx.x*blockDim.x + threadIdx.x; i < n; i += gridDim.x*blockDim.x){
    int d = rowp[i+1] - rowp[i];
    dinv[i] = d > 0 ? rsqrtf((float)d) : 0.f;
  }
}

// ---------------------------------------------------------------- TAG

template<int C, bool ACC>
__global__ void tag_gemm(const float* __restrict__ h, const float* __restrict__ W,
                         float* __restrict__ out, int N){
  int total = N * H;
  for(int t = blockIdx.x*blockDim.x + threadIdx.x; t < total; t += gridDim.x*blockDim.x){
    int i = t >> 7, j = t & 127;
    float acc = ACC ? out[t] : 0.f;
    #pragma unroll
    for(int k = 0; k < C; k++) acc += h[i*C + k] * W[k*H + j];
    out[t] = acc;
  }
}

template<int C>
__global__ void csr_tag_hop(const int* __restrict__ rowp, const int* __restrict__ col,
                            const float* __restrict__ dinv, const float* __restrict__ hin,
                            float* __restrict__ hout, int N){
  for(int i = blockIdx.x*blockDim.x + threadIdx.x; i < N; i += gridDim.x*blockDim.x){
    int b = rowp[i], e = rowp[i+1];
    float dd = dinv[i];
    float acc0[C], acc1[C];
    #pragma unroll
    for(int k = 0; k < C; k++){ acc0[k] = 0.f; acc1[k] = 0.f; }
    int p = b;
    for(; p + 2 <= e; p += 2){
      int s0 = col[p], s1 = col[p+1];
      float n0 = dinv[s0] * dd, n1 = dinv[s1] * dd;
      #pragma unroll
      for(int k = 0; k < C; k++){
        acc0[k] += hin[s0*C + k] * n0;
        acc1[k] += hin[s1*C + k] * n1;
      }
    }
    if(p < e){
      int s0 = col[p];
      float n0 = dinv[s0] * dd;
      #pragma unroll
      for(int k = 0; k < C; k++) acc0[k] += hin[s0*C + k] * n0;
    }
    #pragma unroll
    for(int k = 0; k < C; k++) hout[i*C + k] = acc0[k] + acc1[k];
  }
}

__global__ void bias_relu(float* __restrict__ x, const float* __restrict__ b, int N){
  int total = N * H;
  for(int t = blockIdx.x*blockDim.x + threadIdx.x; t < total; t += gridDim.x*blockDim.x)
    x[t] = fmaxf(x[t] + b[t & 127], 0.f);
}

// ---------------------------------------------------------------- SAGE gather

// agg[i] = mean_{e: dst=i} x[src]  (wave per row, 4-deep unrolled for MLP)
__global__ void csr_gather(const int* __restrict__ rowp, const int* __restrict__ col,
                           const float* __restrict__ x, float* __restrict__ agg, int N){
  int lane = threadIdx.x & 63;
  int w = (blockIdx.x*blockDim.x + threadIdx.x) >> 6;
  int nw = (gridDim.x*blockDim.x) >> 6;
  for(int i = w; i < N; i += nw){
    int b = rowp[i], e = rowp[i+1];
    float2 a0 = make_float2(0.f,0.f), a1 = a0, a2 = a0, a3 = a0;
    int p = b;
    for(; p + 4 <= e; p += 4){
      int s0 = col[p], s1 = col[p+1], s2 = col[p+2], s3 = col[p+3];
      float2 v0 = *(const float2*)&x[(size_t)s0*H + lane*2];
      float2 v1 = *(const float2*)&x[(size_t)s1*H + lane*2];
      float2 v2 = *(const float2*)&x[(size_t)s2*H + lane*2];
      float2 v3 = *(const float2*)&x[(size_t)s3*H + lane*2];
      a0.x += v0.x; a0.y += v0.y; a1.x += v1.x; a1.y += v1.y;
      a2.x += v2.x; a2.y += v2.y; a3.x += v3.x; a3.y += v3.y;
    }
    for(; p < e; p++){
      int s = col[p];
      float2 v = *(const float2*)&x[(size_t)s*H + lane*2];
      a0.x += v.x; a0.y += v.y;
    }
    float inv = 1.f / fmaxf((float)(e - b), 1.f);
    float2 o = make_float2((a0.x+a1.x+a2.x+a3.x)*inv, (a0.y+a1.y+a2.y+a3.y)*inv);
    *(float2*)&agg[(size_t)i*H + lane*2] = o;
  }
}

// ---------------------------------------------------------------- dense combine (tiled GEMM)

// out = maybe_relu( x@Wr [+ agg@Wl] [+ bl] ).  BM=128, BN=128(all), BK=16.
// 256 threads, 8x8 micro-tile. In-place safe: block reads only its own rows,
// stores only at the very end.
template<bool HAS_AGG, bool RELU, bool BIAS>
__global__ __launch_bounds__(256) void combine_gemm(
    const float* __restrict__ x, const float* __restrict__ agg,
    const float* __restrict__ Wl, const float* __restrict__ bl,
    const float* __restrict__ Wr, float* __restrict__ out, int N){
  __shared__ float As[16][132];   // transposed A-tile, padded
  __shared__ float Bs[16][132];   // W-tile, padded

  const int tid = threadIdx.x;
  const int tc = tid & 15;        // 8-col group
  const int tr = tid >> 4;        // 8-row group
  const int base = blockIdx.x * 128;

  // A-load mapping: 128 rows x 16 k; thread -> (row ar, k-half kh)
  const int ar = tid >> 1;
  const int kh = (tid & 1) * 8;
  // B-load mapping: 16 k x 128 n
  const int bk = tid >> 4;
  const int bc = (tid & 15) * 8;

  float acc[8][8];
  #pragma unroll
  for(int r = 0; r < 8; r++)
    #pragma unroll
    for(int c = 0; c < 8; c++) acc[r][c] = 0.f;

  const int nPhase = HAS_AGG ? 2 : 1;
  for(int phase = 0; phase < nPhase; phase++){
    const float* Ap = (phase == 0) ? x : agg;
    const float* Wp = (phase == 0) ? Wr : Wl;
    for(int k0 = 0; k0 < H; k0 += 16){
      // global loads to regs
      float4 u0 = make_float4(0.f,0.f,0.f,0.f), u1 = u0;
      int arow = base + ar;
      if(arow < N){
        const float* p = &Ap[(size_t)arow*H + k0 + kh];
        u0 = *(const float4*)p;
        u1 = *(const float4*)(p + 4);
      }
      const float* q = &Wp[(size_t)(k0 + bk)*H + bc];
      float4 w0 = *(const float4*)q;
      float4 w1 = *(const float4*)(q + 4);

      __syncthreads();   // previous tile fully consumed
      As[kh+0][ar] = u0.x; As[kh+1][ar] = u0.y; As[kh+2][ar] = u0.z; As[kh+3][ar] = u0.w;
      As[kh+4][ar] = u1.x; As[kh+5][ar] = u1.y; As[kh+6][ar] = u1.z; As[kh+7][ar] = u1.w;
      *(float4*)&Bs[bk][bc]     = w0;
      *(float4*)&Bs[bk][bc + 4] = w1;
      __syncthreads();

      #pragma unroll
      for(int k = 0; k < 16; k++){
        float4 a0 = *(const float4*)&As[k][tr*8];
        float4 a1 = *(const float4*)&As[k][tr*8 + 4];
        float4 b0 = *(const float4*)&Bs[k][tc*8];
        float4 b1 = *(const float4*)&Bs[k][tc*8 + 4];
        float av[8] = {a0.x,a0.y,a0.z,a0.w,a1.x,a1.y,a1.z,a1.w};
        float bv[8] = {b0.x,b0.y,b0.z,b0.w,b1.x,b1.y,b1.z,b1.w};
        #pragma unroll
        for(int r = 0; r < 8; r++)
          #pragma unroll
          for(int c = 0; c < 8; c++)
            acc[r][c] += av[r] * bv[c];
      }
    }
  }

  float bias[8];
  #pragma unroll
  for(int c = 0; c < 8; c++) bias[c] = BIAS ? bl[tc*8 + c] : 0.f;

  #pragma unroll
  for(int r = 0; r < 8; r++){
    int row = base + tr*8 + r;
    if(row < N){
      float o[8];
      #pragma unroll
      for(int c = 0; c < 8; c++){
        float v = acc[r][c] + bias[c];
        o[c] = RELU ? fmaxf(v, 0.f) : v;
      }
      *(float4*)&out[(size_t)row*H + tc*8]     = make_float4(o[0],o[1],o[2],o[3]);
      *(float4*)&out[(size_t)row*H + tc*8 + 4] = make_float4(o[4],o[5],o[6],o[7]);
    }
  }
}

// ---------------------------------------------------------------- GAT

__global__ void rowdot(const float* __restrict__ x, const float* __restrict__ v,
                       float* __restrict__ out, int N){
  int lane = threadIdx.x & 63;
  int w = (blockIdx.x*blockDim.x + threadIdx.x) >> 6;
  int nw = (gridDim.x*blockDim.x) >> 6;
  for(int i = w; i < N; i += nw){
    float acc = x[(size_t)i*H + lane] * v[lane] + x[(size_t)i*H + 64 + lane] * v[64 + lane];
    acc = waveReduceSum(acc);
    if(lane == 0) out[i] = acc;
  }
}

__global__ void dot128(const float* __restrict__ a, const float* __restrict__ b,
                       float* __restrict__ o){
  int l = threadIdx.x;
  float acc = a[l]*b[l] + a[l+64]*b[l+64];
  acc = waveReduceSum(acc);
  if(l == 0) o[0] = acc;
}

__global__ void gat_fused(const int* __restrict__ rowp, const int* __restrict__ col,
                          const int* __restrict__ eid, const float* __restrict__ attr,
                          const float* __restrict__ av, const float* __restrict__ ad,
                          const float* __restrict__ cptr, const float* __restrict__ hs,
                          const float* __restrict__ bias, float* __restrict__ out, int N){
  const float c = cptr[0];
  int lane = threadIdx.x & 63;
  int w = (blockIdx.x*blockDim.x + threadIdx.x) >> 6;
  int nw = (gridDim.x*blockDim.x) >> 6;
  for(int i = w; i < N; i += nw){
    int b = rowp[i], e = rowp[i+1];
    float adi = ad[i];
    float amax = -3.0e38f;
    for(int p = b + lane; p < e; p += 64){
      float a = av[col[p]] + adi + attr[eid[p]] * c;
      a = a > 0.f ? a : 0.2f * a;
      amax = fmaxf(amax, a);
    }
    amax = waveAllMax(amax);
    float sume = 0.f;
    for(int p = b + lane; p < e; p += 64){
      float a = av[col[p]] + adi + attr[eid[p]] * c;
      a = a > 0.f ? a : 0.2f * a;
      sume += __expf(a - amax);
    }
    sume = waveAllSum(sume);
    float rden = 1.f / fmaxf(sume, 1e-16f);
    float2 ac0 = make_float2(0.f,0.f), ac1 = ac0;
    int p = b;
    for(; p + 2 <= e; p += 2){
      int s0 = col[p], s1 = col[p+1];
      float a0 = av[s0] + adi + attr[eid[p]] * c;
      float a1 = av[s1] + adi + attr[eid[p+1]] * c;
      a0 = a0 > 0.f ? a0 : 0.2f * a0;
      a1 = a1 > 0.f ? a1 : 0.2f * a1;
      float al0 = __expf(a0 - amax) * rden;
      float al1 = __expf(a1 - amax) * rden;
      float2 v0 = *(const float2*)&hs[(size_t)s0*H + lane*2];
      float2 v1 = *(const float2*)&hs[(size_t)s1*H + lane*2];
      ac0.x += al0 * v0.x; ac0.y += al0 * v0.y;
      ac1.x += al1 * v1.x; ac1.y += al1 * v1.y;
    }
    if(p < e){
      int s0 = col[p];
      float a0 = av[s0] + adi + attr[eid[p]] * c;
      a0 = a0 > 0.f ? a0 : 0.2f * a0;
      float al0 = __expf(a0 - amax) * rden;
      float2 v0 = *(const float2*)&hs[(size_t)s0*H + lane*2];
      ac0.x += al0 * v0.x; ac0.y += al0 * v0.y;
    }
    float2 o = make_float2(fmaxf(ac0.x + ac1.x + bias[lane*2],     0.f),
                           fmaxf(ac0.y + ac1.y + bias[lane*2 + 1], 0.f));
    *(float2*)&out[(size_t)i*H + lane*2] = o;
  }
}

__global__ void mlp_out(const float* __restrict__ x, const float* __restrict__ W,
                        const float* __restrict__ b, float* __restrict__ out, int N){
  int lane = threadIdx.x & 63;
  int w = (blockIdx.x*blockDim.x + threadIdx.x) >> 6;
  int nw = (gridDim.x*blockDim.x) >> 6;
  for(int i = w; i < N; i += nw){
    float acc = x[(size_t)i*H + lane] * W[lane] + x[(size_t)i*H + 64 + lane] * W[64 + lane];
    acc = waveReduceSum(acc);
    if(lane == 0) out[i] = acc + b[0];
  }
}

// ---------------------------------------------------------------- launch

extern "C" void kernel_launch(void* const* d_in, const int* in_sizes, int n_in,
                              void* d_out, int out_size, void* d_ws, size_t ws_size,
                              hipStream_t stream) {
  const float* game_x  = (const float*)d_in[0];
  const float* state_x = (const float*)d_in[1];
  const int*   e_vv    = (const int*)d_in[2];
  const int*   e_hist  = (const int*)d_in[4];
  const float* attr_h  = (const float*)d_in[5];
  const int*   e_in    = (const int*)d_in[6];
  const int*   e_ss    = (const int*)d_in[7];
  const float* tag1_W  = (const float*)d_in[8];
  const float* tag1_b  = (const float*)d_in[9];
  const float* tag2_W  = (const float*)d_in[10];
  const float* tag2_b  = (const float*)d_in[11];
  const float* sage_Wl = (const float*)d_in[12];
  const float* sage_bl = (const float*)d_in[13];
  const float* sage_Wr = (const float*)d_in[14];
  const float* gat_Wsrc= (const float*)d_in[15];
  const float* gat_Wdst= (const float*)d_in[16];
  const float* gat_We  = (const float*)d_in[17];
  const float* gat_asrc= (const float*)d_in[18];
  const float* gat_adst= (const float*)d_in[19];
  const float* gat_ae  = (const float*)d_in[20];
  const float* gat_b   = (const float*)d_in[21];
  const float* mlp_W   = (const float*)d_in[22];
  const float* mlp_b   = (const float*)d_in[23];
  float* out = (float*)d_out;

  const int NV  = in_sizes[0] / 5;
  const int NS  = in_sizes[1] / 6;
  const int EVV = in_sizes[2] / 2;
  const int EH  = in_sizes[4] / 2;
  const int EIN = in_sizes[6] / 2;
  const int ESS = in_sizes[7] / 2;

  const int* vv_src = e_vv;   const int* vv_dst = e_vv + EVV;
  const int* eh_src = e_hist; const int* eh_dst = e_hist + EH;
  const int* in_src = e_in;   const int* in_dst = e_in + EIN;
  const int* ss_src = e_ss;   const int* ss_dst = e_ss + ESS;

  char* wp = (char*)d_ws;
  auto alloc = [&](size_t bytes) -> void* {
    void* p = (void*)wp;
    wp += (bytes + 511) & ~size_t(511);
    return p;
  };
  float* V0 = (float*)alloc((size_t)NV*H*4);
  float* V1 = (float*)alloc((size_t)NV*H*4);
  float* S0 = (float*)alloc((size_t)NS*H*4);
  float* S1 = (float*)alloc((size_t)NS*H*4);
  float* dinv_v = (float*)alloc((size_t)NV*4);
  float* dinv_s = (float*)alloc((size_t)NS*4);
  float* av  = (float*)alloc((size_t)NV*4);
  float* ad  = (float*)alloc((size_t)NS*4);
  float* h5a = (float*)alloc((size_t)NV*5*4);
  float* h5b = (float*)alloc((size_t)NV*5*4);
  float* h6a = (float*)alloc((size_t)NS*6*4);
  float* h6b = (float*)alloc((size_t)NS*6*4);
  float* cbuf= (float*)alloc(4);
  int* vv_rowp = (int*)alloc((size_t)(NV+1)*4);
  int* vv_col  = (int*)alloc((size_t)EVV*4);
  int* vv_cur  = (int*)alloc((size_t)NV*4);
  int* ss_rowp = (int*)alloc((size_t)(NS+1)*4);
  int* ss_col  = (int*)alloc((size_t)ESS*4);
  int* ss_cur  = (int*)alloc((size_t)NS*4);
  int* eh_rowp = (int*)alloc((size_t)(NS+1)*4);
  int* eh_col  = (int*)alloc((size_t)EH*4);
  int* eh_eid  = (int*)alloc((size_t)EH*4);
  int* eh_cur  = (int*)alloc((size_t)NS*4);
  int* in_rowp = (int*)alloc((size_t)(NS+1)*4);
  int* in_col  = (int*)alloc((size_t)EIN*4);
  int* in_cur  = (int*)alloc((size_t)NS*4);
  int* bsum    = (int*)alloc(64*4);
  (void)ws_size; (void)n_in; (void)out_size;

  const int B = 256;
  #define GRID1(n) gridFor((long long)(n), B), B, 0, stream
  #define GRIDW(e) gridFor((long long)(e) * 64, B, 8192), B, 0, stream
  #define GEMM(n)  ((n) + 127) / 128, 256, 0, stream

  auto scan = [&](int* cnt, int* rowp, int n){
    int nb = (n + 4095) / 4096;
    scan_block_sums<<<nb, 256, 0, stream>>>(cnt, bsum, n);
    scan_top<<<1, 64, 0, stream>>>(bsum, nb);
    scan_final<<<nb, 256, 0, stream>>>(cnt, bsum, rowp, n);
  };

  // ---- build 4 CSRs
  hipMemsetAsync(vv_cur, 0, (size_t)NV*4, stream);
  hipMemsetAsync(ss_cur, 0, (size_t)NS*4, stream);
  hipMemsetAsync(eh_cur, 0, (size_t)NS*4, stream);
  hipMemsetAsync(in_cur, 0, (size_t)NS*4, stream);
  count_dst_i<<<GRID1(EVV)>>>(vv_dst, vv_cur, EVV);
  count_dst_i<<<GRID1(ESS)>>>(ss_dst, ss_cur, ESS);
  count_dst_i<<<GRID1(EH)>>>(eh_dst, eh_cur, EH);
  count_dst_i<<<GRID1(EIN)>>>(in_dst, in_cur, EIN);
  scan(vv_cur, vv_rowp, NV);
  scan(ss_cur, ss_rowp, NS);
  scan(eh_cur, eh_rowp, NS);
  scan(in_cur, in_rowp, NS);
  hipMemcpyAsync(vv_cur, vv_rowp, (size_t)NV*4, hipMemcpyDeviceToDevice, stream);
  hipMemcpyAsync(ss_cur, ss_rowp, (size_t)NS*4, hipMemcpyDeviceToDevice, stream);
  hipMemcpyAsync(eh_cur, eh_rowp, (size_t)NS*4, hipMemcpyDeviceToDevice, stream);
  hipMemcpyAsync(in_cur, in_rowp, (size_t)NS*4, hipMemcpyDeviceToDevice, stream);
  csr_fill<<<GRID1(EVV)>>>(vv_src, vv_dst, vv_cur, vv_col, nullptr, EVV);
  csr_fill<<<GRID1(ESS)>>>(ss_src, ss_dst, ss_cur, ss_col, nullptr, ESS);
  csr_fill<<<GRID1(EH)>>>(eh_src, eh_dst, eh_cur, eh_col, eh_eid, EH);
  csr_fill<<<GRID1(EIN)>>>(in_src, in_dst, in_cur, in_col, nullptr, EIN);
  make_dinv<<<GRID1(NV)>>>(vv_rowp, dinv_v, NV);
  make_dinv<<<GRID1(NS)>>>(ss_rowp, dinv_s, NS);

  // ---- TAG1 (game tower) -> V0
  tag_gemm<5,false><<<GRID1((long long)NV*H)>>>(game_x, tag1_W, V0, NV);
  csr_tag_hop<5><<<GRID1(NV)>>>(vv_rowp, vv_col, dinv_v, game_x, h5b, NV);
  tag_gemm<5,true><<<GRID1((long long)NV*H)>>>(h5b, tag1_W + 1*5*H, V0, NV);
  csr_tag_hop<5><<<GRID1(NV)>>>(vv_rowp, vv_col, dinv_v, h5b, h5a, NV);
  tag_gemm<5,true><<<GRID1((long long)NV*H)>>>(h5a, tag1_W + 2*5*H, V0, NV);
  csr_tag_hop<5><<<GRID1(NV)>>>(vv_rowp, vv_col, dinv_v, h5a, h5b, NV);
  tag_gemm<5,true><<<GRID1((long long)NV*H)>>>(h5b, tag1_W + 3*5*H, V0, NV);
  bias_relu<<<GRID1((long long)NV*H)>>>(V0, tag1_b, NV);

  // ---- SAGE 0,1 on vv (in-place on V0)
  for(int layer = 0; layer < 2; layer++){
    csr_gather<<<GRIDW(NV)>>>(vv_rowp, vv_col, V0, V1, NV);
    combine_gemm<true,true,true><<<GEMM(NV)>>>(
        V0, V1, sage_Wl + (size_t)layer*H*H, sage_bl + (size_t)layer*H,
        sage_Wr + (size_t)layer*H*H, V0, NV);
  }

  // ---- TAG2 (state tower) -> S0
  tag_gemm<6,false><<<GRID1((long long)NS*H)>>>(state_x, tag2_W, S0, NS);
  csr_tag_hop<6><<<GRID1(NS)>>>(ss_rowp, ss_col, dinv_s, state_x, h6b, NS);
  tag_gemm<6,true><<<GRID1((long long)NS*H)>>>(h6b, tag2_W + 1*6*H, S0, NS);
  csr_tag_hop<6><<<GRID1(NS)>>>(ss_rowp, ss_col, dinv_s, h6b, h6a, NS);
  tag_gemm<6,true><<<GRID1((long long)NS*H)>>>(h6a, tag2_W + 2*6*H, S0, NS);
  csr_tag_hop<6><<<GRID1(NS)>>>(ss_rowp, ss_col, dinv_s, h6a, h6b, NS);
  tag_gemm<6,true><<<GRID1((long long)NS*H)>>>(h6b, tag2_W + 3*6*H, S0, NS);
  bias_relu<<<GRID1((long long)NS*H)>>>(S0, tag2_b, NS);

  // ---- SAGE 2,3 on ss (in-place on S0)
  for(int layer = 2; layer < 4; layer++){
    csr_gather<<<GRIDW(NS)>>>(ss_rowp, ss_col, S0, S1, NS);
    combine_gemm<true,true,true><<<GEMM(NS)>>>(
        S0, S1, sage_Wl + (size_t)layer*H*H, sage_bl + (size_t)layer*H,
        sage_Wr + (size_t)layer*H*H, S0, NS);
  }

  // ---- GAT (gx -> sx) : hist -> S1
  combine_gemm<false,false,false><<<GEMM(NV)>>>(
      V0, nullptr, nullptr, nullptr, gat_Wsrc, V1, NV);                 // hs = gx@Wsrc
  rowdot<<<GRIDW(NV)>>>(V1, gat_asrc, av, NV);
  combine_gemm<false,false,false><<<GEMM(NS)>>>(
      S0, nullptr, nullptr, nullptr, gat_Wdst, S1, NS);                 // hd = sx@Wdst
  rowdot<<<GRIDW(NS)>>>(S1, gat_adst, ad, NS);
  dot128<<<1, 64, 0, stream>>>(gat_We, gat_ae, cbuf);
  gat_fused<<<GRIDW(NS)>>>(eh_rowp, eh_col, eh_eid, attr_h, av, ad, cbuf,
                           V1, gat_b, S1, NS);                          // hist in S1

  // ---- SAGE4: aggregate gx over e_in, x_dst = hist (in-place on S1)
  csr_gather<<<GRIDW(NS)>>>(in_rowp, in_col, V0, S0, NS);
  combine_gemm<true,true,true><<<GEMM(NS)>>>(
      S1, S0, sage_Wl + (size_t)4*H*H, sage_bl + (size_t)4*H,
      sage_Wr + (size_t)4*H*H, S1, NS);

  // ---- SAGE 5,6 on ss (in-place on S1)
  for(int layer = 5; layer < 7; layer++){
    csr_gather<<<GRIDW(NS)>>>(ss_rowp, ss_col, S1, S0, NS);
    combine_gemm<true,true,true><<<GEMM(NS)>>>(
        S1, S0, sage_Wl + (size_t)layer*H*H, sage_bl + (size_t)layer*H,
        sage_Wr + (size_t)layer*H*H, S1, NS);
  }

  // ---- final MLP -> d_out
  mlp_out<<<GRIDW(NS)>>>(S1, mlp_W, mlp_b, out, NS);

  #undef GRID1
  #undef GRIDW
  #undef GEMM
}

// Round 5
// 1262.138 us; speedup vs baseline: 5.2627x; 1.3358x over previous
//
#include <hip/hip_runtime.h>

#define H 128
typedef unsigned short u16;
typedef __attribute__((ext_vector_type(8))) short bf16x8;
typedef __attribute__((ext_vector_type(4))) float f32x4;

// ---------------------------------------------------------------- utilities

static inline int gridFor(long long work, int block, int cap = 8192){
  long long g = (work + block - 1) / block;
  if (g > cap) g = cap;
  if (g < 1) g = 1;
  return (int)g;
}

__device__ __forceinline__ float waveReduceSum(float v){
  #pragma unroll
  for(int off = 32; off > 0; off >>= 1) v += __shfl_down(v, off);
  return v;
}

__device__ __forceinline__ float bflo(unsigned v){ return __uint_as_float(v << 16); }
__device__ __forceinline__ float bfhi(unsigned v){ return __uint_as_float(v & 0xffff0000u); }
__device__ __forceinline__ u16 f2bf(float f){
  unsigned u = __float_as_uint(f);
  return (u16)((u + 0x7fffu + ((u >> 16) & 1u)) >> 16);
}
__device__ __forceinline__ unsigned pack2(float lo, float hi){
  return (unsigned)f2bf(lo) | ((unsigned)f2bf(hi) << 16);
}

// ---------------------------------------------------------------- CSR build

__global__ void count_dst_i(const int* __restrict__ dst, int* __restrict__ cnt, int E){
  for(int e = blockIdx.x*blockDim.x + threadIdx.x; e < E; e += gridDim.x*blockDim.x)
    atomicAdd(&cnt[dst[e]], 1);
}

__global__ __launch_bounds__(256) void scan_block_sums(const int* __restrict__ in,
                                                       int* __restrict__ bsum, int n){
  int base = blockIdx.x * 4096 + threadIdx.x * 16;
  int s = 0;
  #pragma unroll
  for(int j = 0; j < 16; j++){ int i = base + j; if(i < n) s += in[i]; }
  #pragma unroll
  for(int off = 32; off > 0; off >>= 1) s += __shfl_down(s, off);
  __shared__ int ws[4];
  if((threadIdx.x & 63) == 0) ws[threadIdx.x >> 6] = s;
  __syncthreads();
  if(threadIdx.x == 0) bsum[blockIdx.x] = ws[0] + ws[1] + ws[2] + ws[3];
}

__global__ void scan_top(int* __restrict__ bsum, int nb){
  int t = threadIdx.x;
  int v = (t < nb) ? bsum[t] : 0;
  int incl = v;
  #pragma unroll
  for(int off = 1; off < 64; off <<= 1){
    int u = __shfl_up(incl, off);
    if(t >= off) incl += u;
  }
  if(t < nb) bsum[t] = incl - v;
}

__global__ __launch_bounds__(256) void scan_final(const int* __restrict__ in,
                                                  const int* __restrict__ bsum,
                                                  int* __restrict__ out, int n){
  int t = threadIdx.x;
  int base = blockIdx.x * 4096 + t * 16;
  int v[16]; int s = 0;
  #pragma unroll
  for(int j = 0; j < 16; j++){ int i = base + j; v[j] = (i < n) ? in[i] : 0; s += v[j]; }
  int lane = t & 63, wid = t >> 6;
  int incl = s;
  #pragma unroll
  for(int off = 1; off < 64; off <<= 1){
    int u = __shfl_up(incl, off);
    if(lane >= off) incl += u;
  }
  __shared__ int ws[4];
  if(lane == 63) ws[wid] = incl;
  __syncthreads();
  int wofs = 0;
  for(int wj = 0; wj < wid; wj++) wofs += ws[wj];
  int excl = bsum[blockIdx.x] + wofs + incl - s;
  #pragma unroll
  for(int j = 0; j < 16; j++){ int i = base + j; if(i < n) out[i] = excl; excl += v[j]; }
  if((int)blockIdx.x == (int)gridDim.x - 1 && t == 255) out[n] = excl;
}

__global__ void csr_fill(const int* __restrict__ src, const int* __restrict__ dst,
                         int* __restrict__ cursor, int* __restrict__ col,
                         const float* __restrict__ attr, float* __restrict__ attrp, int E){
  for(int e = blockIdx.x*blockDim.x + threadIdx.x; e < E; e += gridDim.x*blockDim.x){
    int d = dst[e];
    int pos = atomicAdd(&cursor[d], 1);
    col[pos] = src[e];
    if(attr) attrp[pos] = attr[e];
  }
}

__global__ void make_dinv(const int* __restrict__ rowp, float* __restrict__ dinv, int n){
  for(int i = blockIdx.x*blockDim.x + threadIdx.x; i < n; i += gridDim.x*blockDim.x){
    int d = rowp[i+1] - rowp[i];
    dinv[i] = d > 0 ? rsqrtf((float)d) : 0.f;
  }
}

// ---------------------------------------------------------------- weights to bf16 frag-major

// 15 mats of 128x128: 0-6 sage_Wl, 7-13 sage_Wr, 14 gat_Wsrc.
// Wb[mat][col*H + k] = W[mat][k*H + col]
__global__ void cvt_weights(const float* __restrict__ Wl, const float* __restrict__ Wr,
                            const float* __restrict__ Wsrc, u16* __restrict__ Wb){
  const int total = 15 * H * H;
  for(int t = blockIdx.x*blockDim.x + threadIdx.x; t < total; t += gridDim.x*blockDim.x){
    int mat = t >> 14, idx = t & 16383;
    int k = idx >> 7, colj = idx & 127;
    const float* srcp = (mat < 7) ? (Wl + ((size_t)mat << 14))
                       : (mat < 14) ? (Wr + ((size_t)(mat - 7) << 14))
                       : Wsrc;
    Wb[((size_t)mat << 14) + (size_t)colj*H + k] = f2bf(srcp[idx]);
  }
}

// outv[k] = sum_j W[k][j] * a[j]   (128x128)
__global__ void mat_vec_row(const float* __restrict__ W, const float* __restrict__ a,
                            float* __restrict__ outv){
  int k = threadIdx.x;
  if(k < H){
    float s = 0.f;
    for(int j = 0; j < H; j++) s += W[(size_t)k*H + j] * a[j];
    outv[k] = s;
  }
}

__global__ void dot128(const float* __restrict__ a, const float* __restrict__ b,
                       float* __restrict__ o){
  int l = threadIdx.x;
  float acc = a[l]*b[l] + a[l+64]*b[l+64];
  acc = waveReduceSum(acc);
  if(l == 0) o[0] = acc;
}

// ---------------------------------------------------------------- TAG

// hout[i*sout + k] = sum_{e: dst=i} hin[src*sin + k] * dinv[src]*dinv[i]
template<int C>
__global__ void csr_tag_hop(const int* __restrict__ rowp, const int* __restrict__ col,
                            const float* __restrict__ dinv,
                            const float* __restrict__ hin, int sin,
                            float* __restrict__ hout, int sout, int N){
  for(int i = blockIdx.x*blockDim.x + threadIdx.x; i < N; i += gridDim.x*blockDim.x){
    int b = rowp[i], e = rowp[i+1];
    float dd = dinv[i];
    float acc0[C], acc1[C];
    #pragma unroll
    for(int k = 0; k < C; k++){ acc0[k] = 0.f; acc1[k] = 0.f; }
    int p = b;
    for(; p + 2 <= e; p += 2){
      int s0 = col[p], s1 = col[p+1];
      float n0 = dinv[s0] * dd, n1 = dinv[s1] * dd;
      #pragma unroll
      for(int k = 0; k < C; k++){
        acc0[k] += hin[(size_t)s0*sin + k] * n0;
        acc1[k] += hin[(size_t)s1*sin + k] * n1;
      }
    }
    if(p < e){
      int s0 = col[p];
      float n0 = dinv[s0] * dd;
      #pragma unroll
      for(int k = 0; k < C; k++) acc0[k] += hin[(size_t)s0*sin + k] * n0;
    }
    #pragma unroll
    for(int k = 0; k < C; k++) hout[(size_t)i*sout + k] = acc0[k] + acc1[k];
  }
}

// out = relu( concat(x_i, hcat_i) @ W + b ), W = [(K+1)*C][H] flat; out bf16
template<int C>
__global__ __launch_bounds__(256) void tag_fuse(
    const float* __restrict__ x, const float* __restrict__ hcat,
    const float* __restrict__ W, const float* __restrict__ bias,
    u16* __restrict__ out, int N){
  __shared__ float Ws[4*C*H];
  for(int u = threadIdx.x; u < 4*C*H; u += 256) Ws[u] = W[u];
  __syncthreads();
  const long long total = (long long)N * H;
  for(long long t = (long long)blockIdx.x*blockDim.x + threadIdx.x; t < total;
      t += (long long)gridDim.x*blockDim.x){
    int i = (int)(t >> 7), j = (int)(t & 127);
    const float* xr = x + (size_t)i*C;
    const float* hr = hcat + (size_t)i*3*C;
    float acc = bias[j];
    #pragma unroll
    for(int k = 0; k < C; k++) acc += xr[k] * Ws[k*H + j];
    #pragma unroll
    for(int k = 0; k < 3*C; k++) acc += hr[k] * Ws[(C + k)*H + j];
    out[t] = f2bf(fmaxf(acc, 0.f));
  }
}

// ---------------------------------------------------------------- SAGE gather (bf16)

// agg[i] = mean_{e: dst=i} x[src]  (wave per row, 2 bf16 cols per lane)
__global__ void csr_gather(const int* __restrict__ rowp, const int* __restrict__ col,
                           const u16* __restrict__ x, u16* __restrict__ agg, int N){
  int lane = threadIdx.x & 63;
  int w = (blockIdx.x*blockDim.x + threadIdx.x) >> 6;
  int nw = (gridDim.x*blockDim.x) >> 6;
  for(int i = w; i < N; i += nw){
    int b = rowp[i], e = rowp[i+1];
    float x0=0.f, y0=0.f, x1=0.f, y1=0.f, x2=0.f, y2=0.f, x3=0.f, y3=0.f;
    int p = b;
    for(; p + 4 <= e; p += 4){
      int s0 = col[p], s1 = col[p+1], s2 = col[p+2], s3 = col[p+3];
      unsigned v0 = *(const unsigned*)&x[(size_t)s0*H + lane*2];
      unsigned v1 = *(const unsigned*)&x[(size_t)s1*H + lane*2];
      unsigned v2 = *(const unsigned*)&x[(size_t)s2*H + lane*2];
      unsigned v3 = *(const unsigned*)&x[(size_t)s3*H + lane*2];
      x0 += bflo(v0); y0 += bfhi(v0); x1 += bflo(v1); y1 += bfhi(v1);
      x2 += bflo(v2); y2 += bfhi(v2); x3 += bflo(v3); y3 += bfhi(v3);
    }
    for(; p < e; p++){
      unsigned v = *(const unsigned*)&x[(size_t)col[p]*H + lane*2];
      x0 += bflo(v); y0 += bfhi(v);
    }
    float inv = 1.f / fmaxf((float)(e - b), 1.f);
    *(unsigned*)&agg[(size_t)i*H + lane*2] = pack2((x0+x1+x2+x3)*inv, (y0+y1+y2+y3)*inv);
  }
}

// ---------------------------------------------------------------- MFMA combine

// out = maybe_relu( x@Wr [+ agg@Wl] [+ bl] ) in bf16, f32 accumulate.
// Wave owns 16 rows x 128 cols. Wb*: frag-major bf16 [col][k].
// A-frag: lane holds x[m0+(l&15)][k0+(l>>4)*8 + 0..7]. B-frag: Wb[c][k0+(l>>4)*8+0..7].
// C/D: col=lane&15, row=(lane>>4)*4+reg  [verified layout].
template<bool HAS_AGG, bool RELU, bool BIAS>
__global__ __launch_bounds__(256) void combine_mfma(
    const u16* __restrict__ x, const u16* __restrict__ agg,
    const u16* __restrict__ WbR, const u16* __restrict__ WbL,
    const float* __restrict__ bl, u16* __restrict__ out, int N){
  const int lane = threadIdx.x & 63;
  const int wid = blockIdx.x * 4 + (threadIdx.x >> 6);
  const int m0 = wid * 16;
  if(m0 >= N) return;
  const int r16 = lane & 15;
  const int kg = (lane >> 4) * 8;
  const size_t arow = (size_t)(m0 + r16) * H + kg;

  f32x4 acc[8];
  #pragma unroll
  for(int t = 0; t < 8; t++) acc[t] = (f32x4){0.f, 0.f, 0.f, 0.f};

  #pragma unroll
  for(int phase = 0; phase < (HAS_AGG ? 2 : 1); phase++){
    const u16* Ap = phase ? agg : x;
    const u16* Wp = phase ? WbL : WbR;
    #pragma unroll
    for(int k0 = 0; k0 < H; k0 += 32){
      bf16x8 af = *(const bf16x8*)&Ap[arow + k0];
      #pragma unroll
      for(int t = 0; t < 8; t++){
        bf16x8 bf = *(const bf16x8*)&Wp[(size_t)(t*16 + r16)*H + k0 + kg];
        acc[t] = __builtin_amdgcn_mfma_f32_16x16x32_bf16(af, bf, acc[t], 0, 0, 0);
      }
    }
  }

  const int orow = m0 + (lane >> 4) * 4;
  #pragma unroll
  for(int t = 0; t < 8; t++){
    int c = t*16 + r16;
    float bb = BIAS ? bl[c] : 0.f;
    #pragma unroll
    for(int r = 0; r < 4; r++){
      float v = acc[t][r] + bb;
      if(RELU) v = fmaxf(v, 0.f);
      out[(size_t)(orow + r)*H + c] = f2bf(v);
    }
  }
}

// ---------------------------------------------------------------- GAT

// out[i] = dot(x_bf16[i,:], v_f32)
__global__ void rowdot_bf(const u16* __restrict__ x, const float* __restrict__ v,
                          float* __restrict__ out, int N){
  int lane = threadIdx.x & 63;
  int w = (blockIdx.x*blockDim.x + threadIdx.x) >> 6;
  int nw = (gridDim.x*blockDim.x) >> 6;
  for(int i = w; i < N; i += nw){
    unsigned u = *(const unsigned*)&x[(size_t)i*H + lane*2];
    float acc = bflo(u)*v[lane*2] + bfhi(u)*v[lane*2 + 1];
    acc = waveReduceSum(acc);
    if(lane == 0) out[i] = acc;
  }
}

// single pass: out[i] = relu( (sum_e e_p*hs[src]) / max(sum_e e_p,1e-16) + bias )
__global__ void gat_fused(const int* __restrict__ rowp, const int* __restrict__ colv,
                          const float* __restrict__ attrp, const float* __restrict__ av,
                          const float* __restrict__ ad, const float* __restrict__ cptr,
                          const u16* __restrict__ hs, const float* __restrict__ bias,
                          u16* __restrict__ out, int N){
  const float c = cptr[0];
  int lane = threadIdx.x & 63;
  int w = (blockIdx.x*blockDim.x + threadIdx.x) >> 6;
  int nw = (gridDim.x*blockDim.x) >> 6;
  for(int i = w; i < N; i += nw){
    int b = rowp[i], e = rowp[i+1];
    float adi = ad[i];
    float accx0 = 0.f, accy0 = 0.f, accx1 = 0.f, accy1 = 0.f;
    float sume = 0.f;
    int p = b;
    for(; p + 2 <= e; p += 2){
      int s0 = colv[p], s1 = colv[p+1];
      float a0 = av[s0] + adi + attrp[p] * c;
      float a1 = av[s1] + adi + attrp[p+1] * c;
      a0 = a0 > 0.f ? a0 : 0.2f * a0;
      a1 = a1 > 0.f ? a1 : 0.2f * a1;
      float e0 = __expf(a0), e1 = __expf(a1);
      unsigned v0 = *(const unsigned*)&hs[(size_t)s0*H + lane*2];
      unsigned v1 = *(const unsigned*)&hs[(size_t)s1*H + lane*2];
      accx0 += e0 * bflo(v0); accy0 += e0 * bfhi(v0);
      accx1 += e1 * bflo(v1); accy1 += e1 * bfhi(v1);
      sume += e0 + e1;
    }
    if(p < e){
      int s0 = colv[p];
      float a0 = av[s0] + adi + attrp[p] * c;
      a0 = a0 > 0.f ? a0 : 0.2f * a0;
      float e0 = __expf(a0);
      unsigned v0 = *(const unsigned*)&hs[(size_t)s0*H + lane*2];
      accx0 += e0 * bflo(v0); accy0 += e0 * bfhi(v0);
      sume += e0;
    }
    float rd = 1.f / fmaxf(sume, 1e-16f);
    float ox = fmaxf((accx0 + accx1) * rd + bias[lane*2],     0.f);
    float oy = fmaxf((accy0 + accy1) * rd + bias[lane*2 + 1], 0.f);
    *(unsigned*)&out[(size_t)i*H + lane*2] = pack2(ox, oy);
  }
}

__global__ void mlp_out_bf(const u16* __restrict__ x, const float* __restrict__ W,
                           const float* __restrict__ b, float* __restrict__ out, int N){
  int lane = threadIdx.x & 63;
  int w = (blockIdx.x*blockDim.x + threadIdx.x) >> 6;
  int nw = (gridDim.x*blockDim.x) >> 6;
  for(int i = w; i < N; i += nw){
    unsigned u = *(const unsigned*)&x[(size_t)i*H + lane*2];
    float acc = bflo(u)*W[lane*2] + bfhi(u)*W[lane*2 + 1];
    acc = waveReduceSum(acc);
    if(lane == 0) out[i] = acc + b[0];
  }
}

// ---------------------------------------------------------------- launch

extern "C" void kernel_launch(void* const* d_in, const int* in_sizes, int n_in,
                              void* d_out, int out_size, void* d_ws, size_t ws_size,
                              hipStream_t stream) {
  const float* game_x  = (const float*)d_in[0];
  const float* state_x = (const float*)d_in[1];
  const int*   e_vv    = (const int*)d_in[2];
  const int*   e_hist  = (const int*)d_in[4];
  const float* attr_h  = (const float*)d_in[5];
  const int*   e_in    = (const int*)d_in[6];
  const int*   e_ss    = (const int*)d_in[7];
  const float* tag1_W  = (const float*)d_in[8];
  const float* tag1_b  = (const float*)d_in[9];
  const float* tag2_W  = (const float*)d_in[10];
  const float* tag2_b  = (const float*)d_in[11];
  const float* sage_Wl = (const float*)d_in[12];
  const float* sage_bl = (const float*)d_in[13];
  const float* sage_Wr = (const float*)d_in[14];
  const float* gat_Wsrc= (const float*)d_in[15];
  const float* gat_Wdst= (const float*)d_in[16];
  const float* gat_We  = (const float*)d_in[17];
  const float* gat_asrc= (const float*)d_in[18];
  const float* gat_adst= (const float*)d_in[19];
  const float* gat_ae  = (const float*)d_in[20];
  const float* gat_b   = (const float*)d_in[21];
  const float* mlp_W   = (const float*)d_in[22];
  const float* mlp_b   = (const float*)d_in[23];
  float* out = (float*)d_out;

  const int NV  = in_sizes[0] / 5;
  const int NS  = in_sizes[1] / 6;
  const int EVV = in_sizes[2] / 2;
  const int EH  = in_sizes[4] / 2;
  const int EIN = in_sizes[6] / 2;
  const int ESS = in_sizes[7] / 2;

  const int* vv_src = e_vv;   const int* vv_dst = e_vv + EVV;
  const int* eh_src = e_hist; const int* eh_dst = e_hist + EH;
  const int* in_src = e_in;   const int* in_dst = e_in + EIN;
  const int* ss_src = e_ss;   const int* ss_dst = e_ss + ESS;

  char* wp = (char*)d_ws;
  auto alloc = [&](size_t bytes) -> void* {
    void* p = (void*)wp;
    wp += (bytes + 511) & ~size_t(511);
    return p;
  };
  u16* V0 = (u16*)alloc((size_t)NV*H*2);
  u16* V1 = (u16*)alloc((size_t)NV*H*2);
  u16* S0 = (u16*)alloc((size_t)NS*H*2);
  u16* S1 = (u16*)alloc((size_t)NS*H*2);
  u16* Wb = (u16*)alloc((size_t)15*H*H*2);
  float* dinv_v = (float*)alloc((size_t)NV*4);
  float* dinv_s = (float*)alloc((size_t)NS*4);
  float* av   = (float*)alloc((size_t)NV*4);
  float* ad   = (float*)alloc((size_t)NS*4);
  float* hcat5= (float*)alloc((size_t)NV*15*4);
  float* hcat6= (float*)alloc((size_t)NS*18*4);
  float* wvec = (float*)alloc(H*4);
  float* cbuf = (float*)alloc(4);
  int* vv_rowp = (int*)alloc((size_t)(NV+1)*4);
  int* vv_col  = (int*)alloc((size_t)EVV*4);
  int* vv_cur  = (int*)alloc((size_t)NV*4);
  int* ss_rowp = (int*)alloc((size_t)(NS+1)*4);
  int* ss_col  = (int*)alloc((size_t)ESS*4);
  int* ss_cur  = (int*)alloc((size_t)NS*4);
  int* eh_rowp = (int*)alloc((size_t)(NS+1)*4);
  int* eh_col  = (int*)alloc((size_t)EH*4);
  float* eh_attr = (float*)alloc((size_t)EH*4);
  int* eh_cur  = (int*)alloc((size_t)NS*4);
  int* in_rowp = (int*)alloc((size_t)(NS+1)*4);
  int* in_col  = (int*)alloc((size_t)EIN*4);
  int* in_cur  = (int*)alloc((size_t)NS*4);
  int* bsum    = (int*)alloc(64*4);
  (void)ws_size; (void)n_in; (void)out_size;

  const int B = 256;
  #define GRID1(n) gridFor((long long)(n), B), B, 0, stream
  #define GRIDW(e) gridFor((long long)(e) * 64, B, 8192), B, 0, stream
  #define GEMM(n)  ((n) + 63) / 64, 256, 0, stream

  auto scan = [&](int* cnt, int* rowp, int n){
    int nb = (n + 4095) / 4096;
    scan_block_sums<<<nb, 256, 0, stream>>>(cnt, bsum, n);
    scan_top<<<1, 64, 0, stream>>>(bsum, nb);
    scan_final<<<nb, 256, 0, stream>>>(cnt, bsum, rowp, n);
  };

  // ---- build 4 CSRs
  hipMemsetAsync(vv_cur, 0, (size_t)NV*4, stream);
  hipMemsetAsync(ss_cur, 0, (size_t)NS*4, stream);
  hipMemsetAsync(eh_cur, 0, (size_t)NS*4, stream);
  hipMemsetAsync(in_cur, 0, (size_t)NS*4, stream);
  count_dst_i<<<GRID1(EVV)>>>(vv_dst, vv_cur, EVV);
  count_dst_i<<<GRID1(ESS)>>>(ss_dst, ss_cur, ESS);
  count_dst_i<<<GRID1(EH)>>>(eh_dst, eh_cur, EH);
  count_dst_i<<<GRID1(EIN)>>>(in_dst, in_cur, EIN);
  scan(vv_cur, vv_rowp, NV);
  scan(ss_cur, ss_rowp, NS);
  scan(eh_cur, eh_rowp, NS);
  scan(in_cur, in_rowp, NS);
  hipMemcpyAsync(vv_cur, vv_rowp, (size_t)NV*4, hipMemcpyDeviceToDevice, stream);
  hipMemcpyAsync(ss_cur, ss_rowp, (size_t)NS*4, hipMemcpyDeviceToDevice, stream);
  hipMemcpyAsync(eh_cur, eh_rowp, (size_t)NS*4, hipMemcpyDeviceToDevice, stream);
  hipMemcpyAsync(in_cur, in_rowp, (size_t)NS*4, hipMemcpyDeviceToDevice, stream);
  csr_fill<<<GRID1(EVV)>>>(vv_src, vv_dst, vv_cur, vv_col, nullptr, nullptr, EVV);
  csr_fill<<<GRID1(ESS)>>>(ss_src, ss_dst, ss_cur, ss_col, nullptr, nullptr, ESS);
  csr_fill<<<GRID1(EH)>>>(eh_src, eh_dst, eh_cur, eh_col, attr_h, eh_attr, EH);
  csr_fill<<<GRID1(EIN)>>>(in_src, in_dst, in_cur, in_col, nullptr, nullptr, EIN);
  make_dinv<<<GRID1(NV)>>>(vv_rowp, dinv_v, NV);
  make_dinv<<<GRID1(NS)>>>(ss_rowp, dinv_s, NS);

  // ---- weight prep
  cvt_weights<<<GRID1(15*H*H)>>>(sage_Wl, sage_Wr, gat_Wsrc, Wb);
  mat_vec_row<<<1, 128, 0, stream>>>(gat_Wdst, gat_adst, wvec);
  dot128<<<1, 64, 0, stream>>>(gat_We, gat_ae, cbuf);

  #define WBL(l) (Wb + ((size_t)(l) << 14))
  #define WBR(l) (Wb + ((size_t)(7 + (l)) << 14))

  // ---- TAG1 (game tower) -> V0 bf16
  csr_tag_hop<5><<<GRID1(NV)>>>(vv_rowp, vv_col, dinv_v, game_x, 5, hcat5 + 0, 15, NV);
  csr_tag_hop<5><<<GRID1(NV)>>>(vv_rowp, vv_col, dinv_v, hcat5 + 0, 15, hcat5 + 5, 15, NV);
  csr_tag_hop<5><<<GRID1(NV)>>>(vv_rowp, vv_col, dinv_v, hcat5 + 5, 15, hcat5 + 10, 15, NV);
  tag_fuse<5><<<GRID1((long long)NV*H)>>>(game_x, hcat5, tag1_W, tag1_b, V0, NV);

  // ---- SAGE 0,1 on vv (in-place on V0)
  for(int l = 0; l < 2; l++){
    csr_gather<<<GRIDW(NV)>>>(vv_rowp, vv_col, V0, V1, NV);
    combine_mfma<true,true,true><<<GEMM(NV)>>>(V0, V1, WBR(l), WBL(l),
                                               sage_bl + (size_t)l*H, V0, NV);
  }

  // ---- TAG2 (state tower) -> S0 bf16
  csr_tag_hop<6><<<GRID1(NS)>>>(ss_rowp, ss_col, dinv_s, state_x, 6, hcat6 + 0, 18, NS);
  csr_tag_hop<6><<<GRID1(NS)>>>(ss_rowp, ss_col, dinv_s, hcat6 + 0, 18, hcat6 + 6, 18, NS);
  csr_tag_hop<6><<<GRID1(NS)>>>(ss_rowp, ss_col, dinv_s, hcat6 + 6, 18, hcat6 + 12, 18, NS);
  tag_fuse<6><<<GRID1((long long)NS*H)>>>(state_x, hcat6, tag2_W, tag2_b, S0, NS);

  // ---- SAGE 2,3 on ss (in-place on S0)
  for(int l = 2; l < 4; l++){
    csr_gather<<<GRIDW(NS)>>>(ss_rowp, ss_col, S0, S1, NS);
    combine_mfma<true,true,true><<<GEMM(NS)>>>(S0, S1, WBR(l), WBL(l),
                                               sage_bl + (size_t)l*H, S0, NS);
  }

  // ---- GAT (gx -> sx) : hist -> S1
  combine_mfma<false,false,false><<<GEMM(NV)>>>(V0, nullptr, Wb + ((size_t)14 << 14),
                                                nullptr, nullptr, V1, NV);  // hs
  rowdot_bf<<<GRIDW(NV)>>>(V1, gat_asrc, av, NV);
  rowdot_bf<<<GRIDW(NS)>>>(S0, wvec, ad, NS);   // ad = sx @ (Wdst@adst)
  gat_fused<<<GRIDW(NS)>>>(eh_rowp, eh_col, eh_attr, av, ad, cbuf, V1, gat_b, S1, NS);

  // ---- SAGE4: aggregate gx over e_in, x_dst = hist (in-place on S1)
  csr_gather<<<GRIDW(NS)>>>(in_rowp, in_col, V0, S0, NS);
  combine_mfma<true,true,true><<<GEMM(NS)>>>(S1, S0, WBR(4), WBL(4),
                                             sage_bl + (size_t)4*H, S1, NS);

  // ---- SAGE 5,6 on ss (in-place on S1)
  for(int l = 5; l < 7; l++){
    csr_gather<<<GRIDW(NS)>>>(ss_rowp, ss_col, S1, S0, NS);
    combine_mfma<true,true,true><<<GEMM(NS)>>>(S1, S0, WBR(l), WBL(l),
                                               sage_bl + (size_t)l*H, S1, NS);
  }

  // ---- final MLP -> d_out (f32)
  mlp_out_bf<<<GRIDW(NS)>>>(S1, mlp_W, mlp_b, out, NS);

  #undef GRID1
  #undef GRIDW
  #undef GEMM
  #undef WBL
  #undef WBR
}

// Round 6
// 1066.262 us; speedup vs baseline: 6.2294x; 1.1837x over previous
//
#include <hip/hip_runtime.h>

#define H 128
typedef unsigned short u16;
typedef __attribute__((ext_vector_type(8))) short bf16x8;
typedef __attribute__((ext_vector_type(4))) float f32x4;

// ---------------------------------------------------------------- utilities

static inline int gridFor(long long work, int block, int cap = 8192){
  long long g = (work + block - 1) / block;
  if (g > cap) g = cap;
  if (g < 1) g = 1;
  return (int)g;
}

__device__ __forceinline__ float waveReduceSum(float v){
  #pragma unroll
  for(int off = 32; off > 0; off >>= 1) v += __shfl_down(v, off);
  return v;
}

__device__ __forceinline__ float bflo(unsigned v){ return __uint_as_float(v << 16); }
__device__ __forceinline__ float bfhi(unsigned v){ return __uint_as_float(v & 0xffff0000u); }
__device__ __forceinline__ u16 f2bf(float f){
  unsigned u = __float_as_uint(f);
  return (u16)((u + 0x7fffu + ((u >> 16) & 1u)) >> 16);
}
__device__ __forceinline__ unsigned pack2(float lo, float hi){
  return (unsigned)f2bf(lo) | ((unsigned)f2bf(hi) << 16);
}

// ---------------------------------------------------------------- CSR build

__global__ void count_dst_i(const int* __restrict__ dst, int* __restrict__ cnt, int E){
  for(int e = blockIdx.x*blockDim.x + threadIdx.x; e < E; e += gridDim.x*blockDim.x)
    atomicAdd(&cnt[dst[e]], 1);
}

__global__ __launch_bounds__(256) void scan_block_sums(const int* __restrict__ in,
                                                       int* __restrict__ bsum, int n){
  int base = blockIdx.x * 4096 + threadIdx.x * 16;
  int s = 0;
  #pragma unroll
  for(int j = 0; j < 16; j++){ int i = base + j; if(i < n) s += in[i]; }
  #pragma unroll
  for(int off = 32; off > 0; off >>= 1) s += __shfl_down(s, off);
  __shared__ int ws[4];
  if((threadIdx.x & 63) == 0) ws[threadIdx.x >> 6] = s;
  __syncthreads();
  if(threadIdx.x == 0) bsum[blockIdx.x] = ws[0] + ws[1] + ws[2] + ws[3];
}

__global__ void scan_top(int* __restrict__ bsum, int nb){
  int t = threadIdx.x;
  int v = (t < nb) ? bsum[t] : 0;
  int incl = v;
  #pragma unroll
  for(int off = 1; off < 64; off <<= 1){
    int u = __shfl_up(incl, off);
    if(t >= off) incl += u;
  }
  if(t < nb) bsum[t] = incl - v;
}

__global__ __launch_bounds__(256) void scan_final(const int* __restrict__ in,
                                                  const int* __restrict__ bsum,
                                                  int* __restrict__ out, int n){
  int t = threadIdx.x;
  int base = blockIdx.x * 4096 + t * 16;
  int v[16]; int s = 0;
  #pragma unroll
  for(int j = 0; j < 16; j++){ int i = base + j; v[j] = (i < n) ? in[i] : 0; s += v[j]; }
  int lane = t & 63, wid = t >> 6;
  int incl = s;
  #pragma unroll
  for(int off = 1; off < 64; off <<= 1){
    int u = __shfl_up(incl, off);
    if(lane >= off) incl += u;
  }
  __shared__ int ws[4];
  if(lane == 63) ws[wid] = incl;
  __syncthreads();
  int wofs = 0;
  for(int wj = 0; wj < wid; wj++) wofs += ws[wj];
  int excl = bsum[blockIdx.x] + wofs + incl - s;
  #pragma unroll
  for(int j = 0; j < 16; j++){ int i = base + j; if(i < n) out[i] = excl; excl += v[j]; }
  if((int)blockIdx.x == (int)gridDim.x - 1 && t == 255) out[n] = excl;
}

__global__ void csr_fill(const int* __restrict__ src, const int* __restrict__ dst,
                         int* __restrict__ cursor, int* __restrict__ col,
                         const float* __restrict__ attr, float* __restrict__ attrp, int E){
  for(int e = blockIdx.x*blockDim.x + threadIdx.x; e < E; e += gridDim.x*blockDim.x){
    int d = dst[e];
    int pos = atomicAdd(&cursor[d], 1);
    col[pos] = src[e];
    if(attr) attrp[pos] = attr[e];
  }
}

__global__ void make_dinv(const int* __restrict__ rowp, float* __restrict__ dinv, int n){
  for(int i = blockIdx.x*blockDim.x + threadIdx.x; i < n; i += gridDim.x*blockDim.x){
    int d = rowp[i+1] - rowp[i];
    dinv[i] = d > 0 ? rsqrtf((float)d) : 0.f;
  }
}

// ---------------------------------------------------------------- weights to bf16 frag-major

// 15 mats of 128x128: 0-6 sage_Wl, 7-13 sage_Wr, 14 gat_Wsrc.
// Wb[mat][col*H + k] = W[mat][k*H + col]
__global__ void cvt_weights(const float* __restrict__ Wl, const float* __restrict__ Wr,
                            const float* __restrict__ Wsrc, u16* __restrict__ Wb){
  const int total = 15 * H * H;
  for(int t = blockIdx.x*blockDim.x + threadIdx.x; t < total; t += gridDim.x*blockDim.x){
    int mat = t >> 14, idx = t & 16383;
    int k = idx >> 7, colj = idx & 127;
    const float* srcp = (mat < 7) ? (Wl + ((size_t)mat << 14))
                       : (mat < 14) ? (Wr + ((size_t)(mat - 7) << 14))
                       : Wsrc;
    Wb[((size_t)mat << 14) + (size_t)colj*H + k] = f2bf(srcp[idx]);
  }
}

// outv[k] = sum_j W[k][j] * a[j]   (128x128)
__global__ void mat_vec_row(const float* __restrict__ W, const float* __restrict__ a,
                            float* __restrict__ outv){
  int k = threadIdx.x;
  if(k < H){
    float s = 0.f;
    for(int j = 0; j < H; j++) s += W[(size_t)k*H + j] * a[j];
    outv[k] = s;
  }
}

__global__ void dot128(const float* __restrict__ a, const float* __restrict__ b,
                       float* __restrict__ o){
  int l = threadIdx.x;
  float acc = a[l]*b[l] + a[l+64]*b[l+64];
  acc = waveReduceSum(acc);
  if(l == 0) o[0] = acc;
}

// ---------------------------------------------------------------- TAG

// hout[i*sout + k] = sum_{e: dst=i} hin[src*sin + k] * dinv[src]*dinv[i]
template<int C>
__global__ void csr_tag_hop(const int* __restrict__ rowp, const int* __restrict__ col,
                            const float* __restrict__ dinv,
                            const float* __restrict__ hin, int sin,
                            float* __restrict__ hout, int sout, int N){
  for(int i = blockIdx.x*blockDim.x + threadIdx.x; i < N; i += gridDim.x*blockDim.x){
    int b = rowp[i], e = rowp[i+1];
    float dd = dinv[i];
    float acc0[C], acc1[C];
    #pragma unroll
    for(int k = 0; k < C; k++){ acc0[k] = 0.f; acc1[k] = 0.f; }
    int p = b;
    for(; p + 2 <= e; p += 2){
      int s0 = col[p], s1 = col[p+1];
      float n0 = dinv[s0] * dd, n1 = dinv[s1] * dd;
      #pragma unroll
      for(int k = 0; k < C; k++){
        acc0[k] += hin[(size_t)s0*sin + k] * n0;
        acc1[k] += hin[(size_t)s1*sin + k] * n1;
      }
    }
    if(p < e){
      int s0 = col[p];
      float n0 = dinv[s0] * dd;
      #pragma unroll
      for(int k = 0; k < C; k++) acc0[k] += hin[(size_t)s0*sin + k] * n0;
    }
    #pragma unroll
    for(int k = 0; k < C; k++) hout[(size_t)i*sout + k] = acc0[k] + acc1[k];
  }
}

// out = relu( concat(x_i, hcat_i) @ W + b ), W = [(K+1)*C][H] flat; out bf16
template<int C>
__global__ __launch_bounds__(256) void tag_fuse(
    const float* __restrict__ x, const float* __restrict__ hcat,
    const float* __restrict__ W, const float* __restrict__ bias,
    u16* __restrict__ out, int N){
  __shared__ float Ws[4*C*H];
  for(int u = threadIdx.x; u < 4*C*H; u += 256) Ws[u] = W[u];
  __syncthreads();
  const long long total = (long long)N * H;
  for(long long t = (long long)blockIdx.x*blockDim.x + threadIdx.x; t < total;
      t += (long long)gridDim.x*blockDim.x){
    int i = (int)(t >> 7), j = (int)(t & 127);
    const float* xr = x + (size_t)i*C;
    const float* hr = hcat + (size_t)i*3*C;
    float acc = bias[j];
    #pragma unroll
    for(int k = 0; k < C; k++) acc += xr[k] * Ws[k*H + j];
    #pragma unroll
    for(int k = 0; k < 3*C; k++) acc += hr[k] * Ws[(C + k)*H + j];
    out[t] = f2bf(fmaxf(acc, 0.f));
  }
}

// ---------------------------------------------------------------- SAGE gather (bf16)

// agg[i] = mean_{e: dst=i} x[src]  (wave per row, 2 bf16 cols per lane)
__global__ void csr_gather(const int* __restrict__ rowp, const int* __restrict__ col,
                           const u16* __restrict__ x, u16* __restrict__ agg, int N){
  int lane = threadIdx.x & 63;
  int w = (blockIdx.x*blockDim.x + threadIdx.x) >> 6;
  int nw = (gridDim.x*blockDim.x) >> 6;
  for(int i = w; i < N; i += nw){
    int b = rowp[i], e = rowp[i+1];
    float x0=0.f, y0=0.f, x1=0.f, y1=0.f, x2=0.f, y2=0.f, x3=0.f, y3=0.f;
    int p = b;
    for(; p + 4 <= e; p += 4){
      int s0 = col[p], s1 = col[p+1], s2 = col[p+2], s3 = col[p+3];
      unsigned v0 = *(const unsigned*)&x[(size_t)s0*H + lane*2];
      unsigned v1 = *(const unsigned*)&x[(size_t)s1*H + lane*2];
      unsigned v2 = *(const unsigned*)&x[(size_t)s2*H + lane*2];
      unsigned v3 = *(const unsigned*)&x[(size_t)s3*H + lane*2];
      x0 += bflo(v0); y0 += bfhi(v0); x1 += bflo(v1); y1 += bfhi(v1);
      x2 += bflo(v2); y2 += bfhi(v2); x3 += bflo(v3); y3 += bfhi(v3);
    }
    for(; p < e; p++){
      unsigned v = *(const unsigned*)&x[(size_t)col[p]*H + lane*2];
      x0 += bflo(v); y0 += bfhi(v);
    }
    float inv = 1.f / fmaxf((float)(e - b), 1.f);
    *(unsigned*)&agg[(size_t)i*H + lane*2] = pack2((x0+x1+x2+x3)*inv, (y0+y1+y2+y3)*inv);
  }
}

// ---------------------------------------------------------------- MFMA combine (LDS-staged weights)

// out = maybe_relu( x@Wr [+ agg@Wl] [+ bl] ) bf16, f32 accumulate.
// Block: 4 waves x 32 rows = 128 rows. Weights staged in LDS with XOR swizzle
// (byte ^= (row&7)<<4) on both write and read to kill the 256B-row-stride
// bank conflict (G4). Per k0: 2 coalesced A loads + 8 ds_read_b128 + 16 MFMA.
template<bool HAS_AGG, bool RELU, bool BIAS>
__global__ __launch_bounds__(256) void combine_mfma(
    const u16* __restrict__ x, const u16* __restrict__ agg,
    const u16* __restrict__ WbR, const u16* __restrict__ WbL,
    const float* __restrict__ bl, u16* __restrict__ out, int N){
  __shared__ u16 Ws[(HAS_AGG ? 2 : 1) * H * H];

  // ---- stage weights (frag-major [col][k]) into LDS, swizzled
  #pragma unroll
  for(int m = 0; m < (HAS_AGG ? 2 : 1); m++){
    const u16* Wp = m ? WbL : WbR;
    char* dst = (char*)(Ws + m * H * H);
    for(int u = threadIdx.x; u < H * H / 8; u += 256){
      bf16x8 v = *(const bf16x8*)&Wp[u * 8];
      int c  = u >> 4;              // weight column (0..127)
      int kb = (u & 15) * 16;       // byte offset within row (0..255)
      *(bf16x8*)(dst + c * 256 + (kb ^ ((c & 7) << 4))) = v;
    }
  }
  __syncthreads();

  const int lane = threadIdx.x & 63;
  const int wib  = threadIdx.x >> 6;
  const int m0   = (blockIdx.x * 4 + wib) * 32;
  if(m0 >= N) return;
  const int r16 = lane & 15;
  const int kg  = (lane >> 4) * 8;

  f32x4 acc[2][8];
  #pragma unroll
  for(int rt = 0; rt < 2; rt++)
    #pragma unroll
    for(int t = 0; t < 8; t++) acc[rt][t] = (f32x4){0.f, 0.f, 0.f, 0.f};

  #pragma unroll
  for(int phase = 0; phase < (HAS_AGG ? 2 : 1); phase++){
    const u16* Ap = phase ? agg : x;
    const char* Wbase = (const char*)(Ws + phase * H * H);
    #pragma unroll
    for(int k0 = 0; k0 < H; k0 += 32){
      bf16x8 af[2];
      #pragma unroll
      for(int rt = 0; rt < 2; rt++){
        int row = m0 + rt * 16 + r16;
        if(row < N) af[rt] = *(const bf16x8*)&Ap[(size_t)row * H + k0 + kg];
        else        af[rt] = (bf16x8){0,0,0,0,0,0,0,0};
      }
      #pragma unroll
      for(int t = 0; t < 8; t++){
        int c = t * 16 + r16;
        int kb = (k0 + kg) * 2;
        bf16x8 bf = *(const bf16x8*)(Wbase + c * 256 + (kb ^ ((c & 7) << 4)));
        acc[0][t] = __builtin_amdgcn_mfma_f32_16x16x32_bf16(af[0], bf, acc[0][t], 0, 0, 0);
        acc[1][t] = __builtin_amdgcn_mfma_f32_16x16x32_bf16(af[1], bf, acc[1][t], 0, 0, 0);
      }
    }
  }

  #pragma unroll
  for(int rt = 0; rt < 2; rt++){
    const int orow = m0 + rt * 16 + (lane >> 4) * 4;
    #pragma unroll
    for(int t = 0; t < 8; t++){
      int c = t * 16 + r16;
      float bb = BIAS ? bl[c] : 0.f;
      #pragma unroll
      for(int r = 0; r < 4; r++){
        if(orow + r < N){
          float v = acc[rt][t][r] + bb;
          if(RELU) v = fmaxf(v, 0.f);
          out[(size_t)(orow + r) * H + c] = f2bf(v);
        }
      }
    }
  }
}

// ---------------------------------------------------------------- GAT

// out[i] = dot(x_bf16[i,:], v_f32)
__global__ void rowdot_bf(const u16* __restrict__ x, const float* __restrict__ v,
                          float* __restrict__ out, int N){
  int lane = threadIdx.x & 63;
  int w = (blockIdx.x*blockDim.x + threadIdx.x) >> 6;
  int nw = (gridDim.x*blockDim.x) >> 6;
  for(int i = w; i < N; i += nw){
    unsigned u = *(const unsigned*)&x[(size_t)i*H + lane*2];
    float acc = bflo(u)*v[lane*2] + bfhi(u)*v[lane*2 + 1];
    acc = waveReduceSum(acc);
    if(lane == 0) out[i] = acc;
  }
}

// single pass: out[i] = relu( (sum_e e_p*hs[src]) / max(sum_e e_p,1e-16) + bias )
__global__ void gat_fused(const int* __restrict__ rowp, const int* __restrict__ colv,
                          const float* __restrict__ attrp, const float* __restrict__ av,
                          const float* __restrict__ ad, const float* __restrict__ cptr,
                          const u16* __restrict__ hs, const float* __restrict__ bias,
                          u16* __restrict__ out, int N){
  const float c = cptr[0];
  int lane = threadIdx.x & 63;
  int w = (blockIdx.x*blockDim.x + threadIdx.x) >> 6;
  int nw = (gridDim.x*blockDim.x) >> 6;
  for(int i = w; i < N; i += nw){
    int b = rowp[i], e = rowp[i+1];
    float adi = ad[i];
    float accx0 = 0.f, accy0 = 0.f, accx1 = 0.f, accy1 = 0.f;
    float sume = 0.f;
    int p = b;
    for(; p + 2 <= e; p += 2){
      int s0 = colv[p], s1 = colv[p+1];
      float a0 = av[s0] + adi + attrp[p] * c;
      float a1 = av[s1] + adi + attrp[p+1] * c;
      a0 = a0 > 0.f ? a0 : 0.2f * a0;
      a1 = a1 > 0.f ? a1 : 0.2f * a1;
      float e0 = __expf(a0), e1 = __expf(a1);
      unsigned v0 = *(const unsigned*)&hs[(size_t)s0*H + lane*2];
      unsigned v1 = *(const unsigned*)&hs[(size_t)s1*H + lane*2];
      accx0 += e0 * bflo(v0); accy0 += e0 * bfhi(v0);
      accx1 += e1 * bflo(v1); accy1 += e1 * bfhi(v1);
      sume += e0 + e1;
    }
    if(p < e){
      int s0 = colv[p];
      float a0 = av[s0] + adi + attrp[p] * c;
      a0 = a0 > 0.f ? a0 : 0.2f * a0;
      float e0 = __expf(a0);
      unsigned v0 = *(const unsigned*)&hs[(size_t)s0*H + lane*2];
      accx0 += e0 * bflo(v0); accy0 += e0 * bfhi(v0);
      sume += e0;
    }
    float rd = 1.f / fmaxf(sume, 1e-16f);
    float ox = fmaxf((accx0 + accx1) * rd + bias[lane*2],     0.f);
    float oy = fmaxf((accy0 + accy1) * rd + bias[lane*2 + 1], 0.f);
    *(unsigned*)&out[(size_t)i*H + lane*2] = pack2(ox, oy);
  }
}

__global__ void mlp_out_bf(const u16* __restrict__ x, const float* __restrict__ W,
                           const float* __restrict__ b, float* __restrict__ out, int N){
  int lane = threadIdx.x & 63;
  int w = (blockIdx.x*blockDim.x + threadIdx.x) >> 6;
  int nw = (gridDim.x*blockDim.x) >> 6;
  for(int i = w; i < N; i += nw){
    unsigned u = *(const unsigned*)&x[(size_t)i*H + lane*2];
    float acc = bflo(u)*W[lane*2] + bfhi(u)*W[lane*2 + 1];
    acc = waveReduceSum(acc);
    if(lane == 0) out[i] = acc + b[0];
  }
}

// ---------------------------------------------------------------- launch

extern "C" void kernel_launch(void* const* d_in, const int* in_sizes, int n_in,
                              void* d_out, int out_size, void* d_ws, size_t ws_size,
                              hipStream_t stream) {
  const float* game_x  = (const float*)d_in[0];
  const float* state_x = (const float*)d_in[1];
  const int*   e_vv    = (const int*)d_in[2];
  const int*   e_hist  = (const int*)d_in[4];
  const float* attr_h  = (const float*)d_in[5];
  const int*   e_in    = (const int*)d_in[6];
  const int*   e_ss    = (const int*)d_in[7];
  const float* tag1_W  = (const float*)d_in[8];
  const float* tag1_b  = (const float*)d_in[9];
  const float* tag2_W  = (const float*)d_in[10];
  const float* tag2_b  = (const float*)d_in[11];
  const float* sage_Wl = (const float*)d_in[12];
  const float* sage_bl = (const float*)d_in[13];
  const float* sage_Wr = (const float*)d_in[14];
  const float* gat_Wsrc= (const float*)d_in[15];
  const float* gat_Wdst= (const float*)d_in[16];
  const float* gat_We  = (const float*)d_in[17];
  const float* gat_asrc= (const float*)d_in[18];
  const float* gat_adst= (const float*)d_in[19];
  const float* gat_ae  = (const float*)d_in[20];
  const float* gat_b   = (const float*)d_in[21];
  const float* mlp_W   = (const float*)d_in[22];
  const float* mlp_b   = (const float*)d_in[23];
  float* out = (float*)d_out;

  const int NV  = in_sizes[0] / 5;
  const int NS  = in_sizes[1] / 6;
  const int EVV = in_sizes[2] / 2;
  const int EH  = in_sizes[4] / 2;
  const int EIN = in_sizes[6] / 2;
  const int ESS = in_sizes[7] / 2;

  const int* vv_src = e_vv;   const int* vv_dst = e_vv + EVV;
  const int* eh_src = e_hist; const int* eh_dst = e_hist + EH;
  const int* in_src = e_in;   const int* in_dst = e_in + EIN;
  const int* ss_src = e_ss;   const int* ss_dst = e_ss + ESS;

  char* wp = (char*)d_ws;
  auto alloc = [&](size_t bytes) -> void* {
    void* p = (void*)wp;
    wp += (bytes + 511) & ~size_t(511);
    return p;
  };
  u16* V0 = (u16*)alloc((size_t)NV*H*2);
  u16* V1 = (u16*)alloc((size_t)NV*H*2);
  u16* S0 = (u16*)alloc((size_t)NS*H*2);
  u16* S1 = (u16*)alloc((size_t)NS*H*2);
  u16* Wb = (u16*)alloc((size_t)15*H*H*2);
  float* dinv_v = (float*)alloc((size_t)NV*4);
  float* dinv_s = (float*)alloc((size_t)NS*4);
  float* av   = (float*)alloc((size_t)NV*4);
  float* ad   = (float*)alloc((size_t)NS*4);
  float* hcat5= (float*)alloc((size_t)NV*15*4);
  float* hcat6= (float*)alloc((size_t)NS*18*4);
  float* wvec = (float*)alloc(H*4);
  float* cbuf = (float*)alloc(4);
  int* vv_rowp = (int*)alloc((size_t)(NV+1)*4);
  int* vv_col  = (int*)alloc((size_t)EVV*4);
  int* vv_cur  = (int*)alloc((size_t)NV*4);
  int* ss_rowp = (int*)alloc((size_t)(NS+1)*4);
  int* ss_col  = (int*)alloc((size_t)ESS*4);
  int* ss_cur  = (int*)alloc((size_t)NS*4);
  int* eh_rowp = (int*)alloc((size_t)(NS+1)*4);
  int* eh_col  = (int*)alloc((size_t)EH*4);
  float* eh_attr = (float*)alloc((size_t)EH*4);
  int* eh_cur  = (int*)alloc((size_t)NS*4);
  int* in_rowp = (int*)alloc((size_t)(NS+1)*4);
  int* in_col  = (int*)alloc((size_t)EIN*4);
  int* in_cur  = (int*)alloc((size_t)NS*4);
  int* bsum    = (int*)alloc(64*4);
  (void)ws_size; (void)n_in; (void)out_size;

  const int B = 256;
  #define GRID1(n) gridFor((long long)(n), B), B, 0, stream
  #define GRIDW(e) gridFor((long long)(e) * 64, B, 8192), B, 0, stream
  #define GEMM(n)  ((n) + 127) / 128, 256, 0, stream

  auto scan = [&](int* cnt, int* rowp, int n){
    int nb = (n + 4095) / 4096;
    scan_block_sums<<<nb, 256, 0, stream>>>(cnt, bsum, n);
    scan_top<<<1, 64, 0, stream>>>(bsum, nb);
    scan_final<<<nb, 256, 0, stream>>>(cnt, bsum, rowp, n);
  };

  // ---- build 4 CSRs
  hipMemsetAsync(vv_cur, 0, (size_t)NV*4, stream);
  hipMemsetAsync(ss_cur, 0, (size_t)NS*4, stream);
  hipMemsetAsync(eh_cur, 0, (size_t)NS*4, stream);
  hipMemsetAsync(in_cur, 0, (size_t)NS*4, stream);
  count_dst_i<<<GRID1(EVV)>>>(vv_dst, vv_cur, EVV);
  count_dst_i<<<GRID1(ESS)>>>(ss_dst, ss_cur, ESS);
  count_dst_i<<<GRID1(EH)>>>(eh_dst, eh_cur, EH);
  count_dst_i<<<GRID1(EIN)>>>(in_dst, in_cur, EIN);
  scan(vv_cur, vv_rowp, NV);
  scan(ss_cur, ss_rowp, NS);
  scan(eh_cur, eh_rowp, NS);
  scan(in_cur, in_rowp, NS);
  hipMemcpyAsync(vv_cur, vv_rowp, (size_t)NV*4, hipMemcpyDeviceToDevice, stream);
  hipMemcpyAsync(ss_cur, ss_rowp, (size_t)NS*4, hipMemcpyDeviceToDevice, stream);
  hipMemcpyAsync(eh_cur, eh_rowp, (size_t)NS*4, hipMemcpyDeviceToDevice, stream);
  hipMemcpyAsync(in_cur, in_rowp, (size_t)NS*4, hipMemcpyDeviceToDevice, stream);
  csr_fill<<<GRID1(EVV)>>>(vv_src, vv_dst, vv_cur, vv_col, nullptr, nullptr, EVV);
  csr_fill<<<GRID1(ESS)>>>(ss_src, ss_dst, ss_cur, ss_col, nullptr, nullptr, ESS);
  csr_fill<<<GRID1(EH)>>>(eh_src, eh_dst, eh_cur, eh_col, attr_h, eh_attr, EH);
  csr_fill<<<GRID1(EIN)>>>(in_src, in_dst, in_cur, in_col, nullptr, nullptr, EIN);
  make_dinv<<<GRID1(NV)>>>(vv_rowp, dinv_v, NV);
  make_dinv<<<GRID1(NS)>>>(ss_rowp, dinv_s, NS);

  // ---- weight prep
  cvt_weights<<<GRID1(15*H*H)>>>(sage_Wl, sage_Wr, gat_Wsrc, Wb);
  mat_vec_row<<<1, 128, 0, stream>>>(gat_Wdst, gat_adst, wvec);
  dot128<<<1, 64, 0, stream>>>(gat_We, gat_ae, cbuf);

  #define WBL(l) (Wb + ((size_t)(l) << 14))
  #define WBR(l) (Wb + ((size_t)(7 + (l)) << 14))

  // ---- TAG1 (game tower) -> V0 bf16
  csr_tag_hop<5><<<GRID1(NV)>>>(vv_rowp, vv_col, dinv_v, game_x, 5, hcat5 + 0, 15, NV);
  csr_tag_hop<5><<<GRID1(NV)>>>(vv_rowp, vv_col, dinv_v, hcat5 + 0, 15, hcat5 + 5, 15, NV);
  csr_tag_hop<5><<<GRID1(NV)>>>(vv_rowp, vv_col, dinv_v, hcat5 + 5, 15, hcat5 + 10, 15, NV);
  tag_fuse<5><<<GRID1((long long)NV*H)>>>(game_x, hcat5, tag1_W, tag1_b, V0, NV);

  // ---- SAGE 0,1 on vv (in-place on V0)
  for(int l = 0; l < 2; l++){
    csr_gather<<<GRIDW(NV)>>>(vv_rowp, vv_col, V0, V1, NV);
    combine_mfma<true,true,true><<<GEMM(NV)>>>(V0, V1, WBR(l), WBL(l),
                                               sage_bl + (size_t)l*H, V0, NV);
  }

  // ---- TAG2 (state tower) -> S0 bf16
  csr_tag_hop<6><<<GRID1(NS)>>>(ss_rowp, ss_col, dinv_s, state_x, 6, hcat6 + 0, 18, NS);
  csr_tag_hop<6><<<GRID1(NS)>>>(ss_rowp, ss_col, dinv_s, hcat6 + 0, 18, hcat6 + 6, 18, NS);
  csr_tag_hop<6><<<GRID1(NS)>>>(ss_rowp, ss_col, dinv_s, hcat6 + 6, 18, hcat6 + 12, 18, NS);
  tag_fuse<6><<<GRID1((long long)NS*H)>>>(state_x, hcat6, tag2_W, tag2_b, S0, NS);

  // ---- SAGE 2,3 on ss (in-place on S0)
  for(int l = 2; l < 4; l++){
    csr_gather<<<GRIDW(NS)>>>(ss_rowp, ss_col, S0, S1, NS);
    combine_mfma<true,true,true><<<GEMM(NS)>>>(S0, S1, WBR(l), WBL(l),
                                               sage_bl + (size_t)l*H, S0, NS);
  }

  // ---- GAT (gx -> sx) : hist -> S1
  combine_mfma<false,false,false><<<GEMM(NV)>>>(V0, nullptr, Wb + ((size_t)14 << 14),
                                                nullptr, nullptr, V1, NV);  // hs
  rowdot_bf<<<GRIDW(NV)>>>(V1, gat_asrc, av, NV);
  rowdot_bf<<<GRIDW(NS)>>>(S0, wvec, ad, NS);   // ad = sx @ (Wdst@adst)
  gat_fused<<<GRIDW(NS)>>>(eh_rowp, eh_col, eh_attr, av, ad, cbuf, V1, gat_b, S1, NS);

  // ---- SAGE4: aggregate gx over e_in, x_dst = hist (in-place on S1)
  csr_gather<<<GRIDW(NS)>>>(in_rowp, in_col, V0, S0, NS);
  combine_mfma<true,true,true><<<GEMM(NS)>>>(S1, S0, WBR(4), WBL(4),
                                             sage_bl + (size_t)4*H, S1, NS);

  // ---- SAGE 5,6 on ss (in-place on S1)
  for(int l = 5; l < 7; l++){
    csr_gather<<<GRIDW(NS)>>>(ss_rowp, ss_col, S1, S0, NS);
    combine_mfma<true,true,true><<<GEMM(NS)>>>(S1, S0, WBR(l), WBL(l),
                                               sage_bl + (size_t)l*H, S1, NS);
  }

  // ---- final MLP -> d_out (f32)
  mlp_out_bf<<<GRIDW(NS)>>>(S1, mlp_W, mlp_b, out, NS);

  #undef GRID1
  #undef GRIDW
  #undef GEMM
  #undef WBL
  #undef WBR
}

// Round 7
// 1037.492 us; speedup vs baseline: 6.4022x; 1.0277x over previous
//
#include <hip/hip_runtime.h>

#define H 128
typedef unsigned short u16;
typedef __attribute__((ext_vector_type(8))) short bf16x8;
typedef __attribute__((ext_vector_type(4))) float f32x4;

// ---------------------------------------------------------------- utilities

static inline int gridFor(long long work, int block, int cap = 8192){
  long long g = (work + block - 1) / block;
  if (g > cap) g = cap;
  if (g < 1) g = 1;
  return (int)g;
}

__device__ __forceinline__ float waveReduceSum(float v){
  #pragma unroll
  for(int off = 32; off > 0; off >>= 1) v += __shfl_down(v, off);
  return v;
}

__device__ __forceinline__ float bflo(unsigned v){ return __uint_as_float(v << 16); }
__device__ __forceinline__ float bfhi(unsigned v){ return __uint_as_float(v & 0xffff0000u); }
__device__ __forceinline__ u16 f2bf(float f){
  unsigned u = __float_as_uint(f);
  return (u16)((u + 0x7fffu + ((u >> 16) & 1u)) >> 16);
}
__device__ __forceinline__ unsigned pack2(float lo, float hi){
  return (unsigned)f2bf(lo) | ((unsigned)f2bf(hi) << 16);
}

// ---------------------------------------------------------------- CSR build

// one kernel, 4 graphs via blockIdx.y
__global__ void count_all(const int* __restrict__ d0, int* __restrict__ c0, int E0,
                          const int* __restrict__ d1, int* __restrict__ c1, int E1,
                          const int* __restrict__ d2, int* __restrict__ c2, int E2,
                          const int* __restrict__ d3, int* __restrict__ c3, int E3){
  const int* dst; int* cnt; int E;
  switch(blockIdx.y){
    case 0: dst = d0; cnt = c0; E = E0; break;
    case 1: dst = d1; cnt = c1; E = E1; break;
    case 2: dst = d2; cnt = c2; E = E2; break;
    default: dst = d3; cnt = c3; E = E3; break;
  }
  for(int e = blockIdx.x*blockDim.x + threadIdx.x; e < E; e += gridDim.x*blockDim.x)
    atomicAdd(&cnt[dst[e]], 1);
}

// batched multi-block scan, 4 arrays via blockIdx.y
__global__ __launch_bounds__(256) void scan_p1(
    const int* __restrict__ i0, const int* __restrict__ i1,
    const int* __restrict__ i2, const int* __restrict__ i3,
    int* __restrict__ b0, int* __restrict__ b1,
    int* __restrict__ b2, int* __restrict__ b3,
    int n0, int n1, int n2, int n3){
  const int* in; int* bsum; int n;
  switch(blockIdx.y){
    case 0: in = i0; bsum = b0; n = n0; break;
    case 1: in = i1; bsum = b1; n = n1; break;
    case 2: in = i2; bsum = b2; n = n2; break;
    default: in = i3; bsum = b3; n = n3; break;
  }
  int nb = (n + 4095) / 4096;
  if((int)blockIdx.x >= nb) return;
  int base = blockIdx.x * 4096 + threadIdx.x * 16;
  int s = 0;
  #pragma unroll
  for(int j = 0; j < 16; j++){ int i = base + j; if(i < n) s += in[i]; }
  #pragma unroll
  for(int off = 32; off > 0; off >>= 1) s += __shfl_down(s, off);
  __shared__ int ws[4];
  if((threadIdx.x & 63) == 0) ws[threadIdx.x >> 6] = s;
  __syncthreads();
  if(threadIdx.x == 0) bsum[blockIdx.x] = ws[0] + ws[1] + ws[2] + ws[3];
}

// 4 blocks; block b scans bsum_b (nb <= 64)
__global__ void scan_p2(int* __restrict__ b0, int* __restrict__ b1,
                        int* __restrict__ b2, int* __restrict__ b3,
                        int n0, int n1, int n2, int n3){
  int* bsum; int n;
  switch(blockIdx.x){
    case 0: bsum = b0; n = n0; break;
    case 1: bsum = b1; n = n1; break;
    case 2: bsum = b2; n = n2; break;
    default: bsum = b3; n = n3; break;
  }
  int nb = (n + 4095) / 4096;
  int t = threadIdx.x;
  int v = (t < nb) ? bsum[t] : 0;
  int incl = v;
  #pragma unroll
  for(int off = 1; off < 64; off <<= 1){
    int u = __shfl_up(incl, off);
    if(t >= off) incl += u;
  }
  if(t < nb) bsum[t] = incl - v;
}

// writes rowp, cursor copy, rowp[n]=total, and optional dinv = rsqrt(count)
__global__ __launch_bounds__(256) void scan_p3(
    const int* __restrict__ i0, const int* __restrict__ i1,
    const int* __restrict__ i2, const int* __restrict__ i3,
    const int* __restrict__ b0, const int* __restrict__ b1,
    const int* __restrict__ b2, const int* __restrict__ b3,
    int* __restrict__ o0, int* __restrict__ o1,
    int* __restrict__ o2, int* __restrict__ o3,
    int* __restrict__ u0, int* __restrict__ u1,
    int* __restrict__ u2, int* __restrict__ u3,
    float* __restrict__ dv0, float* __restrict__ dv1,
    float* __restrict__ dv2, float* __restrict__ dv3,
    int n0, int n1, int n2, int n3){
  const int* in; const int* bsum; int* out; int* cur; float* dv; int n;
  switch(blockIdx.y){
    case 0: in=i0; bsum=b0; out=o0; cur=u0; dv=dv0; n=n0; break;
    case 1: in=i1; bsum=b1; out=o1; cur=u1; dv=dv1; n=n1; break;
    case 2: in=i2; bsum=b2; out=o2; cur=u2; dv=dv2; n=n2; break;
    default: in=i3; bsum=b3; out=o3; cur=u3; dv=dv3; n=n3; break;
  }
  int nb = (n + 4095) / 4096;
  if((int)blockIdx.x >= nb) return;
  int t = threadIdx.x;
  int base = blockIdx.x * 4096 + t * 16;
  int v[16]; int s = 0;
  #pragma unroll
  for(int j = 0; j < 16; j++){ int i = base + j; v[j] = (i < n) ? in[i] : 0; s += v[j]; }
  int lane = t & 63, wid = t >> 6;
  int incl = s;
  #pragma unroll
  for(int off = 1; off < 64; off <<= 1){
    int u = __shfl_up(incl, off);
    if(lane >= off) incl += u;
  }
  __shared__ int ws[4];
  if(lane == 63) ws[wid] = incl;
  __syncthreads();
  int wofs = 0;
  for(int wj = 0; wj < wid; wj++) wofs += ws[wj];
  int excl = bsum[blockIdx.x] + wofs + incl - s;
  #pragma unroll
  for(int j = 0; j < 16; j++){
    int i = base + j;
    if(i < n){
      out[i] = excl;
      cur[i] = excl;
      if(dv) dv[i] = v[j] > 0 ? rsqrtf((float)v[j]) : 0.f;
    }
    excl += v[j];
  }
  if((int)blockIdx.x == nb - 1 && t == 255) out[n] = excl;
}

// chunked fill: sweep dst-range in 4 chunks so scattered col writes stay
// L2-resident until their 64B line is densely filled (kills 16x write amp).
__global__ void csr_fill_chunk(const int* __restrict__ src, const int* __restrict__ dst,
                               int* __restrict__ cursor, int* __restrict__ col,
                               const float* __restrict__ attr, float* __restrict__ attrp,
                               int E, int n){
  for(int c = 0; c < 4; c++){
    int lo = (int)(((long long)n * c) >> 2);
    int hi = (int)(((long long)n * (c+1)) >> 2);
    for(int e = blockIdx.x*blockDim.x + threadIdx.x; e < E; e += gridDim.x*blockDim.x){
      int d = dst[e];
      if(d >= lo && d < hi){
        int pos = atomicAdd(&cursor[d], 1);
        col[pos] = src[e];
        if(attr) attrp[pos] = attr[e];
      }
    }
  }
}

// ---------------------------------------------------------------- weights to bf16 frag-major

// 15 mats of 128x128: 0-6 sage_Wl, 7-13 sage_Wr, 14 gat_Wsrc.
// Wb[mat][col*H + k] = W[mat][k*H + col]
__global__ void cvt_weights(const float* __restrict__ Wl, const float* __restrict__ Wr,
                            const float* __restrict__ Wsrc, u16* __restrict__ Wb){
  const int total = 15 * H * H;
  for(int t = blockIdx.x*blockDim.x + threadIdx.x; t < total; t += gridDim.x*blockDim.x){
    int mat = t >> 14, idx = t & 16383;
    int k = idx >> 7, colj = idx & 127;
    const float* srcp = (mat < 7) ? (Wl + ((size_t)mat << 14))
                       : (mat < 14) ? (Wr + ((size_t)(mat - 7) << 14))
                       : Wsrc;
    Wb[((size_t)mat << 14) + (size_t)colj*H + k] = f2bf(srcp[idx]);
  }
}

// outv[k] = sum_j W[k][j] * a[j]   (128x128)
__global__ void mat_vec_row(const float* __restrict__ W, const float* __restrict__ a,
                            float* __restrict__ outv){
  int k = threadIdx.x;
  if(k < H){
    float s = 0.f;
    for(int j = 0; j < H; j++) s += W[(size_t)k*H + j] * a[j];
    outv[k] = s;
  }
}

__global__ void dot128(const float* __restrict__ a, const float* __restrict__ b,
                       float* __restrict__ o){
  int l = threadIdx.x;
  float acc = a[l]*b[l] + a[l+64]*b[l+64];
  acc = waveReduceSum(acc);
  if(l == 0) o[0] = acc;
}

// ---------------------------------------------------------------- TAG

// hout[i*sout + k] = sum_{e: dst=i} hin[src*sin + k] * dinv[src]*dinv[i]
template<int C>
__global__ void csr_tag_hop(const int* __restrict__ rowp, const int* __restrict__ col,
                            const float* __restrict__ dinv,
                            const float* __restrict__ hin, int sin,
                            float* __restrict__ hout, int sout, int N){
  for(int i = blockIdx.x*blockDim.x + threadIdx.x; i < N; i += gridDim.x*blockDim.x){
    int b = rowp[i], e = rowp[i+1];
    float dd = dinv[i];
    float acc0[C], acc1[C];
    #pragma unroll
    for(int k = 0; k < C; k++){ acc0[k] = 0.f; acc1[k] = 0.f; }
    int p = b;
    for(; p + 2 <= e; p += 2){
      int s0 = col[p], s1 = col[p+1];
      float n0 = dinv[s0] * dd, n1 = dinv[s1] * dd;
      #pragma unroll
      for(int k = 0; k < C; k++){
        acc0[k] += hin[(size_t)s0*sin + k] * n0;
        acc1[k] += hin[(size_t)s1*sin + k] * n1;
      }
    }
    if(p < e){
      int s0 = col[p];
      float n0 = dinv[s0] * dd;
      #pragma unroll
      for(int k = 0; k < C; k++) acc0[k] += hin[(size_t)s0*sin + k] * n0;
    }
    #pragma unroll
    for(int k = 0; k < C; k++) hout[(size_t)i*sout + k] = acc0[k] + acc1[k];
  }
}

// out = relu( concat(x_i, hcat_i) @ W + b ), W = [(K+1)*C][H] flat; out bf16
template<int C>
__global__ __launch_bounds__(256) void tag_fuse(
    const float* __restrict__ x, const float* __restrict__ hcat,
    const float* __restrict__ W, const float* __restrict__ bias,
    u16* __restrict__ out, int N){
  __shared__ float Ws[4*C*H];
  for(int u = threadIdx.x; u < 4*C*H; u += 256) Ws[u] = W[u];
  __syncthreads();
  const long long total = (long long)N * H;
  for(long long t = (long long)blockIdx.x*blockDim.x + threadIdx.x; t < total;
      t += (long long)gridDim.x*blockDim.x){
    int i = (int)(t >> 7), j = (int)(t & 127);
    const float* xr = x + (size_t)i*C;
    const float* hr = hcat + (size_t)i*3*C;
    float acc = bias[j];
    #pragma unroll
    for(int k = 0; k < C; k++) acc += xr[k] * Ws[k*H + j];
    #pragma unroll
    for(int k = 0; k < 3*C; k++) acc += hr[k] * Ws[(C + k)*H + j];
    out[t] = f2bf(fmaxf(acc, 0.f));
  }
}

// ---------------------------------------------------------------- SAGE gather (bf16)

// agg[i] = mean_{e: dst=i} x[src]  (wave per row, 8-deep unrolled)
__global__ void csr_gather(const int* __restrict__ rowp, const int* __restrict__ col,
                           const u16* __restrict__ x, u16* __restrict__ agg, int N){
  int lane = threadIdx.x & 63;
  int w = (blockIdx.x*blockDim.x + threadIdx.x) >> 6;
  int nw = (gridDim.x*blockDim.x) >> 6;
  for(int i = w; i < N; i += nw){
    int b = rowp[i], e = rowp[i+1];
    float xs[8], ys[8];
    #pragma unroll
    for(int j = 0; j < 8; j++){ xs[j] = 0.f; ys[j] = 0.f; }
    int p = b;
    for(; p + 8 <= e; p += 8){
      unsigned v[8];
      #pragma unroll
      for(int j = 0; j < 8; j++)
        v[j] = *(const unsigned*)&x[(size_t)col[p + j]*H + lane*2];
      #pragma unroll
      for(int j = 0; j < 8; j++){ xs[j] += bflo(v[j]); ys[j] += bfhi(v[j]); }
    }
    for(; p < e; p++){
      unsigned v = *(const unsigned*)&x[(size_t)col[p]*H + lane*2];
      xs[0] += bflo(v); ys[0] += bfhi(v);
    }
    float sx = (xs[0]+xs[1])+(xs[2]+xs[3])+((xs[4]+xs[5])+(xs[6]+xs[7]));
    float sy = (ys[0]+ys[1])+(ys[2]+ys[3])+((ys[4]+ys[5])+(ys[6]+ys[7]));
    float inv = 1.f / fmaxf((float)(e - b), 1.f);
    *(unsigned*)&agg[(size_t)i*H + lane*2] = pack2(sx*inv, sy*inv);
  }
}

// ---------------------------------------------------------------- MFMA combine (LDS-staged weights)

// out = maybe_relu( x@Wr [+ agg@Wl] [+ bl] ) bf16, f32 accumulate.
// Block: 4 waves x 32 rows = 128 rows. Weights staged in LDS with XOR swizzle
// (byte ^= (row&7)<<4) on both write and read (G4).
template<bool HAS_AGG, bool RELU, bool BIAS>
__global__ __launch_bounds__(256) void combine_mfma(
    const u16* __restrict__ x, const u16* __restrict__ agg,
    const u16* __restrict__ WbR, const u16* __restrict__ WbL,
    const float* __restrict__ bl, u16* __restrict__ out, int N){
  __shared__ u16 Ws[(HAS_AGG ? 2 : 1) * H * H];

  #pragma unroll
  for(int m = 0; m < (HAS_AGG ? 2 : 1); m++){
    const u16* Wp = m ? WbL : WbR;
    char* dst = (char*)(Ws + m * H * H);
    for(int u = threadIdx.x; u < H * H / 8; u += 256){
      bf16x8 v = *(const bf16x8*)&Wp[u * 8];
      int c  = u >> 4;
      int kb = (u & 15) * 16;
      *(bf16x8*)(dst + c * 256 + (kb ^ ((c & 7) << 4))) = v;
    }
  }
  __syncthreads();

  const int lane = threadIdx.x & 63;
  const int wib  = threadIdx.x >> 6;
  const int m0   = (blockIdx.x * 4 + wib) * 32;
  if(m0 >= N) return;
  const int r16 = lane & 15;
  const int kg  = (lane >> 4) * 8;

  f32x4 acc[2][8];
  #pragma unroll
  for(int rt = 0; rt < 2; rt++)
    #pragma unroll
    for(int t = 0; t < 8; t++) acc[rt][t] = (f32x4){0.f, 0.f, 0.f, 0.f};

  #pragma unroll
  for(int phase = 0; phase < (HAS_AGG ? 2 : 1); phase++){
    const u16* Ap = phase ? agg : x;
    const char* Wbase = (const char*)(Ws + phase * H * H);
    #pragma unroll
    for(int k0 = 0; k0 < H; k0 += 32){
      bf16x8 af[2];
      #pragma unroll
      for(int rt = 0; rt < 2; rt++){
        int row = m0 + rt * 16 + r16;
        if(row < N) af[rt] = *(const bf16x8*)&Ap[(size_t)row * H + k0 + kg];
        else        af[rt] = (bf16x8){0,0,0,0,0,0,0,0};
      }
      #pragma unroll
      for(int t = 0; t < 8; t++){
        int c = t * 16 + r16;
        int kb = (k0 + kg) * 2;
        bf16x8 bf = *(const bf16x8*)(Wbase + c * 256 + (kb ^ ((c & 7) << 4)));
        acc[0][t] = __builtin_amdgcn_mfma_f32_16x16x32_bf16(af[0], bf, acc[0][t], 0, 0, 0);
        acc[1][t] = __builtin_amdgcn_mfma_f32_16x16x32_bf16(af[1], bf, acc[1][t], 0, 0, 0);
      }
    }
  }

  #pragma unroll
  for(int rt = 0; rt < 2; rt++){
    const int orow = m0 + rt * 16 + (lane >> 4) * 4;
    #pragma unroll
    for(int t = 0; t < 8; t++){
      int c = t * 16 + r16;
      float bb = BIAS ? bl[c] : 0.f;
      #pragma unroll
      for(int r = 0; r < 4; r++){
        if(orow + r < N){
          float v = acc[rt][t][r] + bb;
          if(RELU) v = fmaxf(v, 0.f);
          out[(size_t)(orow + r) * H + c] = f2bf(v);
        }
      }
    }
  }
}

// ---------------------------------------------------------------- GAT

// out[i] = dot(x_bf16[i,:], v_f32)
__global__ void rowdot_bf(const u16* __restrict__ x, const float* __restrict__ v,
                          float* __restrict__ out, int N){
  int lane = threadIdx.x & 63;
  int w = (blockIdx.x*blockDim.x + threadIdx.x) >> 6;
  int nw = (gridDim.x*blockDim.x) >> 6;
  for(int i = w; i < N; i += nw){
    unsigned u = *(const unsigned*)&x[(size_t)i*H + lane*2];
    float acc = bflo(u)*v[lane*2] + bfhi(u)*v[lane*2 + 1];
    acc = waveReduceSum(acc);
    if(lane == 0) out[i] = acc;
  }
}

// single pass: out[i] = relu( (sum_e e_p*hs[src]) / max(sum_e e_p,1e-16) + bias )
__global__ void gat_fused(const int* __restrict__ rowp, const int* __restrict__ colv,
                          const float* __restrict__ attrp, const float* __restrict__ av,
                          const float* __restrict__ ad, const float* __restrict__ cptr,
                          const u16* __restrict__ hs, const float* __restrict__ bias,
                          u16* __restrict__ out, int N){
  const float c = cptr[0];
  int lane = threadIdx.x & 63;
  int w = (blockIdx.x*blockDim.x + threadIdx.x) >> 6;
  int nw = (gridDim.x*blockDim.x) >> 6;
  for(int i = w; i < N; i += nw){
    int b = rowp[i], e = rowp[i+1];
    float adi = ad[i];
    float accx0 = 0.f, accy0 = 0.f, accx1 = 0.f, accy1 = 0.f;
    float sume = 0.f;
    int p = b;
    for(; p + 2 <= e; p += 2){
      int s0 = colv[p], s1 = colv[p+1];
      float a0 = av[s0] + adi + attrp[p] * c;
      float a1 = av[s1] + adi + attrp[p+1] * c;
      a0 = a0 > 0.f ? a0 : 0.2f * a0;
      a1 = a1 > 0.f ? a1 : 0.2f * a1;
      float e0 = __expf(a0), e1 = __expf(a1);
      unsigned v0 = *(const unsigned*)&hs[(size_t)s0*H + lane*2];
      unsigned v1 = *(const unsigned*)&hs[(size_t)s1*H + lane*2];
      accx0 += e0 * bflo(v0); accy0 += e0 * bfhi(v0);
      accx1 += e1 * bflo(v1); accy1 += e1 * bfhi(v1);
      sume += e0 + e1;
    }
    if(p < e){
      int s0 = colv[p];
      float a0 = av[s0] + adi + attrp[p] * c;
      a0 = a0 > 0.f ? a0 : 0.2f * a0;
      float e0 = __expf(a0);
      unsigned v0 = *(const unsigned*)&hs[(size_t)s0*H + lane*2];
      accx0 += e0 * bflo(v0); accy0 += e0 * bfhi(v0);
      sume += e0;
    }
    float rd = 1.f / fmaxf(sume, 1e-16f);
    float ox = fmaxf((accx0 + accx1) * rd + bias[lane*2],     0.f);
    float oy = fmaxf((accy0 + accy1) * rd + bias[lane*2 + 1], 0.f);
    *(unsigned*)&out[(size_t)i*H + lane*2] = pack2(ox, oy);
  }
}

__global__ void mlp_out_bf(const u16* __restrict__ x, const float* __restrict__ W,
                           const float* __restrict__ b, float* __restrict__ out, int N){
  int lane = threadIdx.x & 63;
  int w = (blockIdx.x*blockDim.x + threadIdx.x) >> 6;
  int nw = (gridDim.x*blockDim.x) >> 6;
  for(int i = w; i < N; i += nw){
    unsigned u = *(const unsigned*)&x[(size_t)i*H + lane*2];
    float acc = bflo(u)*W[lane*2] + bfhi(u)*W[lane*2 + 1];
    acc = waveReduceSum(acc);
    if(lane == 0) out[i] = acc + b[0];
  }
}

// ---------------------------------------------------------------- launch

extern "C" void kernel_launch(void* const* d_in, const int* in_sizes, int n_in,
                              void* d_out, int out_size, void* d_ws, size_t ws_size,
                              hipStream_t stream) {
  const float* game_x  = (const float*)d_in[0];
  const float* state_x = (const float*)d_in[1];
  const int*   e_vv    = (const int*)d_in[2];
  const int*   e_hist  = (const int*)d_in[4];
  const float* attr_h  = (const float*)d_in[5];
  const int*   e_in    = (const int*)d_in[6];
  const int*   e_ss    = (const int*)d_in[7];
  const float* tag1_W  = (const float*)d_in[8];
  const float* tag1_b  = (const float*)d_in[9];
  const float* tag2_W  = (const float*)d_in[10];
  const float* tag2_b  = (const float*)d_in[11];
  const float* sage_Wl = (const float*)d_in[12];
  const float* sage_bl = (const float*)d_in[13];
  const float* sage_Wr = (const float*)d_in[14];
  const float* gat_Wsrc= (const float*)d_in[15];
  const float* gat_Wdst= (const float*)d_in[16];
  const float* gat_We  = (const float*)d_in[17];
  const float* gat_asrc= (const float*)d_in[18];
  const float* gat_adst= (const float*)d_in[19];
  const float* gat_ae  = (const float*)d_in[20];
  const float* gat_b   = (const float*)d_in[21];
  const float* mlp_W   = (const float*)d_in[22];
  const float* mlp_b   = (const float*)d_in[23];
  float* out = (float*)d_out;

  const int NV  = in_sizes[0] / 5;
  const int NS  = in_sizes[1] / 6;
  const int EVV = in_sizes[2] / 2;
  const int EH  = in_sizes[4] / 2;
  const int EIN = in_sizes[6] / 2;
  const int ESS = in_sizes[7] / 2;

  const int* vv_src = e_vv;   const int* vv_dst = e_vv + EVV;
  const int* eh_src = e_hist; const int* eh_dst = e_hist + EH;
  const int* in_src = e_in;   const int* in_dst = e_in + EIN;
  const int* ss_src = e_ss;   const int* ss_dst = e_ss + ESS;

  char* wp = (char*)d_ws;
  auto alloc = [&](size_t bytes) -> void* {
    void* p = (void*)wp;
    wp += (bytes + 511) & ~size_t(511);
    return p;
  };
  u16* V0 = (u16*)alloc((size_t)NV*H*2);
  u16* V1 = (u16*)alloc((size_t)NV*H*2);
  u16* S0 = (u16*)alloc((size_t)NS*H*2);
  u16* S1 = (u16*)alloc((size_t)NS*H*2);
  u16* Wb = (u16*)alloc((size_t)15*H*H*2);
  float* dinv_v = (float*)alloc((size_t)NV*4);
  float* dinv_s = (float*)alloc((size_t)NS*4);
  float* av   = (float*)alloc((size_t)NV*4);
  float* ad   = (float*)alloc((size_t)NS*4);
  float* hcat5= (float*)alloc((size_t)NV*15*4);
  float* hcat6= (float*)alloc((size_t)NS*18*4);
  float* wvec = (float*)alloc(H*4);
  float* cbuf = (float*)alloc(4);
  int* vv_rowp = (int*)alloc((size_t)(NV+1)*4);
  int* vv_col  = (int*)alloc((size_t)EVV*4);
  int* vv_cnt  = (int*)alloc((size_t)NV*4);
  int* vv_cur  = (int*)alloc((size_t)NV*4);
  int* ss_rowp = (int*)alloc((size_t)(NS+1)*4);
  int* ss_col  = (int*)alloc((size_t)ESS*4);
  int* ss_cnt  = (int*)alloc((size_t)NS*4);
  int* ss_cur  = (int*)alloc((size_t)NS*4);
  int* eh_rowp = (int*)alloc((size_t)(NS+1)*4);
  int* eh_col  = (int*)alloc((size_t)EH*4);
  float* eh_attr = (float*)alloc((size_t)EH*4);
  int* eh_cnt  = (int*)alloc((size_t)NS*4);
  int* eh_cur  = (int*)alloc((size_t)NS*4);
  int* in_rowp = (int*)alloc((size_t)(NS+1)*4);
  int* in_col  = (int*)alloc((size_t)EIN*4);
  int* in_cnt  = (int*)alloc((size_t)NS*4);
  int* in_cur  = (int*)alloc((size_t)NS*4);
  int* bsum    = (int*)alloc(4*64*4);
  (void)ws_size; (void)n_in; (void)out_size;

  const int B = 256;
  #define GRID1(n) gridFor((long long)(n), B), B, 0, stream
  #define GRIDW(e) gridFor((long long)(e) * 64, B, 8192), B, 0, stream
  #define GEMM(n)  ((n) + 127) / 128, 256, 0, stream

  // ---- build 4 CSRs (fused count + batched scan + chunked fill)
  hipMemsetAsync(vv_cnt, 0, (size_t)NV*4, stream);
  hipMemsetAsync(ss_cnt, 0, (size_t)NS*4, stream);
  hipMemsetAsync(eh_cnt, 0, (size_t)NS*4, stream);
  hipMemsetAsync(in_cnt, 0, (size_t)NS*4, stream);
  {
    dim3 cg(gridFor(EVV, B, 2048), 4);
    count_all<<<cg, B, 0, stream>>>(vv_dst, vv_cnt, EVV, ss_dst, ss_cnt, ESS,
                                    eh_dst, eh_cnt, EH, in_dst, in_cnt, EIN);
    int nbmax = (((NV > NS ? NV : NS) + 4095) / 4096);
    dim3 sg(nbmax, 4);
    scan_p1<<<sg, 256, 0, stream>>>(vv_cnt, ss_cnt, eh_cnt, in_cnt,
                                    bsum, bsum+64, bsum+128, bsum+192,
                                    NV, NS, NS, NS);
    scan_p2<<<4, 64, 0, stream>>>(bsum, bsum+64, bsum+128, bsum+192, NV, NS, NS, NS);
    scan_p3<<<sg, 256, 0, stream>>>(vv_cnt, ss_cnt, eh_cnt, in_cnt,
                                    bsum, bsum+64, bsum+128, bsum+192,
                                    vv_rowp, ss_rowp, eh_rowp, in_rowp,
                                    vv_cur, ss_cur, eh_cur, in_cur,
                                    dinv_v, dinv_s, nullptr, nullptr,
                                    NV, NS, NS, NS);
  }
  csr_fill_chunk<<<GRID1(EVV)>>>(vv_src, vv_dst, vv_cur, vv_col, nullptr, nullptr, EVV, NV);
  csr_fill_chunk<<<GRID1(ESS)>>>(ss_src, ss_dst, ss_cur, ss_col, nullptr, nullptr, ESS, NS);
  csr_fill_chunk<<<GRID1(EH)>>>(eh_src, eh_dst, eh_cur, eh_col, attr_h, eh_attr, EH, NS);
  csr_fill_chunk<<<GRID1(EIN)>>>(in_src, in_dst, in_cur, in_col, nullptr, nullptr, EIN, NS);

  // ---- weight prep
  cvt_weights<<<GRID1(15*H*H)>>>(sage_Wl, sage_Wr, gat_Wsrc, Wb);
  mat_vec_row<<<1, 128, 0, stream>>>(gat_Wdst, gat_adst, wvec);
  dot128<<<1, 64, 0, stream>>>(gat_We, gat_ae, cbuf);

  #define WBL(l) (Wb + ((size_t)(l) << 14))
  #define WBR(l) (Wb + ((size_t)(7 + (l)) << 14))

  // ---- TAG1 (game tower) -> V0 bf16
  csr_tag_hop<5><<<GRID1(NV)>>>(vv_rowp, vv_col, dinv_v, game_x, 5, hcat5 + 0, 15, NV);
  csr_tag_hop<5><<<GRID1(NV)>>>(vv_rowp, vv_col, dinv_v, hcat5 + 0, 15, hcat5 + 5, 15, NV);
  csr_tag_hop<5><<<GRID1(NV)>>>(vv_rowp, vv_col, dinv_v, hcat5 + 5, 15, hcat5 + 10, 15, NV);
  tag_fuse<5><<<GRID1((long long)NV*H)>>>(game_x, hcat5, tag1_W, tag1_b, V0, NV);

  // ---- SAGE 0,1 on vv (in-place on V0)
  for(int l = 0; l < 2; l++){
    csr_gather<<<GRIDW(NV)>>>(vv_rowp, vv_col, V0, V1, NV);
    combine_mfma<true,true,true><<<GEMM(NV)>>>(V0, V1, WBR(l), WBL(l),
                                               sage_bl + (size_t)l*H, V0, NV);
  }

  // ---- TAG2 (state tower) -> S0 bf16
  csr_tag_hop<6><<<GRID1(NS)>>>(ss_rowp, ss_col, dinv_s, state_x, 6, hcat6 + 0, 18, NS);
  csr_tag_hop<6><<<GRID1(NS)>>>(ss_rowp, ss_col, dinv_s, hcat6 + 0, 18, hcat6 + 6, 18, NS);
  csr_tag_hop<6><<<GRID1(NS)>>>(ss_rowp, ss_col, dinv_s, hcat6 + 6, 18, hcat6 + 12, 18, NS);
  tag_fuse<6><<<GRID1((long long)NS*H)>>>(state_x, hcat6, tag2_W, tag2_b, S0, NS);

  // ---- SAGE 2,3 on ss (in-place on S0)
  for(int l = 2; l < 4; l++){
    csr_gather<<<GRIDW(NS)>>>(ss_rowp, ss_col, S0, S1, NS);
    combine_mfma<true,true,true><<<GEMM(NS)>>>(S0, S1, WBR(l), WBL(l),
                                               sage_bl + (size_t)l*H, S0, NS);
  }

  // ---- GAT (gx -> sx) : hist -> S1
  combine_mfma<false,false,false><<<GEMM(NV)>>>(V0, nullptr, Wb + ((size_t)14 << 14),
                                                nullptr, nullptr, V1, NV);  // hs
  rowdot_bf<<<GRIDW(NV)>>>(V1, gat_asrc, av, NV);
  rowdot_bf<<<GRIDW(NS)>>>(S0, wvec, ad, NS);   // ad = sx @ (Wdst@adst)
  gat_fused<<<GRIDW(NS)>>>(eh_rowp, eh_col, eh_attr, av, ad, cbuf, V1, gat_b, S1, NS);

  // ---- SAGE4: aggregate gx over e_in, x_dst = hist (in-place on S1)
  csr_gather<<<GRIDW(NS)>>>(in_rowp, in_col, V0, S0, NS);
  combine_mfma<true,true,true><<<GEMM(NS)>>>(S1, S0, WBR(4), WBL(4),
                                             sage_bl + (size_t)4*H, S1, NS);

  // ---- SAGE 5,6 on ss (in-place on S1)
  for(int l = 5; l < 7; l++){
    csr_gather<<<GRIDW(NS)>>>(ss_rowp, ss_col, S1, S0, NS);
    combine_mfma<true,true,true><<<GEMM(NS)>>>(S1, S0, WBR(l), WBL(l),
                                               sage_bl + (size_t)l*H, S1, NS);
  }

  // ---- final MLP -> d_out (f32)
  mlp_out_bf<<<GRIDW(NS)>>>(S1, mlp_W, mlp_b, out, NS);

  #undef GRID1
  #undef GRIDW
  #undef GEMM
  #undef WBL
  #undef WBR
}

// Round 8
// 908.838 us; speedup vs baseline: 7.3084x; 1.1416x over previous
//
#include <hip/hip_runtime.h>

#define H 128
typedef unsigned short u16;
typedef __attribute__((ext_vector_type(8))) short bf16x8;
typedef __attribute__((ext_vector_type(4))) float f32x4;

// ---------------------------------------------------------------- utilities

static inline int gridFor(long long work, int block, int cap = 8192){
  long long g = (work + block - 1) / block;
  if (g > cap) g = cap;
  if (g < 1) g = 1;
  return (int)g;
}

__device__ __forceinline__ float waveReduceSum(float v){
  #pragma unroll
  for(int off = 32; off > 0; off >>= 1) v += __shfl_down(v, off);
  return v;
}

__device__ __forceinline__ float bflo(unsigned v){ return __uint_as_float(v << 16); }
__device__ __forceinline__ float bfhi(unsigned v){ return __uint_as_float(v & 0xffff0000u); }
__device__ __forceinline__ u16 f2bf(float f){
  unsigned u = __float_as_uint(f);
  return (u16)((u + 0x7fffu + ((u >> 16) & 1u)) >> 16);
}
__device__ __forceinline__ unsigned pack2(float lo, float hi){
  return (unsigned)f2bf(lo) | ((unsigned)f2bf(hi) << 16);
}

// ---------------------------------------------------------------- bucketed CSR build
// Pass A: partition edges into coarse buckets (dst>>9) with LDS-local atomics;
// global atomics only one per (block,bucket). Flush = coalesced bucket runs.
#define BSHIFT 9
#define CH 2048

template<bool HAS_ATTR>
__global__ __launch_bounds__(256) void part_kernel(
    const int* __restrict__ src, const int* __restrict__ dst,
    const float* __restrict__ attr, int* __restrict__ bcur,
    int2* __restrict__ bpairs, float* __restrict__ battr, int E, int cap){
  __shared__ int hist[256];
  __shared__ int hscan[256];
  __shared__ int hbase[256];
  __shared__ int hcur[256];
  __shared__ int2 buf[CH];
  __shared__ float abuf[HAS_ATTR ? CH : 1];

  const int t = threadIdx.x;
  const int e0 = blockIdx.x * CH;
  const int cnt = min(CH, E - e0);

  hist[t] = 0; hcur[t] = 0;
  __syncthreads();

  #pragma unroll
  for(int j = 0; j < 8; j++){
    int i = e0 + j*256 + t;
    if(i - e0 < cnt) atomicAdd(&hist[dst[i] >> BSHIFT], 1);
  }
  __syncthreads();

  // exclusive scan of hist over 256 + reserve global space
  {
    int v = hist[t];
    int lane = t & 63, wid = t >> 6;
    int incl = v;
    #pragma unroll
    for(int off = 1; off < 64; off <<= 1){
      int u = __shfl_up(incl, off);
      if(lane >= off) incl += u;
    }
    __shared__ int ws4[4];
    if(lane == 63) ws4[wid] = incl;
    __syncthreads();
    int wofs = 0;
    for(int wj = 0; wj < wid; wj++) wofs += ws4[wj];
    hscan[t] = wofs + incl - v;
    hbase[t] = (v > 0) ? atomicAdd(&bcur[t], v) : 0;
  }
  __syncthreads();

  // reorder into LDS by bucket
  #pragma unroll
  for(int j = 0; j < 8; j++){
    int i = e0 + j*256 + t;
    if(i - e0 < cnt){
      int d = dst[i], s = src[i];
      int b = d >> BSHIFT;
      int lp = atomicAdd(&hcur[b], 1);
      int slot = hscan[b] + lp;
      buf[slot] = make_int2(d, s);
      if(HAS_ATTR) abuf[slot] = attr[i];
    }
  }
  __syncthreads();

  // flush bucket runs (coalesced within run)
  for(int u = t; u < cnt; u += 256){
    int2 pr = buf[u];
    int b = pr.x >> BSHIFT;
    int g = b * cap + hbase[b] + (u - hscan[b]);
    bpairs[g] = pr;
    if(HAS_ATTR) battr[g] = abuf[u];
  }
}

// Tiny: per-graph exclusive scan of bucket totals (NB<=256); rowp[n] = total.
__global__ void bucket_scan(const int* __restrict__ bcur, int* __restrict__ bbase,
                            int* __restrict__ rp0, int* __restrict__ rp1,
                            int* __restrict__ rp2, int* __restrict__ rp3,
                            int n0, int n1, int n2, int n3){
  int g = blockIdx.x;
  int n = (g == 0) ? n0 : (g == 1) ? n1 : (g == 2) ? n2 : n3;
  int* rowp = (g == 0) ? rp0 : (g == 1) ? rp1 : (g == 2) ? rp2 : rp3;
  int NB = (n + 511) >> BSHIFT;
  int t = threadIdx.x;
  int v = (t < NB) ? bcur[g*256 + t] : 0;
  int lane = t & 63, wid = t >> 6;
  int incl = v;
  #pragma unroll
  for(int off = 1; off < 64; off <<= 1){
    int u = __shfl_up(incl, off);
    if(lane >= off) incl += u;
  }
  __shared__ int ws4[4];
  if(lane == 63) ws4[wid] = incl;
  __syncthreads();
  int wofs = 0;
  for(int wj = 0; wj < wid; wj++) wofs += ws4[wj];
  bbase[g*256 + t] = wofs + incl - v;
  if(t == 0) rowp[n] = ws4[0] + ws4[1] + ws4[2] + ws4[3];
}

// Pass B: one block per bucket. LDS histogram+scan over 512 dsts; writes rowp
// (+dinv) coalesced; scatters col within the bucket's dense region. No global atomics.
template<bool HAS_ATTR, bool DINV>
__global__ __launch_bounds__(256) void build_kernel(
    const int2* __restrict__ bpairs, const float* __restrict__ battr,
    const int* __restrict__ bcur, const int* __restrict__ bbase,
    int* __restrict__ rowp, int* __restrict__ col, float* __restrict__ attrp,
    float* __restrict__ dinv, int cap, int n){
  __shared__ int hist[512];
  __shared__ int hcur[512];
  __shared__ int ws4[4];

  const int b = blockIdx.x;
  const int t = threadIdx.x;
  const int d0 = b << BSHIFT;
  const int dn = min(512, n - d0);
  const int cnt = bcur[b];
  const int base = bbase[b];
  const int2* ep = bpairs + (size_t)b * cap;

  hist[t] = 0; hist[t + 256] = 0;
  __syncthreads();
  for(int u = t; u < cnt; u += 256) atomicAdd(&hist[ep[u].x - d0], 1);
  __syncthreads();

  // exclusive scan of 512 (2 per thread)
  int a0 = hist[2*t], a1 = hist[2*t + 1];
  int s = a0 + a1;
  int lane = t & 63, wid = t >> 6;
  int incl = s;
  #pragma unroll
  for(int off = 1; off < 64; off <<= 1){
    int u = __shfl_up(incl, off);
    if(lane >= off) incl += u;
  }
  if(lane == 63) ws4[wid] = incl;
  __syncthreads();
  int wofs = 0;
  for(int wj = 0; wj < wid; wj++) wofs += ws4[wj];
  int excl = wofs + incl - s;
  __syncthreads();
  hcur[2*t] = excl; hcur[2*t + 1] = excl + a0;
  if(2*t < dn){
    rowp[d0 + 2*t] = base + excl;
    if(DINV) dinv[d0 + 2*t] = a0 > 0 ? rsqrtf((float)a0) : 0.f;
  }
  if(2*t + 1 < dn){
    rowp[d0 + 2*t + 1] = base + excl + a0;
    if(DINV) dinv[d0 + 2*t + 1] = a1 > 0 ? rsqrtf((float)a1) : 0.f;
  }
  __syncthreads();

  for(int u = t; u < cnt; u += 256){
    int2 pr = ep[u];
    int pos = base + atomicAdd(&hcur[pr.x - d0], 1);
    col[pos] = pr.y;
    if(HAS_ATTR) attrp[pos] = battr[(size_t)b * cap + u];
  }
}

// ---------------------------------------------------------------- weights to bf16 frag-major

// 15 mats of 128x128: 0-6 sage_Wl, 7-13 sage_Wr, 14 gat_Wsrc.
// Wb[mat][col*H + k] = W[mat][k*H + col]
__global__ void cvt_weights(const float* __restrict__ Wl, const float* __restrict__ Wr,
                            const float* __restrict__ Wsrc, u16* __restrict__ Wb){
  const int total = 15 * H * H;
  for(int t = blockIdx.x*blockDim.x + threadIdx.x; t < total; t += gridDim.x*blockDim.x){
    int mat = t >> 14, idx = t & 16383;
    int k = idx >> 7, colj = idx & 127;
    const float* srcp = (mat < 7) ? (Wl + ((size_t)mat << 14))
                       : (mat < 14) ? (Wr + ((size_t)(mat - 7) << 14))
                       : Wsrc;
    Wb[((size_t)mat << 14) + (size_t)colj*H + k] = f2bf(srcp[idx]);
  }
}

// outv[k] = sum_j W[k][j] * a[j]   (128x128)
__global__ void mat_vec_row(const float* __restrict__ W, const float* __restrict__ a,
                            float* __restrict__ outv){
  int k = threadIdx.x;
  if(k < H){
    float s = 0.f;
    for(int j = 0; j < H; j++) s += W[(size_t)k*H + j] * a[j];
    outv[k] = s;
  }
}

__global__ void dot128(const float* __restrict__ a, const float* __restrict__ b,
                       float* __restrict__ o){
  int l = threadIdx.x;
  float acc = a[l]*b[l] + a[l+64]*b[l+64];
  acc = waveReduceSum(acc);
  if(l == 0) o[0] = acc;
}

// ---------------------------------------------------------------- TAG

// hout[i*sout + k] = sum_{e: dst=i} hin[src*sin + k] * dinv[src]*dinv[i]
template<int C>
__global__ void csr_tag_hop(const int* __restrict__ rowp, const int* __restrict__ col,
                            const float* __restrict__ dinv,
                            const float* __restrict__ hin, int sin,
                            float* __restrict__ hout, int sout, int N){
  for(int i = blockIdx.x*blockDim.x + threadIdx.x; i < N; i += gridDim.x*blockDim.x){
    int b = rowp[i], e = rowp[i+1];
    float dd = dinv[i];
    float acc0[C], acc1[C];
    #pragma unroll
    for(int k = 0; k < C; k++){ acc0[k] = 0.f; acc1[k] = 0.f; }
    int p = b;
    for(; p + 2 <= e; p += 2){
      int s0 = col[p], s1 = col[p+1];
      float n0 = dinv[s0] * dd, n1 = dinv[s1] * dd;
      #pragma unroll
      for(int k = 0; k < C; k++){
        acc0[k] += hin[(size_t)s0*sin + k] * n0;
        acc1[k] += hin[(size_t)s1*sin + k] * n1;
      }
    }
    if(p < e){
      int s0 = col[p];
      float n0 = dinv[s0] * dd;
      #pragma unroll
      for(int k = 0; k < C; k++) acc0[k] += hin[(size_t)s0*sin + k] * n0;
    }
    #pragma unroll
    for(int k = 0; k < C; k++) hout[(size_t)i*sout + k] = acc0[k] + acc1[k];
  }
}

// out = relu( concat(x_i, hcat_i) @ W + b ), W = [(K+1)*C][H] flat; out bf16
template<int C>
__global__ __launch_bounds__(256) void tag_fuse(
    const float* __restrict__ x, const float* __restrict__ hcat,
    const float* __restrict__ W, const float* __restrict__ bias,
    u16* __restrict__ out, int N){
  __shared__ float Ws[4*C*H];
  for(int u = threadIdx.x; u < 4*C*H; u += 256) Ws[u] = W[u];
  __syncthreads();
  const long long total = (long long)N * H;
  for(long long t = (long long)blockIdx.x*blockDim.x + threadIdx.x; t < total;
      t += (long long)gridDim.x*blockDim.x){
    int i = (int)(t >> 7), j = (int)(t & 127);
    const float* xr = x + (size_t)i*C;
    const float* hr = hcat + (size_t)i*3*C;
    float acc = bias[j];
    #pragma unroll
    for(int k = 0; k < C; k++) acc += xr[k] * Ws[k*H + j];
    #pragma unroll
    for(int k = 0; k < 3*C; k++) acc += hr[k] * Ws[(C + k)*H + j];
    out[t] = f2bf(fmaxf(acc, 0.f));
  }
}

// ---------------------------------------------------------------- SAGE gather (bf16)

// agg[i] = mean_{e: dst=i} x[src]  (wave per row, 8-deep unrolled)
__global__ void csr_gather(const int* __restrict__ rowp, const int* __restrict__ col,
                           const u16* __restrict__ x, u16* __restrict__ agg, int N){
  int lane = threadIdx.x & 63;
  int w = (blockIdx.x*blockDim.x + threadIdx.x) >> 6;
  int nw = (gridDim.x*blockDim.x) >> 6;
  for(int i = w; i < N; i += nw){
    int b = rowp[i], e = rowp[i+1];
    float xs[8], ys[8];
    #pragma unroll
    for(int j = 0; j < 8; j++){ xs[j] = 0.f; ys[j] = 0.f; }
    int p = b;
    for(; p + 8 <= e; p += 8){
      unsigned v[8];
      #pragma unroll
      for(int j = 0; j < 8; j++)
        v[j] = *(const unsigned*)&x[(size_t)col[p + j]*H + lane*2];
      #pragma unroll
      for(int j = 0; j < 8; j++){ xs[j] += bflo(v[j]); ys[j] += bfhi(v[j]); }
    }
    for(; p < e; p++){
      unsigned v = *(const unsigned*)&x[(size_t)col[p]*H + lane*2];
      xs[0] += bflo(v); ys[0] += bfhi(v);
    }
    float sx = (xs[0]+xs[1])+(xs[2]+xs[3])+((xs[4]+xs[5])+(xs[6]+xs[7]));
    float sy = (ys[0]+ys[1])+(ys[2]+ys[3])+((ys[4]+ys[5])+(ys[6]+ys[7]));
    float inv = 1.f / fmaxf((float)(e - b), 1.f);
    *(unsigned*)&agg[(size_t)i*H + lane*2] = pack2(sx*inv, sy*inv);
  }
}

// ---------------------------------------------------------------- MFMA combine (LDS-staged weights)

// out = maybe_relu( x@Wr [+ agg@Wl] [+ bl] ) bf16, f32 accumulate.
// Block: 4 waves x 32 rows = 128 rows. Weights staged in LDS with XOR swizzle
// (byte ^= (row&7)<<4) on both write and read (G4).
template<bool HAS_AGG, bool RELU, bool BIAS>
__global__ __launch_bounds__(256) void combine_mfma(
    const u16* __restrict__ x, const u16* __restrict__ agg,
    const u16* __restrict__ WbR, const u16* __restrict__ WbL,
    const float* __restrict__ bl, u16* __restrict__ out, int N){
  __shared__ u16 Ws[(HAS_AGG ? 2 : 1) * H * H];

  #pragma unroll
  for(int m = 0; m < (HAS_AGG ? 2 : 1); m++){
    const u16* Wp = m ? WbL : WbR;
    char* dst = (char*)(Ws + m * H * H);
    for(int u = threadIdx.x; u < H * H / 8; u += 256){
      bf16x8 v = *(const bf16x8*)&Wp[u * 8];
      int c  = u >> 4;
      int kb = (u & 15) * 16;
      *(bf16x8*)(dst + c * 256 + (kb ^ ((c & 7) << 4))) = v;
    }
  }
  __syncthreads();

  const int lane = threadIdx.x & 63;
  const int wib  = threadIdx.x >> 6;
  const int m0   = (blockIdx.x * 4 + wib) * 32;
  if(m0 >= N) return;
  const int r16 = lane & 15;
  const int kg  = (lane >> 4) * 8;

  f32x4 acc[2][8];
  #pragma unroll
  for(int rt = 0; rt < 2; rt++)
    #pragma unroll
    for(int t = 0; t < 8; t++) acc[rt][t] = (f32x4){0.f, 0.f, 0.f, 0.f};

  #pragma unroll
  for(int phase = 0; phase < (HAS_AGG ? 2 : 1); phase++){
    const u16* Ap = phase ? agg : x;
    const char* Wbase = (const char*)(Ws + phase * H * H);
    #pragma unroll
    for(int k0 = 0; k0 < H; k0 += 32){
      bf16x8 af[2];
      #pragma unroll
      for(int rt = 0; rt < 2; rt++){
        int row = m0 + rt * 16 + r16;
        if(row < N) af[rt] = *(const bf16x8*)&Ap[(size_t)row * H + k0 + kg];
        else        af[rt] = (bf16x8){0,0,0,0,0,0,0,0};
      }
      #pragma unroll
      for(int t = 0; t < 8; t++){
        int c = t * 16 + r16;
        int kb = (k0 + kg) * 2;
        bf16x8 bf = *(const bf16x8*)(Wbase + c * 256 + (kb ^ ((c & 7) << 4)));
        acc[0][t] = __builtin_amdgcn_mfma_f32_16x16x32_bf16(af[0], bf, acc[0][t], 0, 0, 0);
        acc[1][t] = __builtin_amdgcn_mfma_f32_16x16x32_bf16(af[1], bf, acc[1][t], 0, 0, 0);
      }
    }
  }

  #pragma unroll
  for(int rt = 0; rt < 2; rt++){
    const int orow = m0 + rt * 16 + (lane >> 4) * 4;
    #pragma unroll
    for(int t = 0; t < 8; t++){
      int c = t * 16 + r16;
      float bb = BIAS ? bl[c] : 0.f;
      #pragma unroll
      for(int r = 0; r < 4; r++){
        if(orow + r < N){
          float v = acc[rt][t][r] + bb;
          if(RELU) v = fmaxf(v, 0.f);
          out[(size_t)(orow + r) * H + c] = f2bf(v);
        }
      }
    }
  }
}

// ---------------------------------------------------------------- GAT

// out[i] = dot(x_bf16[i,:], v_f32)
__global__ void rowdot_bf(const u16* __restrict__ x, const float* __restrict__ v,
                          float* __restrict__ out, int N){
  int lane = threadIdx.x & 63;
  int w = (blockIdx.x*blockDim.x + threadIdx.x) >> 6;
  int nw = (gridDim.x*blockDim.x) >> 6;
  for(int i = w; i < N; i += nw){
    unsigned u = *(const unsigned*)&x[(size_t)i*H + lane*2];
    float acc = bflo(u)*v[lane*2] + bfhi(u)*v[lane*2 + 1];
    acc = waveReduceSum(acc);
    if(lane == 0) out[i] = acc;
  }
}

// single pass: out[i] = relu( (sum_e e_p*hs[src]) / max(sum_e e_p,1e-16) + bias )
__global__ void gat_fused(const int* __restrict__ rowp, const int* __restrict__ colv,
                          const float* __restrict__ attrp, const float* __restrict__ av,
                          const float* __restrict__ ad, const float* __restrict__ cptr,
                          const u16* __restrict__ hs, const float* __restrict__ bias,
                          u16* __restrict__ out, int N){
  const float c = cptr[0];
  int lane = threadIdx.x & 63;
  int w = (blockIdx.x*blockDim.x + threadIdx.x) >> 6;
  int nw = (gridDim.x*blockDim.x) >> 6;
  for(int i = w; i < N; i += nw){
    int b = rowp[i], e = rowp[i+1];
    float adi = ad[i];
    float accx0 = 0.f, accy0 = 0.f, accx1 = 0.f, accy1 = 0.f;
    float sume = 0.f;
    int p = b;
    for(; p + 2 <= e; p += 2){
      int s0 = colv[p], s1 = colv[p+1];
      float a0 = av[s0] + adi + attrp[p] * c;
      float a1 = av[s1] + adi + attrp[p+1] * c;
      a0 = a0 > 0.f ? a0 : 0.2f * a0;
      a1 = a1 > 0.f ? a1 : 0.2f * a1;
      float e0 = __expf(a0), e1 = __expf(a1);
      unsigned v0 = *(const unsigned*)&hs[(size_t)s0*H + lane*2];
      unsigned v1 = *(const unsigned*)&hs[(size_t)s1*H + lane*2];
      accx0 += e0 * bflo(v0); accy0 += e0 * bfhi(v0);
      accx1 += e1 * bflo(v1); accy1 += e1 * bfhi(v1);
      sume += e0 + e1;
    }
    if(p < e){
      int s0 = colv[p];
      float a0 = av[s0] + adi + attrp[p] * c;
      a0 = a0 > 0.f ? a0 : 0.2f * a0;
      float e0 = __expf(a0);
      unsigned v0 = *(const unsigned*)&hs[(size_t)s0*H + lane*2];
      accx0 += e0 * bflo(v0); accy0 += e0 * bfhi(v0);
      sume += e0;
    }
    float rd = 1.f / fmaxf(sume, 1e-16f);
    float ox = fmaxf((accx0 + accx1) * rd + bias[lane*2],     0.f);
    float oy = fmaxf((accy0 + accy1) * rd + bias[lane*2 + 1], 0.f);
    *(unsigned*)&out[(size_t)i*H + lane*2] = pack2(ox, oy);
  }
}

__global__ void mlp_out_bf(const u16* __restrict__ x, const float* __restrict__ W,
                           const float* __restrict__ b, float* __restrict__ out, int N){
  int lane = threadIdx.x & 63;
  int w = (blockIdx.x*blockDim.x + threadIdx.x) >> 6;
  int nw = (gridDim.x*blockDim.x) >> 6;
  for(int i = w; i < N; i += nw){
    unsigned u = *(const unsigned*)&x[(size_t)i*H + lane*2];
    float acc = bflo(u)*W[lane*2] + bfhi(u)*W[lane*2 + 1];
    acc = waveReduceSum(acc);
    if(lane == 0) out[i] = acc + b[0];
  }
}

// ---------------------------------------------------------------- launch

extern "C" void kernel_launch(void* const* d_in, const int* in_sizes, int n_in,
                              void* d_out, int out_size, void* d_ws, size_t ws_size,
                              hipStream_t stream) {
  const float* game_x  = (const float*)d_in[0];
  const float* state_x = (const float*)d_in[1];
  const int*   e_vv    = (const int*)d_in[2];
  const int*   e_hist  = (const int*)d_in[4];
  const float* attr_h  = (const float*)d_in[5];
  const int*   e_in    = (const int*)d_in[6];
  const int*   e_ss    = (const int*)d_in[7];
  const float* tag1_W  = (const float*)d_in[8];
  const float* tag1_b  = (const float*)d_in[9];
  const float* tag2_W  = (const float*)d_in[10];
  const float* tag2_b  = (const float*)d_in[11];
  const float* sage_Wl = (const float*)d_in[12];
  const float* sage_bl = (const float*)d_in[13];
  const float* sage_Wr = (const float*)d_in[14];
  const float* gat_Wsrc= (const float*)d_in[15];
  const float* gat_Wdst= (const float*)d_in[16];
  const float* gat_We  = (const float*)d_in[17];
  const float* gat_asrc= (const float*)d_in[18];
  const float* gat_adst= (const float*)d_in[19];
  const float* gat_ae  = (const float*)d_in[20];
  const float* gat_b   = (const float*)d_in[21];
  const float* mlp_W   = (const float*)d_in[22];
  const float* mlp_b   = (const float*)d_in[23];
  float* out = (float*)d_out;

  const int NV  = in_sizes[0] / 5;
  const int NS  = in_sizes[1] / 6;
  const int EVV = in_sizes[2] / 2;
  const int EH  = in_sizes[4] / 2;
  const int EIN = in_sizes[6] / 2;
  const int ESS = in_sizes[7] / 2;

  const int* vv_src = e_vv;   const int* vv_dst = e_vv + EVV;
  const int* eh_src = e_hist; const int* eh_dst = e_hist + EH;
  const int* in_src = e_in;   const int* in_dst = e_in + EIN;
  const int* ss_src = e_ss;   const int* ss_dst = e_ss + ESS;

  const int NBv = (NV + 511) >> BSHIFT;    // buckets for NV-dst graphs
  const int NBs = (NS + 511) >> BSHIFT;    // buckets for NS-dst graphs
  const int capvv = (EVV / NBv) * 3 / 2 + 64;
  const int capss = (ESS / NBs) * 3 / 2 + 64;
  const int capeh = (EH  / NBs) * 3 / 2 + 64;
  const int capin = (EIN / NBs) * 3 / 2 + 64;

  char* wp = (char*)d_ws;
  auto alloc = [&](size_t bytes) -> void* {
    void* p = (void*)wp;
    wp += (bytes + 511) & ~size_t(511);
    return p;
  };
  u16* V0 = (u16*)alloc((size_t)NV*H*2);
  u16* V1 = (u16*)alloc((size_t)NV*H*2);
  u16* S0 = (u16*)alloc((size_t)NS*H*2);
  u16* S1 = (u16*)alloc((size_t)NS*H*2);
  u16* Wb = (u16*)alloc((size_t)15*H*H*2);
  float* dinv_v = (float*)alloc((size_t)NV*4);
  float* dinv_s = (float*)alloc((size_t)NS*4);
  float* av   = (float*)alloc((size_t)NV*4);
  float* ad   = (float*)alloc((size_t)NS*4);
  float* hcat5= (float*)alloc((size_t)NV*15*4);
  float* hcat6= (float*)alloc((size_t)NS*18*4);
  float* wvec = (float*)alloc(H*4);
  float* cbuf = (float*)alloc(4);
  int* vv_rowp = (int*)alloc((size_t)(NV+1)*4);
  int* vv_col  = (int*)alloc((size_t)EVV*4);
  int* ss_rowp = (int*)alloc((size_t)(NS+1)*4);
  int* ss_col  = (int*)alloc((size_t)ESS*4);
  int* eh_rowp = (int*)alloc((size_t)(NS+1)*4);
  int* eh_col  = (int*)alloc((size_t)EH*4);
  float* eh_attr = (float*)alloc((size_t)EH*4);
  int* in_rowp = (int*)alloc((size_t)(NS+1)*4);
  int* in_col  = (int*)alloc((size_t)EIN*4);
  int2* vv_bp = (int2*)alloc((size_t)NBv*capvv*8);
  int2* ss_bp = (int2*)alloc((size_t)NBs*capss*8);
  int2* eh_bp = (int2*)alloc((size_t)NBs*capeh*8);
  int2* in_bp = (int2*)alloc((size_t)NBs*capin*8);
  float* eh_ba = (float*)alloc((size_t)NBs*capeh*4);
  int* bcur  = (int*)alloc(4*256*4);
  int* bbase = (int*)alloc(4*256*4);
  (void)ws_size; (void)n_in; (void)out_size;

  const int B = 256;
  #define GRID1(n) gridFor((long long)(n), B), B, 0, stream
  #define GRIDW(e) gridFor((long long)(e) * 64, B, 8192), B, 0, stream
  #define GEMM(n)  ((n) + 127) / 128, 256, 0, stream

  // ---- bucketed CSR build (no scattered global atomics)
  hipMemsetAsync(bcur, 0, 4*256*4, stream);
  part_kernel<false><<<(EVV + CH - 1)/CH, 256, 0, stream>>>(
      vv_src, vv_dst, nullptr, bcur + 0,   vv_bp, nullptr, EVV, capvv);
  part_kernel<false><<<(ESS + CH - 1)/CH, 256, 0, stream>>>(
      ss_src, ss_dst, nullptr, bcur + 256, ss_bp, nullptr, ESS, capss);
  part_kernel<true ><<<(EH  + CH - 1)/CH, 256, 0, stream>>>(
      eh_src, eh_dst, attr_h,  bcur + 512, eh_bp, eh_ba,   EH,  capeh);
  part_kernel<false><<<(EIN + CH - 1)/CH, 256, 0, stream>>>(
      in_src, in_dst, nullptr, bcur + 768, in_bp, nullptr, EIN, capin);
  bucket_scan<<<4, 256, 0, stream>>>(bcur, bbase, vv_rowp, ss_rowp, eh_rowp, in_rowp,
                                     NV, NS, NS, NS);
  build_kernel<false,true ><<<NBv, 256, 0, stream>>>(
      vv_bp, nullptr, bcur + 0,   bbase + 0,   vv_rowp, vv_col, nullptr, dinv_v, capvv, NV);
  build_kernel<false,true ><<<NBs, 256, 0, stream>>>(
      ss_bp, nullptr, bcur + 256, bbase + 256, ss_rowp, ss_col, nullptr, dinv_s, capss, NS);
  build_kernel<true ,false><<<NBs, 256, 0, stream>>>(
      eh_bp, eh_ba,   bcur + 512, bbase + 512, eh_rowp, eh_col, eh_attr, nullptr, capeh, NS);
  build_kernel<false,false><<<NBs, 256, 0, stream>>>(
      in_bp, nullptr, bcur + 768, bbase + 768, in_rowp, in_col, nullptr, nullptr, capin, NS);

  // ---- weight prep
  cvt_weights<<<GRID1(15*H*H)>>>(sage_Wl, sage_Wr, gat_Wsrc, Wb);
  mat_vec_row<<<1, 128, 0, stream>>>(gat_Wdst, gat_adst, wvec);
  dot128<<<1, 64, 0, stream>>>(gat_We, gat_ae, cbuf);

  #define WBL(l) (Wb + ((size_t)(l) << 14))
  #define WBR(l) (Wb + ((size_t)(7 + (l)) << 14))

  // ---- TAG1 (game tower) -> V0 bf16
  csr_tag_hop<5><<<GRID1(NV)>>>(vv_rowp, vv_col, dinv_v, game_x, 5, hcat5 + 0, 15, NV);
  csr_tag_hop<5><<<GRID1(NV)>>>(vv_rowp, vv_col, dinv_v, hcat5 + 0, 15, hcat5 + 5, 15, NV);
  csr_tag_hop<5><<<GRID1(NV)>>>(vv_rowp, vv_col, dinv_v, hcat5 + 5, 15, hcat5 + 10, 15, NV);
  tag_fuse<5><<<GRID1((long long)NV*H)>>>(game_x, hcat5, tag1_W, tag1_b, V0, NV);

  // ---- SAGE 0,1 on vv (in-place on V0)
  for(int l = 0; l < 2; l++){
    csr_gather<<<GRIDW(NV)>>>(vv_rowp, vv_col, V0, V1, NV);
    combine_mfma<true,true,true><<<GEMM(NV)>>>(V0, V1, WBR(l), WBL(l),
                                               sage_bl + (size_t)l*H, V0, NV);
  }

  // ---- TAG2 (state tower) -> S0 bf16
  csr_tag_hop<6><<<GRID1(NS)>>>(ss_rowp, ss_col, dinv_s, state_x, 6, hcat6 + 0, 18, NS);
  csr_tag_hop<6><<<GRID1(NS)>>>(ss_rowp, ss_col, dinv_s, hcat6 + 0, 18, hcat6 + 6, 18, NS);
  csr_tag_hop<6><<<GRID1(NS)>>>(ss_rowp, ss_col, dinv_s, hcat6 + 6, 18, hcat6 + 12, 18, NS);
  tag_fuse<6><<<GRID1((long long)NS*H)>>>(state_x, hcat6, tag2_W, tag2_b, S0, NS);

  // ---- SAGE 2,3 on ss (in-place on S0)
  for(int l = 2; l < 4; l++){
    csr_gather<<<GRIDW(NS)>>>(ss_rowp, ss_col, S0, S1, NS);
    combine_mfma<true,true,true><<<GEMM(NS)>>>(S0, S1, WBR(l), WBL(l),
                                               sage_bl + (size_t)l*H, S0, NS);
  }

  // ---- GAT (gx -> sx) : hist -> S1
  combine_mfma<false,false,false><<<GEMM(NV)>>>(V0, nullptr, Wb + ((size_t)14 << 14),
                                                nullptr, nullptr, V1, NV);  // hs
  rowdot_bf<<<GRIDW(NV)>>>(V1, gat_asrc, av, NV);
  rowdot_bf<<<GRIDW(NS)>>>(S0, wvec, ad, NS);   // ad = sx @ (Wdst@adst)
  gat_fused<<<GRIDW(NS)>>>(eh_rowp, eh_col, eh_attr, av, ad, cbuf, V1, gat_b, S1, NS);

  // ---- SAGE4: aggregate gx over e_in, x_dst = hist (in-place on S1)
  csr_gather<<<GRIDW(NS)>>>(in_rowp, in_col, V0, S0, NS);
  combine_mfma<true,true,true><<<GEMM(NS)>>>(S1, S0, WBR(4), WBL(4),
                                             sage_bl + (size_t)4*H, S1, NS);

  // ---- SAGE 5,6 on ss (in-place on S1)
  for(int l = 5; l < 7; l++){
    csr_gather<<<GRIDW(NS)>>>(ss_rowp, ss_col, S1, S0, NS);
    combine_mfma<true,true,true><<<GEMM(NS)>>>(S1, S0, WBR(l), WBL(l),
                                               sage_bl + (size_t)l*H, S1, NS);
  }

  // ---- final MLP -> d_out (f32)
  mlp_out_bf<<<GRIDW(NS)>>>(S1, mlp_W, mlp_b, out, NS);

  #undef GRID1
  #undef GRIDW
  #undef GEMM
  #undef WBL
  #undef WBR
}

// Round 9
// 898.243 us; speedup vs baseline: 7.3947x; 1.0118x over previous
//
#include <hip/hip_runtime.h>

#define H 128
typedef unsigned short u16;
typedef __attribute__((ext_vector_type(8))) short bf16x8;
typedef __attribute__((ext_vector_type(4))) float f32x4;

// ---------------------------------------------------------------- utilities

static inline int gridFor(long long work, int block, int cap = 8192){
  long long g = (work + block - 1) / block;
  if (g > cap) g = cap;
  if (g < 1) g = 1;
  return (int)g;
}

__device__ __forceinline__ float waveReduceSum(float v){
  #pragma unroll
  for(int off = 32; off > 0; off >>= 1) v += __shfl_down(v, off);
  return v;
}

__device__ __forceinline__ float bflo(unsigned v){ return __uint_as_float(v << 16); }
__device__ __forceinline__ float bfhi(unsigned v){ return __uint_as_float(v & 0xffff0000u); }
__device__ __forceinline__ u16 f2bf(float f){
  unsigned u = __float_as_uint(f);
  return (u16)((u + 0x7fffu + ((u >> 16) & 1u)) >> 16);
}
__device__ __forceinline__ unsigned pack2(float lo, float hi){
  return (unsigned)f2bf(lo) | ((unsigned)f2bf(hi) << 16);
}

// ---------------------------------------------------------------- bucketed CSR build
#define BSHIFT 9
#define CH 2048

template<bool HAS_ATTR>
__global__ __launch_bounds__(256) void part_kernel(
    const int* __restrict__ src, const int* __restrict__ dst,
    const float* __restrict__ attr, int* __restrict__ bcur,
    int2* __restrict__ bpairs, float* __restrict__ battr, int E, int cap){
  __shared__ int hist[256];
  __shared__ int hscan[256];
  __shared__ int hbase[256];
  __shared__ int hcur[256];
  __shared__ int2 buf[CH];
  __shared__ float abuf[HAS_ATTR ? CH : 1];

  const int t = threadIdx.x;
  const int e0 = blockIdx.x * CH;
  const int cnt = min(CH, E - e0);

  hist[t] = 0; hcur[t] = 0;
  __syncthreads();

  #pragma unroll
  for(int j = 0; j < 8; j++){
    int i = e0 + j*256 + t;
    if(i - e0 < cnt) atomicAdd(&hist[dst[i] >> BSHIFT], 1);
  }
  __syncthreads();

  {
    int v = hist[t];
    int lane = t & 63, wid = t >> 6;
    int incl = v;
    #pragma unroll
    for(int off = 1; off < 64; off <<= 1){
      int u = __shfl_up(incl, off);
      if(lane >= off) incl += u;
    }
    __shared__ int ws4[4];
    if(lane == 63) ws4[wid] = incl;
    __syncthreads();
    int wofs = 0;
    for(int wj = 0; wj < wid; wj++) wofs += ws4[wj];
    hscan[t] = wofs + incl - v;
    hbase[t] = (v > 0) ? atomicAdd(&bcur[t], v) : 0;
  }
  __syncthreads();

  #pragma unroll
  for(int j = 0; j < 8; j++){
    int i = e0 + j*256 + t;
    if(i - e0 < cnt){
      int d = dst[i], s = src[i];
      int b = d >> BSHIFT;
      int lp = atomicAdd(&hcur[b], 1);
      int slot = hscan[b] + lp;
      buf[slot] = make_int2(d, s);
      if(HAS_ATTR) abuf[slot] = attr[i];
    }
  }
  __syncthreads();

  for(int u = t; u < cnt; u += 256){
    int2 pr = buf[u];
    int b = pr.x >> BSHIFT;
    int g = b * cap + hbase[b] + (u - hscan[b]);
    bpairs[g] = pr;
    if(HAS_ATTR) battr[g] = abuf[u];
  }
}

__global__ void bucket_scan(const int* __restrict__ bcur, int* __restrict__ bbase,
                            int* __restrict__ rp0, int* __restrict__ rp1,
                            int* __restrict__ rp2, int* __restrict__ rp3,
                            int n0, int n1, int n2, int n3){
  int g = blockIdx.x;
  int n = (g == 0) ? n0 : (g == 1) ? n1 : (g == 2) ? n2 : n3;
  int* rowp = (g == 0) ? rp0 : (g == 1) ? rp1 : (g == 2) ? rp2 : rp3;
  int NB = (n + 511) >> BSHIFT;
  int t = threadIdx.x;
  int v = (t < NB) ? bcur[g*256 + t] : 0;
  int lane = t & 63, wid = t >> 6;
  int incl = v;
  #pragma unroll
  for(int off = 1; off < 64; off <<= 1){
    int u = __shfl_up(incl, off);
    if(lane >= off) incl += u;
  }
  __shared__ int ws4[4];
  if(lane == 63) ws4[wid] = incl;
  __syncthreads();
  int wofs = 0;
  for(int wj = 0; wj < wid; wj++) wofs += ws4[wj];
  bbase[g*256 + t] = wofs + incl - v;
  if(t == 0) rowp[n] = ws4[0] + ws4[1] + ws4[2] + ws4[3];
}

template<bool HAS_ATTR, bool DINV>
__global__ __launch_bounds__(256) void build_kernel(
    const int2* __restrict__ bpairs, const float* __restrict__ battr,
    const int* __restrict__ bcur, const int* __restrict__ bbase,
    int* __restrict__ rowp, int* __restrict__ col, float* __restrict__ attrp,
    float* __restrict__ dinv, int cap, int n){
  __shared__ int hist[512];
  __shared__ int hcur[512];
  __shared__ int ws4[4];

  const int b = blockIdx.x;
  const int t = threadIdx.x;
  const int d0 = b << BSHIFT;
  const int dn = min(512, n - d0);
  const int cnt = bcur[b];
  const int base = bbase[b];
  const int2* ep = bpairs + (size_t)b * cap;

  hist[t] = 0; hist[t + 256] = 0;
  __syncthreads();
  for(int u = t; u < cnt; u += 256) atomicAdd(&hist[ep[u].x - d0], 1);
  __syncthreads();

  int a0 = hist[2*t], a1 = hist[2*t + 1];
  int s = a0 + a1;
  int lane = t & 63, wid = t >> 6;
  int incl = s;
  #pragma unroll
  for(int off = 1; off < 64; off <<= 1){
    int u = __shfl_up(incl, off);
    if(lane >= off) incl += u;
  }
  if(lane == 63) ws4[wid] = incl;
  __syncthreads();
  int wofs = 0;
  for(int wj = 0; wj < wid; wj++) wofs += ws4[wj];
  int excl = wofs + incl - s;
  __syncthreads();
  hcur[2*t] = excl; hcur[2*t + 1] = excl + a0;
  if(2*t < dn){
    rowp[d0 + 2*t] = base + excl;
    if(DINV) dinv[d0 + 2*t] = a0 > 0 ? rsqrtf((float)a0) : 0.f;
  }
  if(2*t + 1 < dn){
    rowp[d0 + 2*t + 1] = base + excl + a0;
    if(DINV) dinv[d0 + 2*t + 1] = a1 > 0 ? rsqrtf((float)a1) : 0.f;
  }
  __syncthreads();

  for(int u = t; u < cnt; u += 256){
    int2 pr = ep[u];
    int pos = base + atomicAdd(&hcur[pr.x - d0], 1);
    col[pos] = pr.y;
    if(HAS_ATTR) attrp[pos] = battr[(size_t)b * cap + u];
  }
}

// ---------------------------------------------------------------- weights to bf16 frag-major

__global__ void cvt_weights(const float* __restrict__ Wl, const float* __restrict__ Wr,
                            const float* __restrict__ Wsrc, u16* __restrict__ Wb){
  const int total = 15 * H * H;
  for(int t = blockIdx.x*blockDim.x + threadIdx.x; t < total; t += gridDim.x*blockDim.x){
    int mat = t >> 14, idx = t & 16383;
    int k = idx >> 7, colj = idx & 127;
    const float* srcp = (mat < 7) ? (Wl + ((size_t)mat << 14))
                       : (mat < 14) ? (Wr + ((size_t)(mat - 7) << 14))
                       : Wsrc;
    Wb[((size_t)mat << 14) + (size_t)colj*H + k] = f2bf(srcp[idx]);
  }
}

__global__ void mat_vec_row(const float* __restrict__ W, const float* __restrict__ a,
                            float* __restrict__ outv){
  int k = threadIdx.x;
  if(k < H){
    float s = 0.f;
    for(int j = 0; j < H; j++) s += W[(size_t)k*H + j] * a[j];
    outv[k] = s;
  }
}

__global__ void dot128(const float* __restrict__ a, const float* __restrict__ b,
                       float* __restrict__ o){
  int l = threadIdx.x;
  float acc = a[l]*b[l] + a[l+64]*b[l+64];
  acc = waveReduceSum(acc);
  if(l == 0) o[0] = acc;
}

// ---------------------------------------------------------------- TAG

// hout[i*8 + k] = sum_{e: dst=i} hin[src*sin + k] * dinv[src]*dinv[i]
// (hop outputs padded to 8-float rows = 32B aligned -> single-line fetches)
template<int C>
__global__ void csr_tag_hop(const int* __restrict__ rowp, const int* __restrict__ col,
                            const float* __restrict__ dinv,
                            const float* __restrict__ hin, int sin,
                            float* __restrict__ hout, int N){
  for(int i = blockIdx.x*blockDim.x + threadIdx.x; i < N; i += gridDim.x*blockDim.x){
    int b = rowp[i], e = rowp[i+1];
    float dd = dinv[i];
    float acc0[C], acc1[C];
    #pragma unroll
    for(int k = 0; k < C; k++){ acc0[k] = 0.f; acc1[k] = 0.f; }
    int p = b;
    for(; p + 2 <= e; p += 2){
      int s0 = col[p], s1 = col[p+1];
      float n0 = dinv[s0] * dd, n1 = dinv[s1] * dd;
      #pragma unroll
      for(int k = 0; k < C; k++){
        acc0[k] += hin[(size_t)s0*sin + k] * n0;
        acc1[k] += hin[(size_t)s1*sin + k] * n1;
      }
    }
    if(p < e){
      int s0 = col[p];
      float n0 = dinv[s0] * dd;
      #pragma unroll
      for(int k = 0; k < C; k++) acc0[k] += hin[(size_t)s0*sin + k] * n0;
    }
    #pragma unroll
    for(int k = 0; k < C; k++) hout[(size_t)i*8 + k] = acc0[k] + acc1[k];
  }
}

// out = relu( x@W0 + h1@W1 + h2@W2 + h3@W3 + b ), out bf16
template<int C>
__global__ __launch_bounds__(256) void tag_fuse(
    const float* __restrict__ x, const float* __restrict__ h1,
    const float* __restrict__ h2, const float* __restrict__ h3,
    const float* __restrict__ W, const float* __restrict__ bias,
    u16* __restrict__ out, int N){
  __shared__ float Ws[4*C*H];
  for(int u = threadIdx.x; u < 4*C*H; u += 256) Ws[u] = W[u];
  __syncthreads();
  const long long total = (long long)N * H;
  for(long long t = (long long)blockIdx.x*blockDim.x + threadIdx.x; t < total;
      t += (long long)gridDim.x*blockDim.x){
    int i = (int)(t >> 7), j = (int)(t & 127);
    const float* xr = x + (size_t)i*C;
    const float* r1 = h1 + (size_t)i*8;
    const float* r2 = h2 + (size_t)i*8;
    const float* r3 = h3 + (size_t)i*8;
    float acc = bias[j];
    #pragma unroll
    for(int k = 0; k < C; k++) acc += xr[k] * Ws[k*H + j];
    #pragma unroll
    for(int k = 0; k < C; k++) acc += r1[k] * Ws[(C + k)*H + j];
    #pragma unroll
    for(int k = 0; k < C; k++) acc += r2[k] * Ws[(2*C + k)*H + j];
    #pragma unroll
    for(int k = 0; k < C; k++) acc += r3[k] * Ws[(3*C + k)*H + j];
    out[t] = f2bf(fmaxf(acc, 0.f));
  }
}

// ---------------------------------------------------------------- fused SAGE (gather + dual-GEMM)

// out = relu( mean_{nbr} G[nbr] @ Wl + X @ Wr + bl ), all bf16, f32 accum.
// Block = 4 waves x 32 rows. Wr staged in LDS (swizzled), X-phase MFMAs;
// restage Wl; per-row register gather (neighbors-outer, full row per visit);
// mean -> bf16 -> MFMAs. Ping-pong buffers: no in-place race.
__global__ __launch_bounds__(256) void sage_fused(
    const u16* __restrict__ G, const u16* __restrict__ X,
    const int* __restrict__ rowp, const int* __restrict__ col,
    const u16* __restrict__ WbR, const u16* __restrict__ WbL,
    const float* __restrict__ bl, u16* __restrict__ out, int N){
  __shared__ u16 Ws[H * H];   // 32 KB, staged twice

  const int t = threadIdx.x;
  const int lane = t & 63;
  const int wib = t >> 6;
  const int m0 = (blockIdx.x * 4 + wib) * 32;
  const int r16 = lane & 15;
  const int kg  = (lane >> 4) * 8;
  const bool active = (m0 < N);

  // ---- stage Wr (swizzled: byte ^= (col&7)<<4)
  for(int u = t; u < H*H/8; u += 256){
    bf16x8 v = *(const bf16x8*)&WbR[u*8];
    int c = u >> 4, kb = (u & 15) * 16;
    *(bf16x8*)((char*)Ws + c*256 + (kb ^ ((c & 7) << 4))) = v;
  }
  __syncthreads();

  f32x4 acc[2][8];
  #pragma unroll
  for(int rt = 0; rt < 2; rt++)
    #pragma unroll
    for(int tt = 0; tt < 8; tt++) acc[rt][tt] = (f32x4){0.f,0.f,0.f,0.f};

  // ---- X phase: acc += X @ Wr
  if(active){
    #pragma unroll
    for(int k0c = 0; k0c < 4; k0c++){
      int k0 = k0c * 32;
      bf16x8 af[2];
      #pragma unroll
      for(int rt = 0; rt < 2; rt++){
        int row = m0 + rt*16 + r16;
        if(row < N) af[rt] = *(const bf16x8*)&X[(size_t)row*H + k0 + kg];
        else        af[rt] = (bf16x8){0,0,0,0,0,0,0,0};
      }
      #pragma unroll
      for(int tt = 0; tt < 8; tt++){
        int c = tt*16 + r16;
        int kb = (k0 + kg)*2;
        bf16x8 bf = *(const bf16x8*)((char*)Ws + c*256 + (kb ^ ((c & 7) << 4)));
        acc[0][tt] = __builtin_amdgcn_mfma_f32_16x16x32_bf16(af[0], bf, acc[0][tt], 0, 0, 0);
        acc[1][tt] = __builtin_amdgcn_mfma_f32_16x16x32_bf16(af[1], bf, acc[1][tt], 0, 0, 0);
      }
    }
  }
  __syncthreads();

  // ---- stage Wl
  for(int u = t; u < H*H/8; u += 256){
    bf16x8 v = *(const bf16x8*)&WbL[u*8];
    int c = u >> 4, kb = (u & 15) * 16;
    *(bf16x8*)((char*)Ws + c*256 + (kb ^ ((c & 7) << 4))) = v;
  }
  __syncthreads();

  // ---- gather + agg phase (per rt to bound registers)
  if(active){
    #pragma unroll
    for(int rt = 0; rt < 2; rt++){
      int row = m0 + rt*16 + r16;
      float ag[4][8];
      #pragma unroll
      for(int kc = 0; kc < 4; kc++)
        #pragma unroll
        for(int j = 0; j < 8; j++) ag[kc][j] = 0.f;

      if(row < N){
        int b = rowp[row], e = rowp[row+1];
        for(int p = b; p < e; p++){
          int s = col[p];
          const u16* gr = &G[(size_t)s*H + kg];
          #pragma unroll
          for(int kc = 0; kc < 4; kc++){
            bf16x8 v = *(const bf16x8*)(gr + kc*32);
            const unsigned* vu = (const unsigned*)&v;
            #pragma unroll
            for(int q = 0; q < 4; q++){
              ag[kc][2*q]   += bflo(vu[q]);
              ag[kc][2*q+1] += bfhi(vu[q]);
            }
          }
        }
        float inv = 1.f / fmaxf((float)(e - b), 1.f);
        #pragma unroll
        for(int kc = 0; kc < 4; kc++)
          #pragma unroll
          for(int j = 0; j < 8; j++) ag[kc][j] *= inv;
      }

      #pragma unroll
      for(int kc = 0; kc < 4; kc++){
        unsigned uu[4];
        #pragma unroll
        for(int q = 0; q < 4; q++) uu[q] = pack2(ag[kc][2*q], ag[kc][2*q+1]);
        bf16x8 agb = *(bf16x8*)uu;
        int kb = (kc*32 + kg)*2;
        #pragma unroll
        for(int tt = 0; tt < 8; tt++){
          int c = tt*16 + r16;
          bf16x8 bf = *(const bf16x8*)((char*)Ws + c*256 + (kb ^ ((c & 7) << 4)));
          acc[rt][tt] = __builtin_amdgcn_mfma_f32_16x16x32_bf16(agb, bf, acc[rt][tt], 0, 0, 0);
        }
      }
    }

    // ---- epilogue
    #pragma unroll
    for(int rt = 0; rt < 2; rt++){
      const int orow = m0 + rt*16 + (lane >> 4) * 4;
      #pragma unroll
      for(int tt = 0; tt < 8; tt++){
        int c = tt*16 + r16;
        float bb = bl[c];
        #pragma unroll
        for(int r = 0; r < 4; r++){
          if(orow + r < N){
            float v = fmaxf(acc[rt][tt][r] + bb, 0.f);
            out[(size_t)(orow + r)*H + c] = f2bf(v);
          }
        }
      }
    }
  }
}

// ---------------------------------------------------------------- single-matrix MFMA (hs = gx @ Wsrc)

__global__ __launch_bounds__(256) void gemm_mfma(
    const u16* __restrict__ x, const u16* __restrict__ Wb,
    u16* __restrict__ out, int N){
  __shared__ u16 Ws[H * H];
  const int t = threadIdx.x;
  for(int u = t; u < H*H/8; u += 256){
    bf16x8 v = *(const bf16x8*)&Wb[u*8];
    int c = u >> 4, kb = (u & 15) * 16;
    *(bf16x8*)((char*)Ws + c*256 + (kb ^ ((c & 7) << 4))) = v;
  }
  __syncthreads();

  const int lane = t & 63;
  const int wib = t >> 6;
  const int m0 = (blockIdx.x * 4 + wib) * 32;
  if(m0 >= N) return;
  const int r16 = lane & 15;
  const int kg = (lane >> 4) * 8;

  f32x4 acc[2][8];
  #pragma unroll
  for(int rt = 0; rt < 2; rt++)
    #pragma unroll
    for(int tt = 0; tt < 8; tt++) acc[rt][tt] = (f32x4){0.f,0.f,0.f,0.f};

  #pragma unroll
  for(int k0c = 0; k0c < 4; k0c++){
    int k0 = k0c * 32;
    bf16x8 af[2];
    #pragma unroll
    for(int rt = 0; rt < 2; rt++){
      int row = m0 + rt*16 + r16;
      if(row < N) af[rt] = *(const bf16x8*)&x[(size_t)row*H + k0 + kg];
      else        af[rt] = (bf16x8){0,0,0,0,0,0,0,0};
    }
    #pragma unroll
    for(int tt = 0; tt < 8; tt++){
      int c = tt*16 + r16;
      int kb = (k0 + kg)*2;
      bf16x8 bf = *(const bf16x8*)((char*)Ws + c*256 + (kb ^ ((c & 7) << 4)));
      acc[0][tt] = __builtin_amdgcn_mfma_f32_16x16x32_bf16(af[0], bf, acc[0][tt], 0, 0, 0);
      acc[1][tt] = __builtin_amdgcn_mfma_f32_16x16x32_bf16(af[1], bf, acc[1][tt], 0, 0, 0);
    }
  }

  #pragma unroll
  for(int rt = 0; rt < 2; rt++){
    const int orow = m0 + rt*16 + (lane >> 4) * 4;
    #pragma unroll
    for(int tt = 0; tt < 8; tt++){
      int c = tt*16 + r16;
      #pragma unroll
      for(int r = 0; r < 4; r++){
        if(orow + r < N)
          out[(size_t)(orow + r)*H + c] = f2bf(acc[rt][tt][r]);
      }
    }
  }
}

// ---------------------------------------------------------------- GAT

__global__ void rowdot_bf(const u16* __restrict__ x, const float* __restrict__ v,
                          float* __restrict__ out, int N){
  int lane = threadIdx.x & 63;
  int w = (blockIdx.x*blockDim.x + threadIdx.x) >> 6;
  int nw = (gridDim.x*blockDim.x) >> 6;
  for(int i = w; i < N; i += nw){
    unsigned u = *(const unsigned*)&x[(size_t)i*H + lane*2];
    float acc = bflo(u)*v[lane*2] + bfhi(u)*v[lane*2 + 1];
    acc = waveReduceSum(acc);
    if(lane == 0) out[i] = acc;
  }
}

__global__ void gat_fused(const int* __restrict__ rowp, const int* __restrict__ colv,
                          const float* __restrict__ attrp, const float* __restrict__ av,
                          const float* __restrict__ ad, const float* __restrict__ cptr,
                          const u16* __restrict__ hs, const float* __restrict__ bias,
                          u16* __restrict__ out, int N){
  const float c = cptr[0];
  int lane = threadIdx.x & 63;
  int w = (blockIdx.x*blockDim.x + threadIdx.x) >> 6;
  int nw = (gridDim.x*blockDim.x) >> 6;
  for(int i = w; i < N; i += nw){
    int b = rowp[i], e = rowp[i+1];
    float adi = ad[i];
    float accx0 = 0.f, accy0 = 0.f, accx1 = 0.f, accy1 = 0.f;
    float sume = 0.f;
    int p = b;
    for(; p + 2 <= e; p += 2){
      int s0 = colv[p], s1 = colv[p+1];
      float a0 = av[s0] + adi + attrp[p] * c;
      float a1 = av[s1] + adi + attrp[p+1] * c;
      a0 = a0 > 0.f ? a0 : 0.2f * a0;
      a1 = a1 > 0.f ? a1 : 0.2f * a1;
      float e0 = __expf(a0), e1 = __expf(a1);
      unsigned v0 = *(const unsigned*)&hs[(size_t)s0*H + lane*2];
      unsigned v1 = *(const unsigned*)&hs[(size_t)s1*H + lane*2];
      accx0 += e0 * bflo(v0); accy0 += e0 * bfhi(v0);
      accx1 += e1 * bflo(v1); accy1 += e1 * bfhi(v1);
      sume += e0 + e1;
    }
    if(p < e){
      int s0 = colv[p];
      float a0 = av[s0] + adi + attrp[p] * c;
      a0 = a0 > 0.f ? a0 : 0.2f * a0;
      float e0 = __expf(a0);
      unsigned v0 = *(const unsigned*)&hs[(size_t)s0*H + lane*2];
      accx0 += e0 * bflo(v0); accy0 += e0 * bfhi(v0);
      sume += e0;
    }
    float rd = 1.f / fmaxf(sume, 1e-16f);
    float ox = fmaxf((accx0 + accx1) * rd + bias[lane*2],     0.f);
    float oy = fmaxf((accy0 + accy1) * rd + bias[lane*2 + 1], 0.f);
    *(unsigned*)&out[(size_t)i*H + lane*2] = pack2(ox, oy);
  }
}

__global__ void mlp_out_bf(const u16* __restrict__ x, const float* __restrict__ W,
                           const float* __restrict__ b, float* __restrict__ out, int N){
  int lane = threadIdx.x & 63;
  int w = (blockIdx.x*blockDim.x + threadIdx.x) >> 6;
  int nw = (gridDim.x*blockDim.x) >> 6;
  for(int i = w; i < N; i += nw){
    unsigned u = *(const unsigned*)&x[(size_t)i*H + lane*2];
    float acc = bflo(u)*W[lane*2] + bfhi(u)*W[lane*2 + 1];
    acc = waveReduceSum(acc);
    if(lane == 0) out[i] = acc + b[0];
  }
}

// ---------------------------------------------------------------- launch

extern "C" void kernel_launch(void* const* d_in, const int* in_sizes, int n_in,
                              void* d_out, int out_size, void* d_ws, size_t ws_size,
                              hipStream_t stream) {
  const float* game_x  = (const float*)d_in[0];
  const float* state_x = (const float*)d_in[1];
  const int*   e_vv    = (const int*)d_in[2];
  const int*   e_hist  = (const int*)d_in[4];
  const float* attr_h  = (const float*)d_in[5];
  const int*   e_in    = (const int*)d_in[6];
  const int*   e_ss    = (const int*)d_in[7];
  const float* tag1_W  = (const float*)d_in[8];
  const float* tag1_b  = (const float*)d_in[9];
  const float* tag2_W  = (const float*)d_in[10];
  const float* tag2_b  = (const float*)d_in[11];
  const float* sage_Wl = (const float*)d_in[12];
  const float* sage_bl = (const float*)d_in[13];
  const float* sage_Wr = (const float*)d_in[14];
  const float* gat_Wsrc= (const float*)d_in[15];
  const float* gat_Wdst= (const float*)d_in[16];
  const float* gat_We  = (const float*)d_in[17];
  const float* gat_asrc= (const float*)d_in[18];
  const float* gat_adst= (const float*)d_in[19];
  const float* gat_ae  = (const float*)d_in[20];
  const float* gat_b   = (const float*)d_in[21];
  const float* mlp_W   = (const float*)d_in[22];
  const float* mlp_b   = (const float*)d_in[23];
  float* out = (float*)d_out;

  const int NV  = in_sizes[0] / 5;
  const int NS  = in_sizes[1] / 6;
  const int EVV = in_sizes[2] / 2;
  const int EH  = in_sizes[4] / 2;
  const int EIN = in_sizes[6] / 2;
  const int ESS = in_sizes[7] / 2;

  const int* vv_src = e_vv;   const int* vv_dst = e_vv + EVV;
  const int* eh_src = e_hist; const int* eh_dst = e_hist + EH;
  const int* in_src = e_in;   const int* in_dst = e_in + EIN;
  const int* ss_src = e_ss;   const int* ss_dst = e_ss + ESS;

  const int NBv = (NV + 511) >> BSHIFT;
  const int NBs = (NS + 511) >> BSHIFT;
  const int capvv = (EVV / NBv) * 3 / 2 + 64;
  const int capss = (ESS / NBs) * 3 / 2 + 64;
  const int capeh = (EH  / NBs) * 3 / 2 + 64;
  const int capin = (EIN / NBs) * 3 / 2 + 64;

  char* wp = (char*)d_ws;
  auto alloc = [&](size_t bytes) -> void* {
    void* p = (void*)wp;
    wp += (bytes + 511) & ~size_t(511);
    return p;
  };
  u16* V0 = (u16*)alloc((size_t)NV*H*2);
  u16* V1 = (u16*)alloc((size_t)NV*H*2);
  u16* S0 = (u16*)alloc((size_t)NS*H*2);
  u16* S1 = (u16*)alloc((size_t)NS*H*2);
  u16* Wb = (u16*)alloc((size_t)15*H*H*2);
  float* dinv_v = (float*)alloc((size_t)NV*4);
  float* dinv_s = (float*)alloc((size_t)NS*4);
  float* av   = (float*)alloc((size_t)NV*4);
  float* ad   = (float*)alloc((size_t)NS*4);
  float* h5a  = (float*)alloc((size_t)NV*8*4);
  float* h5b  = (float*)alloc((size_t)NV*8*4);
  float* h5c  = (float*)alloc((size_t)NV*8*4);
  float* h6a  = (float*)alloc((size_t)NS*8*4);
  float* h6b  = (float*)alloc((size_t)NS*8*4);
  float* h6c  = (float*)alloc((size_t)NS*8*4);
  float* wvec = (float*)alloc(H*4);
  float* cbuf = (float*)alloc(4);
  int* vv_rowp = (int*)alloc((size_t)(NV+1)*4);
  int* vv_col  = (int*)alloc((size_t)EVV*4);
  int* ss_rowp = (int*)alloc((size_t)(NS+1)*4);
  int* ss_col  = (int*)alloc((size_t)ESS*4);
  int* eh_rowp = (int*)alloc((size_t)(NS+1)*4);
  int* eh_col  = (int*)alloc((size_t)EH*4);
  float* eh_attr = (float*)alloc((size_t)EH*4);
  int* in_rowp = (int*)alloc((size_t)(NS+1)*4);
  int* in_col  = (int*)alloc((size_t)EIN*4);
  int2* vv_bp = (int2*)alloc((size_t)NBv*capvv*8);
  int2* ss_bp = (int2*)alloc((size_t)NBs*capss*8);
  int2* eh_bp = (int2*)alloc((size_t)NBs*capeh*8);
  int2* in_bp = (int2*)alloc((size_t)NBs*capin*8);
  float* eh_ba = (float*)alloc((size_t)NBs*capeh*4);
  int* bcur  = (int*)alloc(4*256*4);
  int* bbase = (int*)alloc(4*256*4);
  (void)ws_size; (void)n_in; (void)out_size;

  const int B = 256;
  #define GRID1(n) gridFor((long long)(n), B), B, 0, stream
  #define GRIDW(e) gridFor((long long)(e) * 64, B, 8192), B, 0, stream
  #define GEMM(n)  ((n) + 127) / 128, 256, 0, stream

  // ---- bucketed CSR build
  hipMemsetAsync(bcur, 0, 4*256*4, stream);
  part_kernel<false><<<(EVV + CH - 1)/CH, 256, 0, stream>>>(
      vv_src, vv_dst, nullptr, bcur + 0,   vv_bp, nullptr, EVV, capvv);
  part_kernel<false><<<(ESS + CH - 1)/CH, 256, 0, stream>>>(
      ss_src, ss_dst, nullptr, bcur + 256, ss_bp, nullptr, ESS, capss);
  part_kernel<true ><<<(EH  + CH - 1)/CH, 256, 0, stream>>>(
      eh_src, eh_dst, attr_h,  bcur + 512, eh_bp, eh_ba,   EH,  capeh);
  part_kernel<false><<<(EIN + CH - 1)/CH, 256, 0, stream>>>(
      in_src, in_dst, nullptr, bcur + 768, in_bp, nullptr, EIN, capin);
  bucket_scan<<<4, 256, 0, stream>>>(bcur, bbase, vv_rowp, ss_rowp, eh_rowp, in_rowp,
                                     NV, NS, NS, NS);
  build_kernel<false,true ><<<NBv, 256, 0, stream>>>(
      vv_bp, nullptr, bcur + 0,   bbase + 0,   vv_rowp, vv_col, nullptr, dinv_v, capvv, NV);
  build_kernel<false,true ><<<NBs, 256, 0, stream>>>(
      ss_bp, nullptr, bcur + 256, bbase + 256, ss_rowp, ss_col, nullptr, dinv_s, capss, NS);
  build_kernel<true ,false><<<NBs, 256, 0, stream>>>(
      eh_bp, eh_ba,   bcur + 512, bbase + 512, eh_rowp, eh_col, eh_attr, nullptr, capeh, NS);
  build_kernel<false,false><<<NBs, 256, 0, stream>>>(
      in_bp, nullptr, bcur + 768, bbase + 768, in_rowp, in_col, nullptr, nullptr, capin, NS);

  // ---- weight prep
  cvt_weights<<<GRID1(15*H*H)>>>(sage_Wl, sage_Wr, gat_Wsrc, Wb);
  mat_vec_row<<<1, 128, 0, stream>>>(gat_Wdst, gat_adst, wvec);
  dot128<<<1, 64, 0, stream>>>(gat_We, gat_ae, cbuf);

  #define WBL(l) (Wb + ((size_t)(l) << 14))
  #define WBR(l) (Wb + ((size_t)(7 + (l)) << 14))

  // ---- TAG1 (game tower) -> V0
  csr_tag_hop<5><<<GRID1(NV)>>>(vv_rowp, vv_col, dinv_v, game_x, 5, h5a, NV);
  csr_tag_hop<5><<<GRID1(NV)>>>(vv_rowp, vv_col, dinv_v, h5a, 8, h5b, NV);
  csr_tag_hop<5><<<GRID1(NV)>>>(vv_rowp, vv_col, dinv_v, h5b, 8, h5c, NV);
  tag_fuse<5><<<GRID1((long long)NV*H)>>>(game_x, h5a, h5b, h5c, tag1_W, tag1_b, V0, NV);

  // ---- SAGE 0,1 on vv (ping-pong V0 -> V1 -> V0)
  sage_fused<<<GEMM(NV)>>>(V0, V0, vv_rowp, vv_col, WBR(0), WBL(0),
                           sage_bl + 0*H, V1, NV);
  sage_fused<<<GEMM(NV)>>>(V1, V1, vv_rowp, vv_col, WBR(1), WBL(1),
                           sage_bl + 1*H, V0, NV);          // gx = V0

  // ---- TAG2 (state tower) -> S0
  csr_tag_hop<6><<<GRID1(NS)>>>(ss_rowp, ss_col, dinv_s, state_x, 6, h6a, NS);
  csr_tag_hop<6><<<GRID1(NS)>>>(ss_rowp, ss_col, dinv_s, h6a, 8, h6b, NS);
  csr_tag_hop<6><<<GRID1(NS)>>>(ss_rowp, ss_col, dinv_s, h6b, 8, h6c, NS);
  tag_fuse<6><<<GRID1((long long)NS*H)>>>(state_x, h6a, h6b, h6c, tag2_W, tag2_b, S0, NS);

  // ---- SAGE 2,3 on ss (S0 -> S1 -> S0)
  sage_fused<<<GEMM(NS)>>>(S0, S0, ss_rowp, ss_col, WBR(2), WBL(2),
                           sage_bl + 2*H, S1, NS);
  sage_fused<<<GEMM(NS)>>>(S1, S1, ss_rowp, ss_col, WBR(3), WBL(3),
                           sage_bl + 3*H, S0, NS);          // sx = S0

  // ---- GAT (gx -> sx) : hist -> S1
  gemm_mfma<<<GEMM(NV)>>>(V0, Wb + ((size_t)14 << 14), V1, NV);   // hs = gx@Wsrc -> V1
  rowdot_bf<<<GRIDW(NV)>>>(V1, gat_asrc, av, NV);
  rowdot_bf<<<GRIDW(NS)>>>(S0, wvec, ad, NS);                     // ad = sx @ (Wdst@adst)
  gat_fused<<<GRIDW(NS)>>>(eh_rowp, eh_col, eh_attr, av, ad, cbuf, V1, gat_b, S1, NS);

  // ---- SAGE4: gather gx over in-CSR, x_dst = hist(S1) -> S0
  sage_fused<<<GEMM(NS)>>>(V0, S1, in_rowp, in_col, WBR(4), WBL(4),
                           sage_bl + 4*H, S0, NS);

  // ---- SAGE 5,6 on ss (S0 -> S1 -> S0)
  sage_fused<<<GEMM(NS)>>>(S0, S0, ss_rowp, ss_col, WBR(5), WBL(5),
                           sage_bl + 5*H, S1, NS);
  sage_fused<<<GEMM(NS)>>>(S1, S1, ss_rowp, ss_col, WBR(6), WBL(6),
                           sage_bl + 6*H, S0, NS);

  // ---- final MLP -> d_out (f32)
  mlp_out_bf<<<GRIDW(NS)>>>(S0, mlp_W, mlp_b, out, NS);

  #undef GRID1
  #undef GRIDW
  #undef GEMM
  #undef WBL
  #undef WBR
}